// Round 10
// baseline (1332.118 us; speedup 1.0000x reference)
//
#include <hip/hip_runtime.h>

#define NL 8
#define NM 8192
#define ND 16
#define NH 256
#define NF 64
#define NN (NL * NM)

typedef unsigned short u16;

__device__ __forceinline__ float lrelu(float x) { return fmaxf(x, 0.1f * x); }

// f32 -> bf16 round-to-nearest-even
__device__ __forceinline__ u16 f2bf(float x) {
    union { float f; unsigned int u; } v; v.f = x;
    unsigned int r = (v.u + 0x7FFFu + ((v.u >> 16) & 1u)) >> 16;
    return (u16)r;
}
__device__ __forceinline__ ushort4 f4_to_bf4(float4 o) {
    ushort4 r; r.x = f2bf(o.x); r.y = f2bf(o.y); r.z = f2bf(o.z); r.w = f2bf(o.w);
    return r;
}
// unpack 2 bf16 packed in a u32 -> 2 floats (low half = first element)
__device__ __forceinline__ float2 bfp(unsigned int u) {
    union { unsigned int u; float f; } lo, hi;
    lo.u = u << 16; hi.u = u & 0xFFFF0000u;
    return make_float2(lo.f, hi.f);
}

// ---------- precompute attention constants: cst[32..63] = W_p2 @ av_p ----------
__global__ void precomp_kernel(const float* __restrict__ W_p2, const float* __restrict__ av,
                               float* __restrict__ cst)
{
    int j = threadIdx.x;   // 32 threads
    float w = 0.f;
    for (int k = 0; k < 32; ++k) w += W_p2[j * 32 + k] * av[32 + k];
    cst[32 + j] = w;
}

// ---------- Level 0: h = mlp_pi(delay) (bf16 store) + g epilogue ----------
__global__ __launch_bounds__(512) void level0_kernel(
    const float* __restrict__ delay,
    const float* __restrict__ W1, const float* __restrict__ b1,
    const float* __restrict__ W2, const float* __restrict__ b2,
    const float* __restrict__ av,
    u16* __restrict__ h_all, float* __restrict__ g_all)
{
    const int tid = threadIdx.x;
    const int row0 = blockIdx.x * 32;
    __shared__ __align__(16) float sH[32][132];   // pad: stride 132 (mod32=4)

    for (int x = tid; x < 32 * 128; x += 512) {
        int r = x >> 7, j = x & 127;
        sH[r][j] = lrelu(delay[row0 + r] * W1[j] + b1[j]);
    }
    __syncthreads();

    const int tj = tid & 63, tr = tid >> 6;
    const float4 av4 = *(const float4*)(av + 64 + tj * 4);
    float acc[4][4];
    #pragma unroll
    for (int a = 0; a < 4; ++a)
        #pragma unroll
        for (int b = 0; b < 4; ++b) acc[a][b] = 0.f;

    for (int k = 0; k < 128; k += 4) {
        float4 w0 = *(const float4*)(W2 + (size_t)(k + 0) * 256 + tj * 4);
        float4 w1 = *(const float4*)(W2 + (size_t)(k + 1) * 256 + tj * 4);
        float4 w2 = *(const float4*)(W2 + (size_t)(k + 2) * 256 + tj * 4);
        float4 w3 = *(const float4*)(W2 + (size_t)(k + 3) * 256 + tj * 4);
        #pragma unroll
        for (int rr = 0; rr < 4; ++rr) {
            float4 xv = *(const float4*)(&sH[tr * 4 + rr][k]);
            acc[rr][0] += xv.x * w0.x + xv.y * w1.x + xv.z * w2.x + xv.w * w3.x;
            acc[rr][1] += xv.x * w0.y + xv.y * w1.y + xv.z * w2.y + xv.w * w3.y;
            acc[rr][2] += xv.x * w0.z + xv.y * w1.z + xv.z * w2.z + xv.w * w3.z;
            acc[rr][3] += xv.x * w0.w + xv.y * w1.w + xv.z * w2.w + xv.w * w3.w;
        }
    }
    float4 bv = *(const float4*)(b2 + tj * 4);
    #pragma unroll
    for (int rr = 0; rr < 4; ++rr) {
        const int row = row0 + tr * 4 + rr;
        float4 o;
        o.x = acc[rr][0] + bv.x; o.y = acc[rr][1] + bv.y;
        o.z = acc[rr][2] + bv.z; o.w = acc[rr][3] + bv.w;
        *(ushort4*)(h_all + (size_t)row * NH + tj * 4) = f4_to_bf4(o);
        float gp = o.x * av4.x + o.y * av4.y + o.z * av4.z + o.w * av4.w;
        #pragma unroll
        for (int off = 1; off < 64; off <<= 1) gp += __shfl_xor(gp, off);
        if (tj == 0) g_all[row] = gp;
    }
}

// ---------- Attention: 1 wave per m; g-gather alpha + single 16B-load streamed pass ----------
__global__ __launch_bounds__(256) void attn_kernel(
    const u16* __restrict__ h_all, const float* __restrict__ g_all,
    const float* __restrict__ bit_pos, const int* __restrict__ nbr_idx,
    const float* __restrict__ W_p1, const float* __restrict__ b_p1,
    const float* __restrict__ cst,
    float* __restrict__ neigh, int level)
{
    const int w = threadIdx.x >> 6, lane = threadIdx.x & 63;
    const int m = blockIdx.x * 4 + w;
    const int d = lane & 15, jj = lane >> 4;
    const size_t ebase = ((size_t)(level - 1) * NM + m) * ND;

    const int   idx = nbr_idx[ebase + d];
    const float bp  = bit_pos[ebase + d];

    // collapsed mlp_p: 4 jj-groups each cover 8 of the 32 hidden units
    float ep = 0.f;
    #pragma unroll
    for (int t = 0; t < 8; ++t) {
        int j = jj * 8 + t;
        ep += cst[32 + j] * lrelu(bp * W_p1[j] + b_p1[j]);
    }
    ep += __shfl_xor(ep, 16);
    ep += __shfl_xor(ep, 32);

    // e = e_h + e_p  (e_t is constant over d -> cancels in softmax)
    float e = g_all[idx] + ep;
    float mx = e;
    #pragma unroll
    for (int off = 1; off < 16; off <<= 1) mx = fmaxf(mx, __shfl_xor(mx, off));
    float wexp = __expf(e - mx);
    float s = wexp;
    #pragma unroll
    for (int off = 1; off < 16; off <<= 1) s += __shfl_xor(s, off);
    const float alpha = wexp / s;

    // streamed weighted sum: lane = rh*32 + cl; 16B (8 bf16) per lane, 2 rows/step
    const int rh = lane >> 5, cl = lane & 31;
    float4 a0 = make_float4(0.f, 0.f, 0.f, 0.f);
    float4 a1 = make_float4(0.f, 0.f, 0.f, 0.f);
    #pragma unroll
    for (int t = 0; t < 8; ++t) {
        const int d2 = t * 2 + rh;
        float a = __shfl(alpha, d2);
        int   r = __shfl(idx, d2);
        uint4 hv = *(const uint4*)(h_all + (size_t)r * NH + cl * 8);
        float2 p0 = bfp(hv.x), p1 = bfp(hv.y), p2 = bfp(hv.z), p3 = bfp(hv.w);
        a0.x += a * p0.x; a0.y += a * p0.y; a0.z += a * p1.x; a0.w += a * p1.y;
        a1.x += a * p2.x; a1.y += a * p2.y; a1.z += a * p3.x; a1.w += a * p3.y;
    }
    // combine the two row-halves
    a0.x += __shfl_xor(a0.x, 32); a0.y += __shfl_xor(a0.y, 32);
    a0.z += __shfl_xor(a0.z, 32); a0.w += __shfl_xor(a0.w, 32);
    a1.x += __shfl_xor(a1.x, 32); a1.y += __shfl_xor(a1.y, 32);
    a1.z += __shfl_xor(a1.z, 32); a1.w += __shfl_xor(a1.w, 32);

    float4 outv = (rh == 0) ? a0 : a1;
    *(float4*)(neigh + (size_t)m * NH + cl * 8 + rh * 4) = outv;
}

// ---------- Neighborhood MLP: 256 thr / 8 rows / 1024 blocks; col-split; padded LDS ----------
__global__ __launch_bounds__(256) void mlp_n_kernel(
    const float* __restrict__ neigh,
    const float* __restrict__ W1, const float* __restrict__ b1,
    const float* __restrict__ W2, const float* __restrict__ b2,
    const int* __restrict__ is_po, const float* __restrict__ av,
    u16* __restrict__ h_all, float* __restrict__ g_all, int level)
{
    const int tid = threadIdx.x;
    const int w = tid >> 6, lane = tid & 63;
    const int row0 = blockIdx.x * 8;
    __shared__ __align__(16) float sX[8][NH + 4];   // stride 260 (mod32=4)
    __shared__ __align__(16) float sH[8][132];      // stride 132 (mod32=4)
    __shared__ float gpart[4][8];

    for (int x = tid; x < 8 * 64; x += 256) {
        int r = x >> 6, c = x & 63;
        *(float4*)(&sX[r][c * 4]) = *(const float4*)(neigh + (size_t)(row0 + r) * NH + c * 4);
    }
    __syncthreads();

    // layer 1: (8x256)@(256x128); wave w -> cols [w*32, w*32+32); 8 grp x 1 row
    {
        const int tj = lane & 7, tr = lane >> 3;
        const int c0 = w * 32 + tj * 4;
        float acc[4] = {0.f, 0.f, 0.f, 0.f};

        for (int k = 0; k < NH; k += 4) {
            float4 w0 = *(const float4*)(W1 + (size_t)(k + 0) * 128 + c0);
            float4 w1 = *(const float4*)(W1 + (size_t)(k + 1) * 128 + c0);
            float4 w2 = *(const float4*)(W1 + (size_t)(k + 2) * 128 + c0);
            float4 w3 = *(const float4*)(W1 + (size_t)(k + 3) * 128 + c0);
            float4 xv = *(const float4*)(&sX[tr][k]);
            acc[0] += xv.x * w0.x + xv.y * w1.x + xv.z * w2.x + xv.w * w3.x;
            acc[1] += xv.x * w0.y + xv.y * w1.y + xv.z * w2.y + xv.w * w3.y;
            acc[2] += xv.x * w0.z + xv.y * w1.z + xv.z * w2.z + xv.w * w3.z;
            acc[3] += xv.x * w0.w + xv.y * w1.w + xv.z * w2.w + xv.w * w3.w;
        }
        float4 bv = *(const float4*)(b1 + c0);
        float4 o;
        o.x = lrelu(acc[0] + bv.x); o.y = lrelu(acc[1] + bv.y);
        o.z = lrelu(acc[2] + bv.z); o.w = lrelu(acc[3] + bv.w);
        *(float4*)(&sH[tr][c0]) = o;
    }
    __syncthreads();

    // layer 2: (8x128)@(128x256); wave w -> cols [w*64, w*64+64); 4 grp x 2 rows
    {
        const int tj = lane & 15, tr = lane >> 4;
        const int c0 = w * 64 + tj * 4;
        const float4 av4 = *(const float4*)(av + 64 + c0);
        float acc[2][4];
        #pragma unroll
        for (int a = 0; a < 2; ++a)
            #pragma unroll
            for (int b = 0; b < 4; ++b) acc[a][b] = 0.f;

        for (int k = 0; k < 128; k += 4) {
            float4 w0 = *(const float4*)(W2 + (size_t)(k + 0) * 256 + c0);
            float4 w1 = *(const float4*)(W2 + (size_t)(k + 1) * 256 + c0);
            float4 w2 = *(const float4*)(W2 + (size_t)(k + 2) * 256 + c0);
            float4 w3 = *(const float4*)(W2 + (size_t)(k + 3) * 256 + c0);
            #pragma unroll
            for (int rr = 0; rr < 2; ++rr) {
                float4 xv = *(const float4*)(&sH[tr * 2 + rr][k]);
                acc[rr][0] += xv.x * w0.x + xv.y * w1.x + xv.z * w2.x + xv.w * w3.x;
                acc[rr][1] += xv.x * w0.y + xv.y * w1.y + xv.z * w2.y + xv.w * w3.y;
                acc[rr][2] += xv.x * w0.z + xv.y * w1.z + xv.z * w2.z + xv.w * w3.z;
                acc[rr][3] += xv.x * w0.w + xv.y * w1.w + xv.z * w2.w + xv.w * w3.w;
            }
        }
        float4 bv = *(const float4*)(b2 + c0);
        #pragma unroll
        for (int rr = 0; rr < 2; ++rr) {
            const int gm = level * NM + row0 + tr * 2 + rr;
            bool po = (is_po[gm] == 1);
            float4 o;
            o.x = acc[rr][0] + bv.x; o.y = acc[rr][1] + bv.y;
            o.z = acc[rr][2] + bv.z; o.w = acc[rr][3] + bv.w;
            if (!po) {
                o.x = fmaxf(o.x, 0.f); o.y = fmaxf(o.y, 0.f);
                o.z = fmaxf(o.z, 0.f); o.w = fmaxf(o.w, 0.f);
            }
            *(ushort4*)(h_all + (size_t)gm * NH + c0) = f4_to_bf4(o);
            float gp = o.x * av4.x + o.y * av4.y + o.z * av4.z + o.w * av4.w;
            gp += __shfl_xor(gp, 1); gp += __shfl_xor(gp, 2);
            gp += __shfl_xor(gp, 4); gp += __shfl_xor(gp, 8);
            if (tj == 0) gpart[w][tr * 2 + rr] = gp;
        }
    }
    __syncthreads();
    if (tid < 8)
        g_all[level * NM + row0 + tid] =
            gpart[0][tid] + gpart[1][tid] + gpart[2][tid] + gpart[3][tid];
}

// ---------- Final readout: 256 thr / 8 rows / 1024 blocks; col-split; padded LDS ----------
__global__ __launch_bounds__(256) void final_kernel(
    const u16* __restrict__ h_gnn, const float* __restrict__ po_feat,
    const float* __restrict__ Wg1, const float* __restrict__ bg1,
    const float* __restrict__ Wg2, const float* __restrict__ bg2,
    const float* __restrict__ Wo1, const float* __restrict__ bo1,
    const float* __restrict__ Wo2, const float* __restrict__ bo2,
    float* __restrict__ out)
{
    const int tid = threadIdx.x;
    const int w = tid >> 6, lane = tid & 63;
    const int row0 = blockIdx.x * 8;
    __shared__ __align__(16) float sx[8][516];   // stride 516 (mod32=4)
    __shared__ __align__(16) float sg[8][132];
    __shared__ float part[4][8];

    for (int x = tid; x < 8 * 32; x += 256) {
        int r = x >> 5, c = x & 31;
        uint4 hv = *(const uint4*)(h_gnn + (size_t)(row0 + r) * NH + c * 8);
        float2 p0 = bfp(hv.x), p1 = bfp(hv.y), p2 = bfp(hv.z), p3 = bfp(hv.w);
        float* dst = &sx[r][c * 8];
        dst[0] = p0.x; dst[1] = p0.y; dst[2] = p1.x; dst[3] = p1.y;
        dst[4] = p2.x; dst[5] = p2.y; dst[6] = p3.x; dst[7] = p3.y;
    }
    for (int x = tid; x < 8 * 128; x += 256) {
        int r = x >> 7, j = x & 127;
        sg[r][j] = lrelu(po_feat[row0 + r] * Wg1[j] + bg1[j]);
    }
    __syncthreads();

    // h_global = sg @ Wg2 + bg2 -> sx[:, 256:]; wave w -> cols [w*64, w*64+64); 4 grp x 2 rows
    {
        const int tj = lane & 15, tr = lane >> 4;
        const int c0 = w * 64 + tj * 4;
        float acc[2][4];
        #pragma unroll
        for (int a = 0; a < 2; ++a)
            #pragma unroll
            for (int b = 0; b < 4; ++b) acc[a][b] = 0.f;

        for (int k = 0; k < 128; k += 4) {
            float4 w0 = *(const float4*)(Wg2 + (size_t)(k + 0) * 256 + c0);
            float4 w1 = *(const float4*)(Wg2 + (size_t)(k + 1) * 256 + c0);
            float4 w2 = *(const float4*)(Wg2 + (size_t)(k + 2) * 256 + c0);
            float4 w3 = *(const float4*)(Wg2 + (size_t)(k + 3) * 256 + c0);
            #pragma unroll
            for (int rr = 0; rr < 2; ++rr) {
                float4 xv = *(const float4*)(&sg[tr * 2 + rr][k]);
                acc[rr][0] += xv.x * w0.x + xv.y * w1.x + xv.z * w2.x + xv.w * w3.x;
                acc[rr][1] += xv.x * w0.y + xv.y * w1.y + xv.z * w2.y + xv.w * w3.y;
                acc[rr][2] += xv.x * w0.z + xv.y * w1.z + xv.z * w2.z + xv.w * w3.z;
                acc[rr][3] += xv.x * w0.w + xv.y * w1.w + xv.z * w2.w + xv.w * w3.w;
            }
        }
        float4 bv = *(const float4*)(bg2 + c0);
        #pragma unroll
        for (int rr = 0; rr < 2; ++rr) {
            float4 o;
            o.x = acc[rr][0] + bv.x; o.y = acc[rr][1] + bv.y;
            o.z = acc[rr][2] + bv.z; o.w = acc[rr][3] + bv.w;
            *(float4*)(&sx[tr * 2 + rr][256 + c0]) = o;
        }
    }
    __syncthreads();

    // o1 = lrelu(sx @ Wo1 + bo1), K=512, col-split; fused partial dot with Wo2
    {
        const int tj = lane & 15, tr = lane >> 4;
        const int c0 = w * 64 + tj * 4;
        float acc[2][4];
        #pragma unroll
        for (int a = 0; a < 2; ++a)
            #pragma unroll
            for (int b = 0; b < 4; ++b) acc[a][b] = 0.f;

        for (int k = 0; k < 512; k += 4) {
            float4 w0 = *(const float4*)(Wo1 + (size_t)(k + 0) * 256 + c0);
            float4 w1 = *(const float4*)(Wo1 + (size_t)(k + 1) * 256 + c0);
            float4 w2 = *(const float4*)(Wo1 + (size_t)(k + 2) * 256 + c0);
            float4 w3 = *(const float4*)(Wo1 + (size_t)(k + 3) * 256 + c0);
            #pragma unroll
            for (int rr = 0; rr < 2; ++rr) {
                float4 xv = *(const float4*)(&sx[tr * 2 + rr][k]);
                acc[rr][0] += xv.x * w0.x + xv.y * w1.x + xv.z * w2.x + xv.w * w3.x;
                acc[rr][1] += xv.x * w0.y + xv.y * w1.y + xv.z * w2.y + xv.w * w3.y;
                acc[rr][2] += xv.x * w0.z + xv.y * w1.z + xv.z * w2.z + xv.w * w3.z;
                acc[rr][3] += xv.x * w0.w + xv.y * w1.w + xv.z * w2.w + xv.w * w3.w;
            }
        }
        float4 bv = *(const float4*)(bo1 + c0);
        float4 wv = *(const float4*)(Wo2 + c0);
        #pragma unroll
        for (int rr = 0; rr < 2; ++rr) {
            float pc = lrelu(acc[rr][0] + bv.x) * wv.x
                     + lrelu(acc[rr][1] + bv.y) * wv.y
                     + lrelu(acc[rr][2] + bv.z) * wv.z
                     + lrelu(acc[rr][3] + bv.w) * wv.w;
            pc += __shfl_xor(pc, 1); pc += __shfl_xor(pc, 2);
            pc += __shfl_xor(pc, 4); pc += __shfl_xor(pc, 8);
            if (tj == 0) part[w][tr * 2 + rr] = pc;
        }
    }
    __syncthreads();
    if (tid < 8)
        out[row0 + tid] = part[0][tid] + part[1][tid] + part[2][tid] + part[3][tid] + bo2[0];
}

extern "C" void kernel_launch(void* const* d_in, const int* in_sizes, int n_in,
                              void* d_out, int out_size, void* d_ws, size_t ws_size,
                              hipStream_t stream) {
    const float* W_pi1 = (const float*)d_in[0];
    const float* b_pi1 = (const float*)d_in[1];
    const float* W_pi2 = (const float*)d_in[2];
    const float* b_pi2 = (const float*)d_in[3];
    const float* W_p1  = (const float*)d_in[8];
    const float* b_p1  = (const float*)d_in[9];
    const float* W_p2  = (const float*)d_in[10];
    const float* W_n1  = (const float*)d_in[12];
    const float* b_n1  = (const float*)d_in[13];
    const float* W_n2  = (const float*)d_in[14];
    const float* b_n2  = (const float*)d_in[15];
    const float* W_g1  = (const float*)d_in[16];
    const float* b_g1  = (const float*)d_in[17];
    const float* W_g2  = (const float*)d_in[18];
    const float* b_g2  = (const float*)d_in[19];
    const float* W_o1  = (const float*)d_in[20];
    const float* b_o1  = (const float*)d_in[21];
    const float* W_o2  = (const float*)d_in[22];
    const float* b_o2  = (const float*)d_in[23];
    const float* av    = (const float*)d_in[24];
    const float* delay = (const float*)d_in[26];
    const float* bit_pos = (const float*)d_in[27];
    const float* po_feat = (const float*)d_in[28];
    const int*   is_po   = (const int*)d_in[29];
    const int*   nbr_idx = (const int*)d_in[30];

    u16*   h_all = (u16*)d_ws;                                // NN*NH bf16 (33.5 MB)
    float* g_all = (float*)(h_all + (size_t)NN * NH);         // NN floats
    float* neigh = g_all + NN;                                // NM*NH floats
    float* cst   = neigh + (size_t)NM * NH;                   // 64 floats
    float* out   = (float*)d_out;

    precomp_kernel<<<1, 32, 0, stream>>>(W_p2, av, cst);

    level0_kernel<<<NM / 32, 512, 0, stream>>>(delay, W_pi1, b_pi1, W_pi2, b_pi2,
                                               av, h_all, g_all);

    for (int level = 1; level < NL; ++level) {
        attn_kernel<<<NM / 4, 256, 0, stream>>>(h_all, g_all, bit_pos, nbr_idx,
                                                W_p1, b_p1, cst, neigh, level);
        mlp_n_kernel<<<NM / 8, 256, 0, stream>>>(neigh, W_n1, b_n1, W_n2, b_n2,
                                                 is_po, av, h_all, g_all, level);
    }

    final_kernel<<<NM / 8, 256, 0, stream>>>(h_all + (size_t)(NN - NM) * NH, po_feat,
                                             W_g1, b_g1, W_g2, b_g2,
                                             W_o1, b_o1, W_o2, b_o2, out);
}

// Round 11
// 508.331 us; speedup vs baseline: 2.6206x; 2.6206x over previous
//
#include <hip/hip_runtime.h>

#define NL 8
#define NM 8192
#define ND 16
#define NH 256
#define NF 64
#define NN (NL * NM)

typedef unsigned short u16;

__device__ __forceinline__ float lrelu(float x) { return fmaxf(x, 0.1f * x); }

// f32 -> bf16 round-to-nearest-even
__device__ __forceinline__ u16 f2bf(float x) {
    union { float f; unsigned int u; } v; v.f = x;
    unsigned int r = (v.u + 0x7FFFu + ((v.u >> 16) & 1u)) >> 16;
    return (u16)r;
}
__device__ __forceinline__ ushort4 f4_to_bf4(float4 o) {
    ushort4 r; r.x = f2bf(o.x); r.y = f2bf(o.y); r.z = f2bf(o.z); r.w = f2bf(o.w);
    return r;
}
// unpack 2 bf16 packed in a u32 -> 2 floats (low half = first element)
__device__ __forceinline__ float2 bfp(unsigned int u) {
    union { unsigned int u; float f; } lo, hi;
    lo.u = u << 16; hi.u = u & 0xFFFF0000u;
    return make_float2(lo.f, hi.f);
}

// ---------- precompute attention constants: cst[32..63] = W_p2 @ av_p ----------
__global__ void precomp_kernel(const float* __restrict__ W_p2, const float* __restrict__ av,
                               float* __restrict__ cst)
{
    int j = threadIdx.x;   // 32 threads
    float w = 0.f;
    for (int k = 0; k < 32; ++k) w += W_p2[j * 32 + k] * av[32 + k];
    cst[32 + j] = w;
}

// ---------- Level 0: h = mlp_pi(delay) (bf16 store) + g epilogue ----------
__global__ __launch_bounds__(512) void level0_kernel(
    const float* __restrict__ delay,
    const float* __restrict__ W1, const float* __restrict__ b1,
    const float* __restrict__ W2, const float* __restrict__ b2,
    const float* __restrict__ av,
    u16* __restrict__ h_all, float* __restrict__ g_all)
{
    const int tid = threadIdx.x;
    const int row0 = blockIdx.x * 32;
    __shared__ __align__(16) float sH[32][132];   // pad: stride 132 (mod32=4)

    for (int x = tid; x < 32 * 128; x += 512) {
        int r = x >> 7, j = x & 127;
        sH[r][j] = lrelu(delay[row0 + r] * W1[j] + b1[j]);
    }
    __syncthreads();

    const int tj = tid & 63, tr = tid >> 6;
    const float4 av4 = *(const float4*)(av + 64 + tj * 4);
    float acc[4][4];
    #pragma unroll
    for (int a = 0; a < 4; ++a)
        #pragma unroll
        for (int b = 0; b < 4; ++b) acc[a][b] = 0.f;

    for (int k = 0; k < 128; k += 4) {
        float4 w0 = *(const float4*)(W2 + (size_t)(k + 0) * 256 + tj * 4);
        float4 w1 = *(const float4*)(W2 + (size_t)(k + 1) * 256 + tj * 4);
        float4 w2 = *(const float4*)(W2 + (size_t)(k + 2) * 256 + tj * 4);
        float4 w3 = *(const float4*)(W2 + (size_t)(k + 3) * 256 + tj * 4);
        #pragma unroll
        for (int rr = 0; rr < 4; ++rr) {
            float4 xv = *(const float4*)(&sH[tr * 4 + rr][k]);
            acc[rr][0] += xv.x * w0.x + xv.y * w1.x + xv.z * w2.x + xv.w * w3.x;
            acc[rr][1] += xv.x * w0.y + xv.y * w1.y + xv.z * w2.y + xv.w * w3.y;
            acc[rr][2] += xv.x * w0.z + xv.y * w1.z + xv.z * w2.z + xv.w * w3.z;
            acc[rr][3] += xv.x * w0.w + xv.y * w1.w + xv.z * w2.w + xv.w * w3.w;
        }
    }
    float4 bv = *(const float4*)(b2 + tj * 4);
    #pragma unroll
    for (int rr = 0; rr < 4; ++rr) {
        const int row = row0 + tr * 4 + rr;
        float4 o;
        o.x = acc[rr][0] + bv.x; o.y = acc[rr][1] + bv.y;
        o.z = acc[rr][2] + bv.z; o.w = acc[rr][3] + bv.w;
        *(ushort4*)(h_all + (size_t)row * NH + tj * 4) = f4_to_bf4(o);
        float gp = o.x * av4.x + o.y * av4.y + o.z * av4.z + o.w * av4.w;
        #pragma unroll
        for (int off = 1; off < 64; off <<= 1) gp += __shfl_xor(gp, off);
        if (tj == 0) g_all[row] = gp;
    }
}

// ---------- Attention: 1 wave per m; g-gather alpha + single 16B-load streamed pass ----------
__global__ __launch_bounds__(256) void attn_kernel(
    const u16* __restrict__ h_all, const float* __restrict__ g_all,
    const float* __restrict__ bit_pos, const int* __restrict__ nbr_idx,
    const float* __restrict__ W_p1, const float* __restrict__ b_p1,
    const float* __restrict__ cst,
    float* __restrict__ neigh, int level)
{
    const int w = threadIdx.x >> 6, lane = threadIdx.x & 63;
    const int m = blockIdx.x * 4 + w;
    const int d = lane & 15, jj = lane >> 4;
    const size_t ebase = ((size_t)(level - 1) * NM + m) * ND;

    const int   idx = nbr_idx[ebase + d];
    const float bp  = bit_pos[ebase + d];

    // collapsed mlp_p: 4 jj-groups each cover 8 of the 32 hidden units
    float ep = 0.f;
    #pragma unroll
    for (int t = 0; t < 8; ++t) {
        int j = jj * 8 + t;
        ep += cst[32 + j] * lrelu(bp * W_p1[j] + b_p1[j]);
    }
    ep += __shfl_xor(ep, 16);
    ep += __shfl_xor(ep, 32);

    // e = e_h + e_p  (e_t is constant over d -> cancels in softmax)
    float e = g_all[idx] + ep;
    float mx = e;
    #pragma unroll
    for (int off = 1; off < 16; off <<= 1) mx = fmaxf(mx, __shfl_xor(mx, off));
    float wexp = __expf(e - mx);
    float s = wexp;
    #pragma unroll
    for (int off = 1; off < 16; off <<= 1) s += __shfl_xor(s, off);
    const float alpha = wexp / s;

    // streamed weighted sum: lane = rh*32 + cl; 16B (8 bf16) per lane, 2 rows/step
    const int rh = lane >> 5, cl = lane & 31;
    float4 a0 = make_float4(0.f, 0.f, 0.f, 0.f);
    float4 a1 = make_float4(0.f, 0.f, 0.f, 0.f);
    #pragma unroll
    for (int t = 0; t < 8; ++t) {
        const int d2 = t * 2 + rh;
        float a = __shfl(alpha, d2);
        int   r = __shfl(idx, d2);
        uint4 hv = *(const uint4*)(h_all + (size_t)r * NH + cl * 8);
        float2 p0 = bfp(hv.x), p1 = bfp(hv.y), p2 = bfp(hv.z), p3 = bfp(hv.w);
        a0.x += a * p0.x; a0.y += a * p0.y; a0.z += a * p1.x; a0.w += a * p1.y;
        a1.x += a * p2.x; a1.y += a * p2.y; a1.z += a * p3.x; a1.w += a * p3.y;
    }
    // combine the two row-halves
    a0.x += __shfl_xor(a0.x, 32); a0.y += __shfl_xor(a0.y, 32);
    a0.z += __shfl_xor(a0.z, 32); a0.w += __shfl_xor(a0.w, 32);
    a1.x += __shfl_xor(a1.x, 32); a1.y += __shfl_xor(a1.y, 32);
    a1.z += __shfl_xor(a1.z, 32); a1.w += __shfl_xor(a1.w, 32);

    float4 outv = (rh == 0) ? a0 : a1;
    *(float4*)(neigh + (size_t)m * NH + cl * 8 + rh * 4) = outv;
}

// ---------- Neighborhood MLP: 256 thr / 8 rows / 1024 blocks; unroll pinned ----------
__global__ __launch_bounds__(256, 4) void mlp_n_kernel(
    const float* __restrict__ neigh,
    const float* __restrict__ W1, const float* __restrict__ b1,
    const float* __restrict__ W2, const float* __restrict__ b2,
    const int* __restrict__ is_po, const float* __restrict__ av,
    u16* __restrict__ h_all, float* __restrict__ g_all, int level)
{
    const int tid = threadIdx.x;
    const int w = tid >> 6, lane = tid & 63;
    const int row0 = blockIdx.x * 8;
    __shared__ __align__(16) float sX[8][NH + 4];   // stride 260 (mod32=4)
    __shared__ __align__(16) float sH[8][132];      // stride 132 (mod32=4)
    __shared__ float gpart[4][8];

    for (int x = tid; x < 8 * 64; x += 256) {
        int r = x >> 6, c = x & 63;
        *(float4*)(&sX[r][c * 4]) = *(const float4*)(neigh + (size_t)(row0 + r) * NH + c * 4);
    }
    __syncthreads();

    // layer 1: (8x256)@(256x128); wave w -> cols [w*32, w*32+32); 8 grp x 1 row
    {
        const int tj = lane & 7, tr = lane >> 3;
        const int c0 = w * 32 + tj * 4;
        float acc[4] = {0.f, 0.f, 0.f, 0.f};

        #pragma unroll 2
        for (int k = 0; k < NH; k += 4) {
            float4 w0 = *(const float4*)(W1 + (size_t)(k + 0) * 128 + c0);
            float4 w1 = *(const float4*)(W1 + (size_t)(k + 1) * 128 + c0);
            float4 w2 = *(const float4*)(W1 + (size_t)(k + 2) * 128 + c0);
            float4 w3 = *(const float4*)(W1 + (size_t)(k + 3) * 128 + c0);
            float4 xv = *(const float4*)(&sX[tr][k]);
            acc[0] += xv.x * w0.x + xv.y * w1.x + xv.z * w2.x + xv.w * w3.x;
            acc[1] += xv.x * w0.y + xv.y * w1.y + xv.z * w2.y + xv.w * w3.y;
            acc[2] += xv.x * w0.z + xv.y * w1.z + xv.z * w2.z + xv.w * w3.z;
            acc[3] += xv.x * w0.w + xv.y * w1.w + xv.z * w2.w + xv.w * w3.w;
        }
        float4 bv = *(const float4*)(b1 + c0);
        float4 o;
        o.x = lrelu(acc[0] + bv.x); o.y = lrelu(acc[1] + bv.y);
        o.z = lrelu(acc[2] + bv.z); o.w = lrelu(acc[3] + bv.w);
        *(float4*)(&sH[tr][c0]) = o;
    }
    __syncthreads();

    // layer 2: (8x128)@(128x256); wave w -> cols [w*64, w*64+64); 4 grp x 2 rows
    {
        const int tj = lane & 15, tr = lane >> 4;
        const int c0 = w * 64 + tj * 4;
        const float4 av4 = *(const float4*)(av + 64 + c0);
        float acc[2][4];
        #pragma unroll
        for (int a = 0; a < 2; ++a)
            #pragma unroll
            for (int b = 0; b < 4; ++b) acc[a][b] = 0.f;

        #pragma unroll 2
        for (int k = 0; k < 128; k += 4) {
            float4 w0 = *(const float4*)(W2 + (size_t)(k + 0) * 256 + c0);
            float4 w1 = *(const float4*)(W2 + (size_t)(k + 1) * 256 + c0);
            float4 w2 = *(const float4*)(W2 + (size_t)(k + 2) * 256 + c0);
            float4 w3 = *(const float4*)(W2 + (size_t)(k + 3) * 256 + c0);
            #pragma unroll
            for (int rr = 0; rr < 2; ++rr) {
                float4 xv = *(const float4*)(&sH[tr * 2 + rr][k]);
                acc[rr][0] += xv.x * w0.x + xv.y * w1.x + xv.z * w2.x + xv.w * w3.x;
                acc[rr][1] += xv.x * w0.y + xv.y * w1.y + xv.z * w2.y + xv.w * w3.y;
                acc[rr][2] += xv.x * w0.z + xv.y * w1.z + xv.z * w2.z + xv.w * w3.z;
                acc[rr][3] += xv.x * w0.w + xv.y * w1.w + xv.z * w2.w + xv.w * w3.w;
            }
        }
        float4 bv = *(const float4*)(b2 + c0);
        #pragma unroll
        for (int rr = 0; rr < 2; ++rr) {
            const int gm = level * NM + row0 + tr * 2 + rr;
            bool po = (is_po[gm] == 1);
            float4 o;
            o.x = acc[rr][0] + bv.x; o.y = acc[rr][1] + bv.y;
            o.z = acc[rr][2] + bv.z; o.w = acc[rr][3] + bv.w;
            if (!po) {
                o.x = fmaxf(o.x, 0.f); o.y = fmaxf(o.y, 0.f);
                o.z = fmaxf(o.z, 0.f); o.w = fmaxf(o.w, 0.f);
            }
            *(ushort4*)(h_all + (size_t)gm * NH + c0) = f4_to_bf4(o);
            float gp = o.x * av4.x + o.y * av4.y + o.z * av4.z + o.w * av4.w;
            gp += __shfl_xor(gp, 1); gp += __shfl_xor(gp, 2);
            gp += __shfl_xor(gp, 4); gp += __shfl_xor(gp, 8);
            if (tj == 0) gpart[w][tr * 2 + rr] = gp;
        }
    }
    __syncthreads();
    if (tid < 8)
        g_all[level * NM + row0 + tid] =
            gpart[0][tid] + gpart[1][tid] + gpart[2][tid] + gpart[3][tid];
}

// ---------- Final readout: 256 thr / 8 rows / 1024 blocks; unroll pinned ----------
__global__ __launch_bounds__(256, 4) void final_kernel(
    const u16* __restrict__ h_gnn, const float* __restrict__ po_feat,
    const float* __restrict__ Wg1, const float* __restrict__ bg1,
    const float* __restrict__ Wg2, const float* __restrict__ bg2,
    const float* __restrict__ Wo1, const float* __restrict__ bo1,
    const float* __restrict__ Wo2, const float* __restrict__ bo2,
    float* __restrict__ out)
{
    const int tid = threadIdx.x;
    const int w = tid >> 6, lane = tid & 63;
    const int row0 = blockIdx.x * 8;
    __shared__ __align__(16) float sx[8][516];   // stride 516 (mod32=4)
    __shared__ __align__(16) float sg[8][132];
    __shared__ float part[4][8];

    for (int x = tid; x < 8 * 32; x += 256) {
        int r = x >> 5, c = x & 31;
        uint4 hv = *(const uint4*)(h_gnn + (size_t)(row0 + r) * NH + c * 8);
        float2 p0 = bfp(hv.x), p1 = bfp(hv.y), p2 = bfp(hv.z), p3 = bfp(hv.w);
        float* dst = &sx[r][c * 8];
        dst[0] = p0.x; dst[1] = p0.y; dst[2] = p1.x; dst[3] = p1.y;
        dst[4] = p2.x; dst[5] = p2.y; dst[6] = p3.x; dst[7] = p3.y;
    }
    for (int x = tid; x < 8 * 128; x += 256) {
        int r = x >> 7, j = x & 127;
        sg[r][j] = lrelu(po_feat[row0 + r] * Wg1[j] + bg1[j]);
    }
    __syncthreads();

    // h_global = sg @ Wg2 + bg2 -> sx[:, 256:]; wave w -> cols [w*64, w*64+64); 4 grp x 2 rows
    {
        const int tj = lane & 15, tr = lane >> 4;
        const int c0 = w * 64 + tj * 4;
        float acc[2][4];
        #pragma unroll
        for (int a = 0; a < 2; ++a)
            #pragma unroll
            for (int b = 0; b < 4; ++b) acc[a][b] = 0.f;

        #pragma unroll 2
        for (int k = 0; k < 128; k += 4) {
            float4 w0 = *(const float4*)(Wg2 + (size_t)(k + 0) * 256 + c0);
            float4 w1 = *(const float4*)(Wg2 + (size_t)(k + 1) * 256 + c0);
            float4 w2 = *(const float4*)(Wg2 + (size_t)(k + 2) * 256 + c0);
            float4 w3 = *(const float4*)(Wg2 + (size_t)(k + 3) * 256 + c0);
            #pragma unroll
            for (int rr = 0; rr < 2; ++rr) {
                float4 xv = *(const float4*)(&sg[tr * 2 + rr][k]);
                acc[rr][0] += xv.x * w0.x + xv.y * w1.x + xv.z * w2.x + xv.w * w3.x;
                acc[rr][1] += xv.x * w0.y + xv.y * w1.y + xv.z * w2.y + xv.w * w3.y;
                acc[rr][2] += xv.x * w0.z + xv.y * w1.z + xv.z * w2.z + xv.w * w3.z;
                acc[rr][3] += xv.x * w0.w + xv.y * w1.w + xv.z * w2.w + xv.w * w3.w;
            }
        }
        float4 bv = *(const float4*)(bg2 + c0);
        #pragma unroll
        for (int rr = 0; rr < 2; ++rr) {
            float4 o;
            o.x = acc[rr][0] + bv.x; o.y = acc[rr][1] + bv.y;
            o.z = acc[rr][2] + bv.z; o.w = acc[rr][3] + bv.w;
            *(float4*)(&sx[tr * 2 + rr][256 + c0]) = o;
        }
    }
    __syncthreads();

    // o1 = lrelu(sx @ Wo1 + bo1), K=512, col-split; fused partial dot with Wo2
    {
        const int tj = lane & 15, tr = lane >> 4;
        const int c0 = w * 64 + tj * 4;
        float acc[2][4];
        #pragma unroll
        for (int a = 0; a < 2; ++a)
            #pragma unroll
            for (int b = 0; b < 4; ++b) acc[a][b] = 0.f;

        #pragma unroll 2
        for (int k = 0; k < 512; k += 4) {
            float4 w0 = *(const float4*)(Wo1 + (size_t)(k + 0) * 256 + c0);
            float4 w1 = *(const float4*)(Wo1 + (size_t)(k + 1) * 256 + c0);
            float4 w2 = *(const float4*)(Wo1 + (size_t)(k + 2) * 256 + c0);
            float4 w3 = *(const float4*)(Wo1 + (size_t)(k + 3) * 256 + c0);
            #pragma unroll
            for (int rr = 0; rr < 2; ++rr) {
                float4 xv = *(const float4*)(&sx[tr * 2 + rr][k]);
                acc[rr][0] += xv.x * w0.x + xv.y * w1.x + xv.z * w2.x + xv.w * w3.x;
                acc[rr][1] += xv.x * w0.y + xv.y * w1.y + xv.z * w2.y + xv.w * w3.y;
                acc[rr][2] += xv.x * w0.z + xv.y * w1.z + xv.z * w2.z + xv.w * w3.z;
                acc[rr][3] += xv.x * w0.w + xv.y * w1.w + xv.z * w2.w + xv.w * w3.w;
            }
        }
        float4 bv = *(const float4*)(bo1 + c0);
        float4 wv = *(const float4*)(Wo2 + c0);
        #pragma unroll
        for (int rr = 0; rr < 2; ++rr) {
            float pc = lrelu(acc[rr][0] + bv.x) * wv.x
                     + lrelu(acc[rr][1] + bv.y) * wv.y
                     + lrelu(acc[rr][2] + bv.z) * wv.z
                     + lrelu(acc[rr][3] + bv.w) * wv.w;
            pc += __shfl_xor(pc, 1); pc += __shfl_xor(pc, 2);
            pc += __shfl_xor(pc, 4); pc += __shfl_xor(pc, 8);
            if (tj == 0) part[w][tr * 2 + rr] = pc;
        }
    }
    __syncthreads();
    if (tid < 8)
        out[row0 + tid] = part[0][tid] + part[1][tid] + part[2][tid] + part[3][tid] + bo2[0];
}

extern "C" void kernel_launch(void* const* d_in, const int* in_sizes, int n_in,
                              void* d_out, int out_size, void* d_ws, size_t ws_size,
                              hipStream_t stream) {
    const float* W_pi1 = (const float*)d_in[0];
    const float* b_pi1 = (const float*)d_in[1];
    const float* W_pi2 = (const float*)d_in[2];
    const float* b_pi2 = (const float*)d_in[3];
    const float* W_p1  = (const float*)d_in[8];
    const float* b_p1  = (const float*)d_in[9];
    const float* W_p2  = (const float*)d_in[10];
    const float* W_n1  = (const float*)d_in[12];
    const float* b_n1  = (const float*)d_in[13];
    const float* W_n2  = (const float*)d_in[14];
    const float* b_n2  = (const float*)d_in[15];
    const float* W_g1  = (const float*)d_in[16];
    const float* b_g1  = (const float*)d_in[17];
    const float* W_g2  = (const float*)d_in[18];
    const float* b_g2  = (const float*)d_in[19];
    const float* W_o1  = (const float*)d_in[20];
    const float* b_o1  = (const float*)d_in[21];
    const float* W_o2  = (const float*)d_in[22];
    const float* b_o2  = (const float*)d_in[23];
    const float* av    = (const float*)d_in[24];
    const float* delay = (const float*)d_in[26];
    const float* bit_pos = (const float*)d_in[27];
    const float* po_feat = (const float*)d_in[28];
    const int*   is_po   = (const int*)d_in[29];
    const int*   nbr_idx = (const int*)d_in[30];

    u16*   h_all = (u16*)d_ws;                                // NN*NH bf16 (33.5 MB)
    float* g_all = (float*)(h_all + (size_t)NN * NH);         // NN floats
    float* neigh = g_all + NN;                                // NM*NH floats
    float* cst   = neigh + (size_t)NM * NH;                   // 64 floats
    float* out   = (float*)d_out;

    precomp_kernel<<<1, 32, 0, stream>>>(W_p2, av, cst);

    level0_kernel<<<NM / 32, 512, 0, stream>>>(delay, W_pi1, b_pi1, W_pi2, b_pi2,
                                               av, h_all, g_all);

    for (int level = 1; level < NL; ++level) {
        attn_kernel<<<NM / 4, 256, 0, stream>>>(h_all, g_all, bit_pos, nbr_idx,
                                                W_p1, b_p1, cst, neigh, level);
        mlp_n_kernel<<<NM / 8, 256, 0, stream>>>(neigh, W_n1, b_n1, W_n2, b_n2,
                                                 is_po, av, h_all, g_all, level);
    }

    final_kernel<<<NM / 8, 256, 0, stream>>>(h_all + (size_t)(NN - NM) * NH, po_feat,
                                             W_g1, b_g1, W_g2, b_g2,
                                             W_o1, b_o1, W_o2, b_o2, out);
}

// Round 12
// 434.539 us; speedup vs baseline: 3.0656x; 1.1698x over previous
//
#include <hip/hip_runtime.h>

#define NL 8
#define NM 8192
#define ND 16
#define NH 256
#define NF 64
#define NN (NL * NM)

typedef unsigned short u16;

__device__ __forceinline__ float lrelu(float x) { return fmaxf(x, 0.1f * x); }

__device__ __forceinline__ u16 f2bf(float x) {
    union { float f; unsigned int u; } v; v.f = x;
    unsigned int r = (v.u + 0x7FFFu + ((v.u >> 16) & 1u)) >> 16;
    return (u16)r;
}
__device__ __forceinline__ ushort4 f4_to_bf4(float4 o) {
    ushort4 r; r.x = f2bf(o.x); r.y = f2bf(o.y); r.z = f2bf(o.z); r.w = f2bf(o.w);
    return r;
}
__device__ __forceinline__ float2 bfp(unsigned int u) {
    union { unsigned int u; float f; } lo, hi;
    lo.u = u << 16; hi.u = u & 0xFFFF0000u;
    return make_float2(lo.f, hi.f);
}

// ---------- precompute attention constants: cst[32..63] = W_p2 @ av_p ----------
__global__ void precomp_kernel(const float* __restrict__ W_p2, const float* __restrict__ av,
                               float* __restrict__ cst)
{
    int j = threadIdx.x;   // 32 threads
    float w = 0.f;
    for (int k = 0; k < 32; ++k) w += W_p2[j * 32 + k] * av[32 + k];
    cst[32 + j] = w;
}

// ---------- Level 0: h = mlp_pi(delay) (bf16 store) + g epilogue ----------
__global__ __launch_bounds__(512) void level0_kernel(
    const float* __restrict__ delay,
    const float* __restrict__ W1, const float* __restrict__ b1,
    const float* __restrict__ W2, const float* __restrict__ b2,
    const float* __restrict__ av,
    u16* __restrict__ h_all, float* __restrict__ g_all)
{
    const int tid = threadIdx.x;
    const int row0 = blockIdx.x * 32;
    __shared__ __align__(16) float sH[32][132];

    for (int x = tid; x < 32 * 128; x += 512) {
        int r = x >> 7, j = x & 127;
        sH[r][j] = lrelu(delay[row0 + r] * W1[j] + b1[j]);
    }
    __syncthreads();

    const int tj = tid & 63, tr = tid >> 6;
    const float4 av4 = *(const float4*)(av + 64 + tj * 4);
    float acc[4][4];
    #pragma unroll
    for (int a = 0; a < 4; ++a)
        #pragma unroll
        for (int b = 0; b < 4; ++b) acc[a][b] = 0.f;

    for (int k = 0; k < 128; k += 4) {
        float4 w0 = *(const float4*)(W2 + (size_t)(k + 0) * 256 + tj * 4);
        float4 w1 = *(const float4*)(W2 + (size_t)(k + 1) * 256 + tj * 4);
        float4 w2 = *(const float4*)(W2 + (size_t)(k + 2) * 256 + tj * 4);
        float4 w3 = *(const float4*)(W2 + (size_t)(k + 3) * 256 + tj * 4);
        #pragma unroll
        for (int rr = 0; rr < 4; ++rr) {
            float4 xv = *(const float4*)(&sH[tr * 4 + rr][k]);
            acc[rr][0] += xv.x * w0.x + xv.y * w1.x + xv.z * w2.x + xv.w * w3.x;
            acc[rr][1] += xv.x * w0.y + xv.y * w1.y + xv.z * w2.y + xv.w * w3.y;
            acc[rr][2] += xv.x * w0.z + xv.y * w1.z + xv.z * w2.z + xv.w * w3.z;
            acc[rr][3] += xv.x * w0.w + xv.y * w1.w + xv.z * w2.w + xv.w * w3.w;
        }
    }
    float4 bv = *(const float4*)(b2 + tj * 4);
    #pragma unroll
    for (int rr = 0; rr < 4; ++rr) {
        const int row = row0 + tr * 4 + rr;
        float4 o;
        o.x = acc[rr][0] + bv.x; o.y = acc[rr][1] + bv.y;
        o.z = acc[rr][2] + bv.z; o.w = acc[rr][3] + bv.w;
        *(ushort4*)(h_all + (size_t)row * NH + tj * 4) = f4_to_bf4(o);
        float gp = o.x * av4.x + o.y * av4.y + o.z * av4.z + o.w * av4.w;
        #pragma unroll
        for (int off = 1; off < 64; off <<= 1) gp += __shfl_xor(gp, off);
        if (tj == 0) g_all[row] = gp;
    }
}

// ---------- Fused per-level: streamed attention (reg->LDS) + unroll-pinned mlp_n ----------
// 256 thr (4 waves), 8 rows/block, 1024 blocks. Wave w: attention for rows w*2, w*2+1.
__global__ __launch_bounds__(256, 4) void level_kernel(
    const u16* __restrict__ h_all, const float* __restrict__ g_all,
    const float* __restrict__ bit_pos, const int* __restrict__ nbr_idx,
    const float* __restrict__ W_p1, const float* __restrict__ b_p1,
    const float* __restrict__ cst,
    const float* __restrict__ W1, const float* __restrict__ b1,
    const float* __restrict__ W2, const float* __restrict__ b2,
    const int* __restrict__ is_po, const float* __restrict__ av,
    u16* __restrict__ h_out, float* __restrict__ g_out, int level)
{
    const int tid = threadIdx.x;
    const int w = tid >> 6, lane = tid & 63;
    const int row0 = blockIdx.x * 8;
    __shared__ __align__(16) float sX[8][NH + 4];   // stride 260 (mod32=4)
    __shared__ __align__(16) float sH[8][132];      // stride 132 (mod32=4)
    __shared__ float gpart[4][8];

    // ---- Phase A: attention, 2 rows per wave (one at a time to cap VGPR) ----
    #pragma unroll 1
    for (int mi = 0; mi < 2; ++mi) {
        const int mrow = w * 2 + mi;
        const int m = row0 + mrow;
        const int d = lane & 15, jj = lane >> 4;
        const size_t ebase = ((size_t)(level - 1) * NM + m) * ND;

        const int   idx = nbr_idx[ebase + d];
        const float bp  = bit_pos[ebase + d];

        // collapsed mlp_p: 4 jj-groups each cover 8 of the 32 hidden units
        float ep = 0.f;
        #pragma unroll
        for (int t = 0; t < 8; ++t) {
            int j = jj * 8 + t;
            ep += cst[32 + j] * lrelu(bp * W_p1[j] + b_p1[j]);
        }
        ep += __shfl_xor(ep, 16);
        ep += __shfl_xor(ep, 32);

        // e = e_h + e_p  (e_t constant over d -> cancels in softmax)
        float e = g_all[idx] + ep;
        float mx = e;
        #pragma unroll
        for (int off = 1; off < 16; off <<= 1) mx = fmaxf(mx, __shfl_xor(mx, off));
        float wexp = __expf(e - mx);
        float s = wexp;
        #pragma unroll
        for (int off = 1; off < 16; off <<= 1) s += __shfl_xor(s, off);
        const float alpha = wexp / s;

        // streamed weighted sum: lane = rh*32 + cl; 16B (8 bf16) per lane, 2 rows/step
        const int rh = lane >> 5, cl = lane & 31;
        float4 a0 = make_float4(0.f, 0.f, 0.f, 0.f);
        float4 a1 = make_float4(0.f, 0.f, 0.f, 0.f);
        #pragma unroll
        for (int t = 0; t < 8; ++t) {
            const int d2 = t * 2 + rh;
            float a = __shfl(alpha, d2);
            int   r = __shfl(idx, d2);
            uint4 hv = *(const uint4*)(h_all + (size_t)r * NH + cl * 8);
            float2 p0 = bfp(hv.x), p1 = bfp(hv.y), p2 = bfp(hv.z), p3 = bfp(hv.w);
            a0.x += a * p0.x; a0.y += a * p0.y; a0.z += a * p1.x; a0.w += a * p1.y;
            a1.x += a * p2.x; a1.y += a * p2.y; a1.z += a * p3.x; a1.w += a * p3.y;
        }
        a0.x += __shfl_xor(a0.x, 32); a0.y += __shfl_xor(a0.y, 32);
        a0.z += __shfl_xor(a0.z, 32); a0.w += __shfl_xor(a0.w, 32);
        a1.x += __shfl_xor(a1.x, 32); a1.y += __shfl_xor(a1.y, 32);
        a1.z += __shfl_xor(a1.z, 32); a1.w += __shfl_xor(a1.w, 32);

        float4 outv = (rh == 0) ? a0 : a1;
        *(float4*)(&sX[mrow][cl * 8 + rh * 4]) = outv;
    }
    __syncthreads();

    // ---- Phase B layer 1: (8x256)@(256x128); wave w -> cols [w*32, w*32+32) ----
    {
        const int tj = lane & 7, tr = lane >> 3;
        const int c0 = w * 32 + tj * 4;
        float acc[4] = {0.f, 0.f, 0.f, 0.f};

        #pragma unroll 2
        for (int k = 0; k < NH; k += 4) {
            float4 w0 = *(const float4*)(W1 + (size_t)(k + 0) * 128 + c0);
            float4 w1 = *(const float4*)(W1 + (size_t)(k + 1) * 128 + c0);
            float4 w2 = *(const float4*)(W1 + (size_t)(k + 2) * 128 + c0);
            float4 w3 = *(const float4*)(W1 + (size_t)(k + 3) * 128 + c0);
            float4 xv = *(const float4*)(&sX[tr][k]);
            acc[0] += xv.x * w0.x + xv.y * w1.x + xv.z * w2.x + xv.w * w3.x;
            acc[1] += xv.x * w0.y + xv.y * w1.y + xv.z * w2.y + xv.w * w3.y;
            acc[2] += xv.x * w0.z + xv.y * w1.z + xv.z * w2.z + xv.w * w3.z;
            acc[3] += xv.x * w0.w + xv.y * w1.w + xv.z * w2.w + xv.w * w3.w;
        }
        float4 bv = *(const float4*)(b1 + c0);
        float4 o;
        o.x = lrelu(acc[0] + bv.x); o.y = lrelu(acc[1] + bv.y);
        o.z = lrelu(acc[2] + bv.z); o.w = lrelu(acc[3] + bv.w);
        *(float4*)(&sH[tr][c0]) = o;
    }
    __syncthreads();

    // ---- Phase B layer 2: (8x128)@(128x256); wave w -> cols [w*64, w*64+64) ----
    {
        const int tj = lane & 15, tr = lane >> 4;
        const int c0 = w * 64 + tj * 4;
        const float4 av4 = *(const float4*)(av + 64 + c0);
        float acc[2][4];
        #pragma unroll
        for (int a = 0; a < 2; ++a)
            #pragma unroll
            for (int b = 0; b < 4; ++b) acc[a][b] = 0.f;

        #pragma unroll 2
        for (int k = 0; k < 128; k += 4) {
            float4 w0 = *(const float4*)(W2 + (size_t)(k + 0) * 256 + c0);
            float4 w1 = *(const float4*)(W2 + (size_t)(k + 1) * 256 + c0);
            float4 w2 = *(const float4*)(W2 + (size_t)(k + 2) * 256 + c0);
            float4 w3 = *(const float4*)(W2 + (size_t)(k + 3) * 256 + c0);
            #pragma unroll
            for (int rr = 0; rr < 2; ++rr) {
                float4 xv = *(const float4*)(&sH[tr * 2 + rr][k]);
                acc[rr][0] += xv.x * w0.x + xv.y * w1.x + xv.z * w2.x + xv.w * w3.x;
                acc[rr][1] += xv.x * w0.y + xv.y * w1.y + xv.z * w2.y + xv.w * w3.y;
                acc[rr][2] += xv.x * w0.z + xv.y * w1.z + xv.z * w2.z + xv.w * w3.z;
                acc[rr][3] += xv.x * w0.w + xv.y * w1.w + xv.z * w2.w + xv.w * w3.w;
            }
        }
        float4 bv = *(const float4*)(b2 + c0);
        #pragma unroll
        for (int rr = 0; rr < 2; ++rr) {
            const int gm = level * NM + row0 + tr * 2 + rr;
            bool po = (is_po[gm] == 1);
            float4 o;
            o.x = acc[rr][0] + bv.x; o.y = acc[rr][1] + bv.y;
            o.z = acc[rr][2] + bv.z; o.w = acc[rr][3] + bv.w;
            if (!po) {
                o.x = fmaxf(o.x, 0.f); o.y = fmaxf(o.y, 0.f);
                o.z = fmaxf(o.z, 0.f); o.w = fmaxf(o.w, 0.f);
            }
            *(ushort4*)(h_out + (size_t)gm * NH + c0) = f4_to_bf4(o);
            float gp = o.x * av4.x + o.y * av4.y + o.z * av4.z + o.w * av4.w;
            gp += __shfl_xor(gp, 1); gp += __shfl_xor(gp, 2);
            gp += __shfl_xor(gp, 4); gp += __shfl_xor(gp, 8);
            if (tj == 0) gpart[w][tr * 2 + rr] = gp;
        }
    }
    __syncthreads();
    if (tid < 8)
        g_out[level * NM + row0 + tid] =
            gpart[0][tid] + gpart[1][tid] + gpart[2][tid] + gpart[3][tid];
}

// ---------- Final readout (round-9 proven): 256 thr / 16 rows; col-split; padded LDS ----------
__global__ __launch_bounds__(256) void final_kernel(
    const u16* __restrict__ h_gnn, const float* __restrict__ po_feat,
    const float* __restrict__ Wg1, const float* __restrict__ bg1,
    const float* __restrict__ Wg2, const float* __restrict__ bg2,
    const float* __restrict__ Wo1, const float* __restrict__ bo1,
    const float* __restrict__ Wo2, const float* __restrict__ bo2,
    float* __restrict__ out)
{
    const int tid = threadIdx.x;
    const int w = tid >> 6, lane = tid & 63;
    const int row0 = blockIdx.x * 16;
    __shared__ __align__(16) float sx[16][516];
    __shared__ __align__(16) float sg[16][132];
    __shared__ float part[4][16];

    for (int x = tid; x < 16 * 32; x += 256) {
        int r = x >> 5, c = x & 31;
        uint4 hv = *(const uint4*)(h_gnn + (size_t)(row0 + r) * NH + c * 8);
        float2 p0 = bfp(hv.x), p1 = bfp(hv.y), p2 = bfp(hv.z), p3 = bfp(hv.w);
        float* dst = &sx[r][c * 8];
        dst[0] = p0.x; dst[1] = p0.y; dst[2] = p1.x; dst[3] = p1.y;
        dst[4] = p2.x; dst[5] = p2.y; dst[6] = p3.x; dst[7] = p3.y;
    }
    for (int x = tid; x < 16 * 128; x += 256) {
        int r = x >> 7, j = x & 127;
        sg[r][j] = lrelu(po_feat[row0 + r] * Wg1[j] + bg1[j]);
    }
    __syncthreads();

    {
        const int tj = lane & 15, tr = lane >> 4;
        const int c0 = w * 64 + tj * 4;
        float acc[4][4];
        #pragma unroll
        for (int a = 0; a < 4; ++a)
            #pragma unroll
            for (int b = 0; b < 4; ++b) acc[a][b] = 0.f;

        for (int k = 0; k < 128; k += 4) {
            float4 w0 = *(const float4*)(Wg2 + (size_t)(k + 0) * 256 + c0);
            float4 w1 = *(const float4*)(Wg2 + (size_t)(k + 1) * 256 + c0);
            float4 w2 = *(const float4*)(Wg2 + (size_t)(k + 2) * 256 + c0);
            float4 w3 = *(const float4*)(Wg2 + (size_t)(k + 3) * 256 + c0);
            #pragma unroll
            for (int rr = 0; rr < 4; ++rr) {
                float4 xv = *(const float4*)(&sg[tr * 4 + rr][k]);
                acc[rr][0] += xv.x * w0.x + xv.y * w1.x + xv.z * w2.x + xv.w * w3.x;
                acc[rr][1] += xv.x * w0.y + xv.y * w1.y + xv.z * w2.y + xv.w * w3.y;
                acc[rr][2] += xv.x * w0.z + xv.y * w1.z + xv.z * w2.z + xv.w * w3.z;
                acc[rr][3] += xv.x * w0.w + xv.y * w1.w + xv.z * w2.w + xv.w * w3.w;
            }
        }
        float4 bv = *(const float4*)(bg2 + c0);
        #pragma unroll
        for (int rr = 0; rr < 4; ++rr) {
            float4 o;
            o.x = acc[rr][0] + bv.x; o.y = acc[rr][1] + bv.y;
            o.z = acc[rr][2] + bv.z; o.w = acc[rr][3] + bv.w;
            *(float4*)(&sx[tr * 4 + rr][256 + c0]) = o;
        }
    }
    __syncthreads();

    {
        const int tj = lane & 15, tr = lane >> 4;
        const int c0 = w * 64 + tj * 4;
        float acc[4][4];
        #pragma unroll
        for (int a = 0; a < 4; ++a)
            #pragma unroll
            for (int b = 0; b < 4; ++b) acc[a][b] = 0.f;

        for (int k = 0; k < 512; k += 4) {
            float4 w0 = *(const float4*)(Wo1 + (size_t)(k + 0) * 256 + c0);
            float4 w1 = *(const float4*)(Wo1 + (size_t)(k + 1) * 256 + c0);
            float4 w2 = *(const float4*)(Wo1 + (size_t)(k + 2) * 256 + c0);
            float4 w3 = *(const float4*)(Wo1 + (size_t)(k + 3) * 256 + c0);
            #pragma unroll
            for (int rr = 0; rr < 4; ++rr) {
                float4 xv = *(const float4*)(&sx[tr * 4 + rr][k]);
                acc[rr][0] += xv.x * w0.x + xv.y * w1.x + xv.z * w2.x + xv.w * w3.x;
                acc[rr][1] += xv.x * w0.y + xv.y * w1.y + xv.z * w2.y + xv.w * w3.y;
                acc[rr][2] += xv.x * w0.z + xv.y * w1.z + xv.z * w2.z + xv.w * w3.z;
                acc[rr][3] += xv.x * w0.w + xv.y * w1.w + xv.z * w2.w + xv.w * w3.w;
            }
        }
        float4 bv = *(const float4*)(bo1 + c0);
        float4 wv = *(const float4*)(Wo2 + c0);
        #pragma unroll
        for (int rr = 0; rr < 4; ++rr) {
            float pc = lrelu(acc[rr][0] + bv.x) * wv.x
                     + lrelu(acc[rr][1] + bv.y) * wv.y
                     + lrelu(acc[rr][2] + bv.z) * wv.z
                     + lrelu(acc[rr][3] + bv.w) * wv.w;
            pc += __shfl_xor(pc, 1); pc += __shfl_xor(pc, 2);
            pc += __shfl_xor(pc, 4); pc += __shfl_xor(pc, 8);
            if (tj == 0) part[w][tr * 4 + rr] = pc;
        }
    }
    __syncthreads();
    if (tid < 16)
        out[row0 + tid] = part[0][tid] + part[1][tid] + part[2][tid] + part[3][tid] + bo2[0];
}

extern "C" void kernel_launch(void* const* d_in, const int* in_sizes, int n_in,
                              void* d_out, int out_size, void* d_ws, size_t ws_size,
                              hipStream_t stream) {
    const float* W_pi1 = (const float*)d_in[0];
    const float* b_pi1 = (const float*)d_in[1];
    const float* W_pi2 = (const float*)d_in[2];
    const float* b_pi2 = (const float*)d_in[3];
    const float* W_p1  = (const float*)d_in[8];
    const float* b_p1  = (const float*)d_in[9];
    const float* W_p2  = (const float*)d_in[10];
    const float* W_n1  = (const float*)d_in[12];
    const float* b_n1  = (const float*)d_in[13];
    const float* W_n2  = (const float*)d_in[14];
    const float* b_n2  = (const float*)d_in[15];
    const float* W_g1  = (const float*)d_in[16];
    const float* b_g1  = (const float*)d_in[17];
    const float* W_g2  = (const float*)d_in[18];
    const float* b_g2  = (const float*)d_in[19];
    const float* W_o1  = (const float*)d_in[20];
    const float* b_o1  = (const float*)d_in[21];
    const float* W_o2  = (const float*)d_in[22];
    const float* b_o2  = (const float*)d_in[23];
    const float* av    = (const float*)d_in[24];
    const float* delay = (const float*)d_in[26];
    const float* bit_pos = (const float*)d_in[27];
    const float* po_feat = (const float*)d_in[28];
    const int*   is_po   = (const int*)d_in[29];
    const int*   nbr_idx = (const int*)d_in[30];

    u16*   h_all = (u16*)d_ws;                                // NN*NH bf16 (33.5 MB)
    float* g_all = (float*)(h_all + (size_t)NN * NH);         // NN floats
    float* cst   = g_all + NN;                                // 64 floats
    float* out   = (float*)d_out;

    precomp_kernel<<<1, 32, 0, stream>>>(W_p2, av, cst);

    level0_kernel<<<NM / 32, 512, 0, stream>>>(delay, W_pi1, b_pi1, W_pi2, b_pi2,
                                               av, h_all, g_all);

    for (int level = 1; level < NL; ++level) {
        level_kernel<<<NM / 8, 256, 0, stream>>>(h_all, g_all, bit_pos, nbr_idx,
                                                 W_p1, b_p1, cst,
                                                 W_n1, b_n1, W_n2, b_n2,
                                                 is_po, av, h_all, g_all, level);
    }

    final_kernel<<<NM / 16, 256, 0, stream>>>(h_all + (size_t)(NN - NM) * NH, po_feat,
                                              W_g1, b_g1, W_g2, b_g2,
                                              W_o1, b_o1, W_o2, b_o2, out);
}

// Round 13
// 379.295 us; speedup vs baseline: 3.5121x; 1.1456x over previous
//
#include <hip/hip_runtime.h>

#define NL 8
#define NM 8192
#define ND 16
#define NH 256
#define NF 64
#define NN (NL * NM)

typedef unsigned short u16;

__device__ __forceinline__ float lrelu(float x) { return fmaxf(x, 0.1f * x); }

__device__ __forceinline__ u16 f2bf(float x) {
    union { float f; unsigned int u; } v; v.f = x;
    unsigned int r = (v.u + 0x7FFFu + ((v.u >> 16) & 1u)) >> 16;
    return (u16)r;
}
__device__ __forceinline__ ushort4 f4_to_bf4(float4 o) {
    ushort4 r; r.x = f2bf(o.x); r.y = f2bf(o.y); r.z = f2bf(o.z); r.w = f2bf(o.w);
    return r;
}
__device__ __forceinline__ float2 bfp(unsigned int u) {
    union { unsigned int u; float f; } lo, hi;
    lo.u = u << 16; hi.u = u & 0xFFFF0000u;
    return make_float2(lo.f, hi.f);
}
// load 4 bf16 from LDS (8B) -> float4
__device__ __forceinline__ float4 ld4bf(const u16* p) {
    uint2 xu = *(const uint2*)p;
    float2 a = bfp(xu.x), b = bfp(xu.y);
    return make_float4(a.x, a.y, b.x, b.y);
}

// ---------- precompute attention constants: cst[32..63] = W_p2 @ av_p ----------
__global__ void precomp_kernel(const float* __restrict__ W_p2, const float* __restrict__ av,
                               float* __restrict__ cst)
{
    int j = threadIdx.x;   // 32 threads
    float w = 0.f;
    for (int k = 0; k < 32; ++k) w += W_p2[j * 32 + k] * av[32 + k];
    cst[32 + j] = w;
}

// ---------- Level 0: h = mlp_pi(delay) (bf16 store) + g epilogue ----------
__global__ __launch_bounds__(512) void level0_kernel(
    const float* __restrict__ delay,
    const float* __restrict__ W1, const float* __restrict__ b1,
    const float* __restrict__ W2, const float* __restrict__ b2,
    const float* __restrict__ av,
    u16* __restrict__ h_all, float* __restrict__ g_all)
{
    const int tid = threadIdx.x;
    const int row0 = blockIdx.x * 32;
    __shared__ __align__(16) float sH[32][132];

    for (int x = tid; x < 32 * 128; x += 512) {
        int r = x >> 7, j = x & 127;
        sH[r][j] = lrelu(delay[row0 + r] * W1[j] + b1[j]);
    }
    __syncthreads();

    const int tj = tid & 63, tr = tid >> 6;
    const float4 av4 = *(const float4*)(av + 64 + tj * 4);
    float acc[4][4];
    #pragma unroll
    for (int a = 0; a < 4; ++a)
        #pragma unroll
        for (int b = 0; b < 4; ++b) acc[a][b] = 0.f;

    for (int k = 0; k < 128; k += 4) {
        float4 w0 = *(const float4*)(W2 + (size_t)(k + 0) * 256 + tj * 4);
        float4 w1 = *(const float4*)(W2 + (size_t)(k + 1) * 256 + tj * 4);
        float4 w2 = *(const float4*)(W2 + (size_t)(k + 2) * 256 + tj * 4);
        float4 w3 = *(const float4*)(W2 + (size_t)(k + 3) * 256 + tj * 4);
        #pragma unroll
        for (int rr = 0; rr < 4; ++rr) {
            float4 xv = *(const float4*)(&sH[tr * 4 + rr][k]);
            acc[rr][0] += xv.x * w0.x + xv.y * w1.x + xv.z * w2.x + xv.w * w3.x;
            acc[rr][1] += xv.x * w0.y + xv.y * w1.y + xv.z * w2.y + xv.w * w3.y;
            acc[rr][2] += xv.x * w0.z + xv.y * w1.z + xv.z * w2.z + xv.w * w3.z;
            acc[rr][3] += xv.x * w0.w + xv.y * w1.w + xv.z * w2.w + xv.w * w3.w;
        }
    }
    float4 bv = *(const float4*)(b2 + tj * 4);
    #pragma unroll
    for (int rr = 0; rr < 4; ++rr) {
        const int row = row0 + tr * 4 + rr;
        float4 o;
        o.x = acc[rr][0] + bv.x; o.y = acc[rr][1] + bv.y;
        o.z = acc[rr][2] + bv.z; o.w = acc[rr][3] + bv.w;
        *(ushort4*)(h_all + (size_t)row * NH + tj * 4) = f4_to_bf4(o);
        float gp = o.x * av4.x + o.y * av4.y + o.z * av4.z + o.w * av4.w;
        #pragma unroll
        for (int off = 1; off < 64; off <<= 1) gp += __shfl_xor(gp, off);
        if (tj == 0) g_all[row] = gp;
    }
}

// ---------- Attention: 1 wave per m; g-gather alpha + single 16B-load streamed pass ----------
__global__ __launch_bounds__(256) void attn_kernel(
    const u16* __restrict__ h_all, const float* __restrict__ g_all,
    const float* __restrict__ bit_pos, const int* __restrict__ nbr_idx,
    const float* __restrict__ W_p1, const float* __restrict__ b_p1,
    const float* __restrict__ cst,
    u16* __restrict__ neigh, int level)
{
    const int w = threadIdx.x >> 6, lane = threadIdx.x & 63;
    const int m = blockIdx.x * 4 + w;
    const int d = lane & 15, jj = lane >> 4;
    const size_t ebase = ((size_t)(level - 1) * NM + m) * ND;

    const int   idx = nbr_idx[ebase + d];
    const float bp  = bit_pos[ebase + d];

    // collapsed mlp_p: 4 jj-groups each cover 8 of the 32 hidden units
    float ep = 0.f;
    #pragma unroll
    for (int t = 0; t < 8; ++t) {
        int j = jj * 8 + t;
        ep += cst[32 + j] * lrelu(bp * W_p1[j] + b_p1[j]);
    }
    ep += __shfl_xor(ep, 16);
    ep += __shfl_xor(ep, 32);

    // e = e_h + e_p  (e_t is constant over d -> cancels in softmax)
    float e = g_all[idx] + ep;
    float mx = e;
    #pragma unroll
    for (int off = 1; off < 16; off <<= 1) mx = fmaxf(mx, __shfl_xor(mx, off));
    float wexp = __expf(e - mx);
    float s = wexp;
    #pragma unroll
    for (int off = 1; off < 16; off <<= 1) s += __shfl_xor(s, off);
    const float alpha = wexp / s;

    // streamed weighted sum: lane = rh*32 + cl; 16B (8 bf16) per lane, 2 rows/step
    const int rh = lane >> 5, cl = lane & 31;
    float4 a0 = make_float4(0.f, 0.f, 0.f, 0.f);
    float4 a1 = make_float4(0.f, 0.f, 0.f, 0.f);
    #pragma unroll
    for (int t = 0; t < 8; ++t) {
        const int d2 = t * 2 + rh;
        float a = __shfl(alpha, d2);
        int   r = __shfl(idx, d2);
        uint4 hv = *(const uint4*)(h_all + (size_t)r * NH + cl * 8);
        float2 p0 = bfp(hv.x), p1 = bfp(hv.y), p2 = bfp(hv.z), p3 = bfp(hv.w);
        a0.x += a * p0.x; a0.y += a * p0.y; a0.z += a * p1.x; a0.w += a * p1.y;
        a1.x += a * p2.x; a1.y += a * p2.y; a1.z += a * p3.x; a1.w += a * p3.y;
    }
    a0.x += __shfl_xor(a0.x, 32); a0.y += __shfl_xor(a0.y, 32);
    a0.z += __shfl_xor(a0.z, 32); a0.w += __shfl_xor(a0.w, 32);
    a1.x += __shfl_xor(a1.x, 32); a1.y += __shfl_xor(a1.y, 32);
    a1.z += __shfl_xor(a1.z, 32); a1.w += __shfl_xor(a1.w, 32);

    float4 outv = (rh == 0) ? a0 : a1;
    *(ushort4*)(neigh + (size_t)m * NH + cl * 8 + rh * 4) = f4_to_bf4(outv);
}

// ---------- Neighborhood MLP: 256 thr / 16 rows / 512 blocks; bf16 sX in LDS ----------
__global__ __launch_bounds__(256) void mlp_n_kernel(
    const u16* __restrict__ neigh,
    const float* __restrict__ W1, const float* __restrict__ b1,
    const float* __restrict__ W2, const float* __restrict__ b2,
    const int* __restrict__ is_po, const float* __restrict__ av,
    u16* __restrict__ h_all, float* __restrict__ g_all, int level)
{
    const int tid = threadIdx.x;
    const int w = tid >> 6, lane = tid & 63;
    const int row0 = blockIdx.x * 16;
    __shared__ __align__(16) u16   sXb[16][NH + 8];   // stride 264 u16 = 132 dw (mod32=4)
    __shared__ __align__(16) float sH[16][132];       // stride 132 (mod32=4)
    __shared__ float gpart[4][16];

    for (int x = tid; x < 16 * 32; x += 256) {
        int r = x >> 5, c = x & 31;
        *(uint4*)(&sXb[r][c * 8]) = *(const uint4*)(neigh + (size_t)(row0 + r) * NH + c * 8);
    }
    __syncthreads();

    // layer 1: (16x256)@(256x128); wave w -> cols [w*32, w*32+32)
    {
        const int tj = lane & 7, tr = lane >> 3;   // 8 col-thr x 4 cols; 8 grp x 2 rows
        const int c0 = w * 32 + tj * 4;
        float acc[2][4];
        #pragma unroll
        for (int a = 0; a < 2; ++a)
            #pragma unroll
            for (int b = 0; b < 4; ++b) acc[a][b] = 0.f;

        for (int k = 0; k < NH; k += 4) {
            float4 w0 = *(const float4*)(W1 + (size_t)(k + 0) * 128 + c0);
            float4 w1 = *(const float4*)(W1 + (size_t)(k + 1) * 128 + c0);
            float4 w2 = *(const float4*)(W1 + (size_t)(k + 2) * 128 + c0);
            float4 w3 = *(const float4*)(W1 + (size_t)(k + 3) * 128 + c0);
            #pragma unroll
            for (int rr = 0; rr < 2; ++rr) {
                float4 xv = ld4bf(&sXb[tr * 2 + rr][k]);
                acc[rr][0] += xv.x * w0.x + xv.y * w1.x + xv.z * w2.x + xv.w * w3.x;
                acc[rr][1] += xv.x * w0.y + xv.y * w1.y + xv.z * w2.y + xv.w * w3.y;
                acc[rr][2] += xv.x * w0.z + xv.y * w1.z + xv.z * w2.z + xv.w * w3.z;
                acc[rr][3] += xv.x * w0.w + xv.y * w1.w + xv.z * w2.w + xv.w * w3.w;
            }
        }
        float4 bv = *(const float4*)(b1 + c0);
        #pragma unroll
        for (int rr = 0; rr < 2; ++rr) {
            float4 o;
            o.x = lrelu(acc[rr][0] + bv.x); o.y = lrelu(acc[rr][1] + bv.y);
            o.z = lrelu(acc[rr][2] + bv.z); o.w = lrelu(acc[rr][3] + bv.w);
            *(float4*)(&sH[tr * 2 + rr][c0]) = o;
        }
    }
    __syncthreads();

    // layer 2: (16x128)@(128x256); wave w -> cols [w*64, w*64+64); cond-relu, bf16 store + g partial
    {
        const int tj = lane & 15, tr = lane >> 4;  // 16 col-thr x 4 cols; 4 grp x 4 rows
        const int c0 = w * 64 + tj * 4;
        const float4 av4 = *(const float4*)(av + 64 + c0);
        float acc[4][4];
        #pragma unroll
        for (int a = 0; a < 4; ++a)
            #pragma unroll
            for (int b = 0; b < 4; ++b) acc[a][b] = 0.f;

        for (int k = 0; k < 128; k += 4) {
            float4 w0 = *(const float4*)(W2 + (size_t)(k + 0) * 256 + c0);
            float4 w1 = *(const float4*)(W2 + (size_t)(k + 1) * 256 + c0);
            float4 w2 = *(const float4*)(W2 + (size_t)(k + 2) * 256 + c0);
            float4 w3 = *(const float4*)(W2 + (size_t)(k + 3) * 256 + c0);
            #pragma unroll
            for (int rr = 0; rr < 4; ++rr) {
                float4 xv = *(const float4*)(&sH[tr * 4 + rr][k]);
                acc[rr][0] += xv.x * w0.x + xv.y * w1.x + xv.z * w2.x + xv.w * w3.x;
                acc[rr][1] += xv.x * w0.y + xv.y * w1.y + xv.z * w2.y + xv.w * w3.y;
                acc[rr][2] += xv.x * w0.z + xv.y * w1.z + xv.z * w2.z + xv.w * w3.z;
                acc[rr][3] += xv.x * w0.w + xv.y * w1.w + xv.z * w2.w + xv.w * w3.w;
            }
        }
        float4 bv = *(const float4*)(b2 + c0);
        #pragma unroll
        for (int rr = 0; rr < 4; ++rr) {
            const int gm = level * NM + row0 + tr * 4 + rr;
            bool po = (is_po[gm] == 1);
            float4 o;
            o.x = acc[rr][0] + bv.x; o.y = acc[rr][1] + bv.y;
            o.z = acc[rr][2] + bv.z; o.w = acc[rr][3] + bv.w;
            if (!po) {
                o.x = fmaxf(o.x, 0.f); o.y = fmaxf(o.y, 0.f);
                o.z = fmaxf(o.z, 0.f); o.w = fmaxf(o.w, 0.f);
            }
            *(ushort4*)(h_all + (size_t)gm * NH + c0) = f4_to_bf4(o);
            float gp = o.x * av4.x + o.y * av4.y + o.z * av4.z + o.w * av4.w;
            gp += __shfl_xor(gp, 1); gp += __shfl_xor(gp, 2);
            gp += __shfl_xor(gp, 4); gp += __shfl_xor(gp, 8);
            if (tj == 0) gpart[w][tr * 4 + rr] = gp;
        }
    }
    __syncthreads();
    if (tid < 16)
        g_all[level * NM + row0 + tid] =
            gpart[0][tid] + gpart[1][tid] + gpart[2][tid] + gpart[3][tid];
}

// ---------- Final readout: 256 thr / 16 rows / 512 blocks; bf16 sx in LDS ----------
__global__ __launch_bounds__(256) void final_kernel(
    const u16* __restrict__ h_gnn, const float* __restrict__ po_feat,
    const float* __restrict__ Wg1, const float* __restrict__ bg1,
    const float* __restrict__ Wg2, const float* __restrict__ bg2,
    const float* __restrict__ Wo1, const float* __restrict__ bo1,
    const float* __restrict__ Wo2, const float* __restrict__ bo2,
    float* __restrict__ out)
{
    const int tid = threadIdx.x;
    const int w = tid >> 6, lane = tid & 63;
    const int row0 = blockIdx.x * 16;
    __shared__ __align__(16) u16   sxb[16][520];   // stride 520 u16 = 260 dw (mod32=4)
    __shared__ __align__(16) float sg[16][132];
    __shared__ float part[4][16];

    // h quadrant: direct bf16 copy (no rounding)
    for (int x = tid; x < 16 * 32; x += 256) {
        int r = x >> 5, c = x & 31;
        *(uint4*)(&sxb[r][c * 8]) = *(const uint4*)(h_gnn + (size_t)(row0 + r) * NH + c * 8);
    }
    for (int x = tid; x < 16 * 128; x += 256) {
        int r = x >> 7, j = x & 127;
        sg[r][j] = lrelu(po_feat[row0 + r] * Wg1[j] + bg1[j]);
    }
    __syncthreads();

    // h_global = sg @ Wg2 + bg2 -> sxb[:, 256:] (bf16); wave w -> cols [w*64, w*64+64)
    {
        const int tj = lane & 15, tr = lane >> 4;
        const int c0 = w * 64 + tj * 4;
        float acc[4][4];
        #pragma unroll
        for (int a = 0; a < 4; ++a)
            #pragma unroll
            for (int b = 0; b < 4; ++b) acc[a][b] = 0.f;

        for (int k = 0; k < 128; k += 4) {
            float4 w0 = *(const float4*)(Wg2 + (size_t)(k + 0) * 256 + c0);
            float4 w1 = *(const float4*)(Wg2 + (size_t)(k + 1) * 256 + c0);
            float4 w2 = *(const float4*)(Wg2 + (size_t)(k + 2) * 256 + c0);
            float4 w3 = *(const float4*)(Wg2 + (size_t)(k + 3) * 256 + c0);
            #pragma unroll
            for (int rr = 0; rr < 4; ++rr) {
                float4 xv = *(const float4*)(&sg[tr * 4 + rr][k]);
                acc[rr][0] += xv.x * w0.x + xv.y * w1.x + xv.z * w2.x + xv.w * w3.x;
                acc[rr][1] += xv.x * w0.y + xv.y * w1.y + xv.z * w2.y + xv.w * w3.y;
                acc[rr][2] += xv.x * w0.z + xv.y * w1.z + xv.z * w2.z + xv.w * w3.z;
                acc[rr][3] += xv.x * w0.w + xv.y * w1.w + xv.z * w2.w + xv.w * w3.w;
            }
        }
        float4 bv = *(const float4*)(bg2 + c0);
        #pragma unroll
        for (int rr = 0; rr < 4; ++rr) {
            float4 o;
            o.x = acc[rr][0] + bv.x; o.y = acc[rr][1] + bv.y;
            o.z = acc[rr][2] + bv.z; o.w = acc[rr][3] + bv.w;
            *(ushort4*)(&sxb[tr * 4 + rr][256 + c0]) = f4_to_bf4(o);
        }
    }
    __syncthreads();

    // o1 = lrelu(sxb @ Wo1 + bo1), K=512, col-split; fused partial dot with Wo2
    {
        const int tj = lane & 15, tr = lane >> 4;
        const int c0 = w * 64 + tj * 4;
        float acc[4][4];
        #pragma unroll
        for (int a = 0; a < 4; ++a)
            #pragma unroll
            for (int b = 0; b < 4; ++b) acc[a][b] = 0.f;

        for (int k = 0; k < 512; k += 4) {
            float4 w0 = *(const float4*)(Wo1 + (size_t)(k + 0) * 256 + c0);
            float4 w1 = *(const float4*)(Wo1 + (size_t)(k + 1) * 256 + c0);
            float4 w2 = *(const float4*)(Wo1 + (size_t)(k + 2) * 256 + c0);
            float4 w3 = *(const float4*)(Wo1 + (size_t)(k + 3) * 256 + c0);
            #pragma unroll
            for (int rr = 0; rr < 4; ++rr) {
                float4 xv = ld4bf(&sxb[tr * 4 + rr][k]);
                acc[rr][0] += xv.x * w0.x + xv.y * w1.x + xv.z * w2.x + xv.w * w3.x;
                acc[rr][1] += xv.x * w0.y + xv.y * w1.y + xv.z * w2.y + xv.w * w3.y;
                acc[rr][2] += xv.x * w0.z + xv.y * w1.z + xv.z * w2.z + xv.w * w3.z;
                acc[rr][3] += xv.x * w0.w + xv.y * w1.w + xv.z * w2.w + xv.w * w3.w;
            }
        }
        float4 bv = *(const float4*)(bo1 + c0);
        float4 wv = *(const float4*)(Wo2 + c0);
        #pragma unroll
        for (int rr = 0; rr < 4; ++rr) {
            float pc = lrelu(acc[rr][0] + bv.x) * wv.x
                     + lrelu(acc[rr][1] + bv.y) * wv.y
                     + lrelu(acc[rr][2] + bv.z) * wv.z
                     + lrelu(acc[rr][3] + bv.w) * wv.w;
            pc += __shfl_xor(pc, 1); pc += __shfl_xor(pc, 2);
            pc += __shfl_xor(pc, 4); pc += __shfl_xor(pc, 8);
            if (tj == 0) part[w][tr * 4 + rr] = pc;
        }
    }
    __syncthreads();
    if (tid < 16)
        out[row0 + tid] = part[0][tid] + part[1][tid] + part[2][tid] + part[3][tid] + bo2[0];
}

extern "C" void kernel_launch(void* const* d_in, const int* in_sizes, int n_in,
                              void* d_out, int out_size, void* d_ws, size_t ws_size,
                              hipStream_t stream) {
    const float* W_pi1 = (const float*)d_in[0];
    const float* b_pi1 = (const float*)d_in[1];
    const float* W_pi2 = (const float*)d_in[2];
    const float* b_pi2 = (const float*)d_in[3];
    const float* W_p1  = (const float*)d_in[8];
    const float* b_p1  = (const float*)d_in[9];
    const float* W_p2  = (const float*)d_in[10];
    const float* W_n1  = (const float*)d_in[12];
    const float* b_n1  = (const float*)d_in[13];
    const float* W_n2  = (const float*)d_in[14];
    const float* b_n2  = (const float*)d_in[15];
    const float* W_g1  = (const float*)d_in[16];
    const float* b_g1  = (const float*)d_in[17];
    const float* W_g2  = (const float*)d_in[18];
    const float* b_g2  = (const float*)d_in[19];
    const float* W_o1  = (const float*)d_in[20];
    const float* b_o1  = (const float*)d_in[21];
    const float* W_o2  = (const float*)d_in[22];
    const float* b_o2  = (const float*)d_in[23];
    const float* av    = (const float*)d_in[24];
    const float* delay = (const float*)d_in[26];
    const float* bit_pos = (const float*)d_in[27];
    const float* po_feat = (const float*)d_in[28];
    const int*   is_po   = (const int*)d_in[29];
    const int*   nbr_idx = (const int*)d_in[30];

    u16*   h_all = (u16*)d_ws;                                // NN*NH bf16 (33.5 MB)
    float* g_all = (float*)(h_all + (size_t)NN * NH);         // NN floats
    u16*   neigh = (u16*)(g_all + NN);                        // NM*NH bf16 (4 MB)
    float* cst   = (float*)(neigh + (size_t)NM * NH);         // 64 floats
    float* out   = (float*)d_out;

    precomp_kernel<<<1, 32, 0, stream>>>(W_p2, av, cst);

    level0_kernel<<<NM / 32, 512, 0, stream>>>(delay, W_pi1, b_pi1, W_pi2, b_pi2,
                                               av, h_all, g_all);

    for (int level = 1; level < NL; ++level) {
        attn_kernel<<<NM / 4, 256, 0, stream>>>(h_all, g_all, bit_pos, nbr_idx,
                                                W_p1, b_p1, cst, neigh, level);
        mlp_n_kernel<<<NM / 16, 256, 0, stream>>>(neigh, W_n1, b_n1, W_n2, b_n2,
                                                  is_po, av, h_all, g_all, level);
    }

    final_kernel<<<NM / 16, 256, 0, stream>>>(h_all + (size_t)(NN - NM) * NH, po_feat,
                                              W_g1, b_g1, W_g2, b_g2,
                                              W_o1, b_o1, W_o2, b_o2, out);
}

// Round 14
// 378.234 us; speedup vs baseline: 3.5219x; 1.0028x over previous
//
#include <hip/hip_runtime.h>

#define NL 8
#define NM 8192
#define ND 16
#define NH 256
#define NF 64
#define NN (NL * NM)

typedef unsigned short u16;

__device__ __forceinline__ float lrelu(float x) { return fmaxf(x, 0.1f * x); }

__device__ __forceinline__ u16 f2bf(float x) {
    union { float f; unsigned int u; } v; v.f = x;
    unsigned int r = (v.u + 0x7FFFu + ((v.u >> 16) & 1u)) >> 16;
    return (u16)r;
}
__device__ __forceinline__ ushort4 f4_to_bf4(float4 o) {
    ushort4 r; r.x = f2bf(o.x); r.y = f2bf(o.y); r.z = f2bf(o.z); r.w = f2bf(o.w);
    return r;
}
__device__ __forceinline__ float2 bfp(unsigned int u) {
    union { unsigned int u; float f; } lo, hi;
    lo.u = u << 16; hi.u = u & 0xFFFF0000u;
    return make_float2(lo.f, hi.f);
}

// ---------- precompute attention constants: cst[32..63] = W_p2 @ av_p ----------
__global__ void precomp_kernel(const float* __restrict__ W_p2, const float* __restrict__ av,
                               float* __restrict__ cst)
{
    int j = threadIdx.x;   // 32 threads
    float w = 0.f;
    for (int k = 0; k < 32; ++k) w += W_p2[j * 32 + k] * av[32 + k];
    cst[32 + j] = w;
}

// ---------- Level 0: h = mlp_pi(delay) (bf16 store) + g epilogue ----------
__global__ __launch_bounds__(512) void level0_kernel(
    const float* __restrict__ delay,
    const float* __restrict__ W1, const float* __restrict__ b1,
    const float* __restrict__ W2, const float* __restrict__ b2,
    const float* __restrict__ av,
    u16* __restrict__ h_all, float* __restrict__ g_all)
{
    const int tid = threadIdx.x;
    const int row0 = blockIdx.x * 32;
    __shared__ __align__(16) float sH[32][132];

    for (int x = tid; x < 32 * 128; x += 512) {
        int r = x >> 7, j = x & 127;
        sH[r][j] = lrelu(delay[row0 + r] * W1[j] + b1[j]);
    }
    __syncthreads();

    const int tj = tid & 63, tr = tid >> 6;
    const float4 av4 = *(const float4*)(av + 64 + tj * 4);
    float acc[4][4];
    #pragma unroll
    for (int a = 0; a < 4; ++a)
        #pragma unroll
        for (int b = 0; b < 4; ++b) acc[a][b] = 0.f;

    for (int k = 0; k < 128; k += 4) {
        float4 w0 = *(const float4*)(W2 + (size_t)(k + 0) * 256 + tj * 4);
        float4 w1 = *(const float4*)(W2 + (size_t)(k + 1) * 256 + tj * 4);
        float4 w2 = *(const float4*)(W2 + (size_t)(k + 2) * 256 + tj * 4);
        float4 w3 = *(const float4*)(W2 + (size_t)(k + 3) * 256 + tj * 4);
        #pragma unroll
        for (int rr = 0; rr < 4; ++rr) {
            float4 xv = *(const float4*)(&sH[tr * 4 + rr][k]);
            acc[rr][0] += xv.x * w0.x + xv.y * w1.x + xv.z * w2.x + xv.w * w3.x;
            acc[rr][1] += xv.x * w0.y + xv.y * w1.y + xv.z * w2.y + xv.w * w3.y;
            acc[rr][2] += xv.x * w0.z + xv.y * w1.z + xv.z * w2.z + xv.w * w3.z;
            acc[rr][3] += xv.x * w0.w + xv.y * w1.w + xv.z * w2.w + xv.w * w3.w;
        }
    }
    float4 bv = *(const float4*)(b2 + tj * 4);
    #pragma unroll
    for (int rr = 0; rr < 4; ++rr) {
        const int row = row0 + tr * 4 + rr;
        float4 o;
        o.x = acc[rr][0] + bv.x; o.y = acc[rr][1] + bv.y;
        o.z = acc[rr][2] + bv.z; o.w = acc[rr][3] + bv.w;
        *(ushort4*)(h_all + (size_t)row * NH + tj * 4) = f4_to_bf4(o);
        float gp = o.x * av4.x + o.y * av4.y + o.z * av4.z + o.w * av4.w;
        #pragma unroll
        for (int off = 1; off < 64; off <<= 1) gp += __shfl_xor(gp, off);
        if (tj == 0) g_all[row] = gp;
    }
}

// ---------- Attention: 1 wave per m; g-gather alpha + single 16B-load streamed pass ----------
__global__ __launch_bounds__(256) void attn_kernel(
    const u16* __restrict__ h_all, const float* __restrict__ g_all,
    const float* __restrict__ bit_pos, const int* __restrict__ nbr_idx,
    const float* __restrict__ W_p1, const float* __restrict__ b_p1,
    const float* __restrict__ cst,
    u16* __restrict__ neigh, int level)
{
    const int w = threadIdx.x >> 6, lane = threadIdx.x & 63;
    const int m = blockIdx.x * 4 + w;
    const int d = lane & 15, jj = lane >> 4;
    const size_t ebase = ((size_t)(level - 1) * NM + m) * ND;

    const int   idx = nbr_idx[ebase + d];
    const float bp  = bit_pos[ebase + d];

    float ep = 0.f;
    #pragma unroll
    for (int t = 0; t < 8; ++t) {
        int j = jj * 8 + t;
        ep += cst[32 + j] * lrelu(bp * W_p1[j] + b_p1[j]);
    }
    ep += __shfl_xor(ep, 16);
    ep += __shfl_xor(ep, 32);

    float e = g_all[idx] + ep;
    float mx = e;
    #pragma unroll
    for (int off = 1; off < 16; off <<= 1) mx = fmaxf(mx, __shfl_xor(mx, off));
    float wexp = __expf(e - mx);
    float s = wexp;
    #pragma unroll
    for (int off = 1; off < 16; off <<= 1) s += __shfl_xor(s, off);
    const float alpha = wexp / s;

    const int rh = lane >> 5, cl = lane & 31;
    float4 a0 = make_float4(0.f, 0.f, 0.f, 0.f);
    float4 a1 = make_float4(0.f, 0.f, 0.f, 0.f);
    #pragma unroll
    for (int t = 0; t < 8; ++t) {
        const int d2 = t * 2 + rh;
        float a = __shfl(alpha, d2);
        int   r = __shfl(idx, d2);
        uint4 hv = *(const uint4*)(h_all + (size_t)r * NH + cl * 8);
        float2 p0 = bfp(hv.x), p1 = bfp(hv.y), p2 = bfp(hv.z), p3 = bfp(hv.w);
        a0.x += a * p0.x; a0.y += a * p0.y; a0.z += a * p1.x; a0.w += a * p1.y;
        a1.x += a * p2.x; a1.y += a * p2.y; a1.z += a * p3.x; a1.w += a * p3.y;
    }
    a0.x += __shfl_xor(a0.x, 32); a0.y += __shfl_xor(a0.y, 32);
    a0.z += __shfl_xor(a0.z, 32); a0.w += __shfl_xor(a0.w, 32);
    a1.x += __shfl_xor(a1.x, 32); a1.y += __shfl_xor(a1.y, 32);
    a1.z += __shfl_xor(a1.z, 32); a1.w += __shfl_xor(a1.w, 32);

    float4 outv = (rh == 0) ? a0 : a1;
    *(ushort4*)(neigh + (size_t)m * NH + cl * 8 + rh * 4) = f4_to_bf4(outv);
}

// ---------- Neighborhood MLP: r9 geometry (256 thr / 16 rows / 512 blocks);
//            bf16 neigh unpacked to f32 LDS at stage time; K-loops full-unroll (proven) ----------
__global__ __launch_bounds__(256) void mlp_n_kernel(
    const u16* __restrict__ neigh,
    const float* __restrict__ W1, const float* __restrict__ b1,
    const float* __restrict__ W2, const float* __restrict__ b2,
    const int* __restrict__ is_po, const float* __restrict__ av,
    u16* __restrict__ h_all, float* __restrict__ g_all, int level)
{
    const int tid = threadIdx.x;
    const int w = tid >> 6, lane = tid & 63;
    const int row0 = blockIdx.x * 16;
    __shared__ __align__(16) float sX[16][NH + 4];   // stride 260 (mod32=4)
    __shared__ __align__(16) float sH[16][132];      // stride 132 (mod32=4)
    __shared__ float gpart[4][16];

    // stage: bf16 -> f32 once, outside the K-loops
    for (int x = tid; x < 16 * 32; x += 256) {
        int r = x >> 5, c = x & 31;
        uint4 nv = *(const uint4*)(neigh + (size_t)(row0 + r) * NH + c * 8);
        float2 p0 = bfp(nv.x), p1 = bfp(nv.y), p2 = bfp(nv.z), p3 = bfp(nv.w);
        float* dst = &sX[r][c * 8];
        dst[0] = p0.x; dst[1] = p0.y; dst[2] = p1.x; dst[3] = p1.y;
        dst[4] = p2.x; dst[5] = p2.y; dst[6] = p3.x; dst[7] = p3.y;
    }
    __syncthreads();

    // layer 1: (16x256)@(256x128); wave w -> cols [w*32, w*32+32)
    {
        const int tj = lane & 7, tr = lane >> 3;
        const int c0 = w * 32 + tj * 4;
        float acc[2][4];
        #pragma unroll
        for (int a = 0; a < 2; ++a)
            #pragma unroll
            for (int b = 0; b < 4; ++b) acc[a][b] = 0.f;

        for (int k = 0; k < NH; k += 4) {
            float4 w0 = *(const float4*)(W1 + (size_t)(k + 0) * 128 + c0);
            float4 w1 = *(const float4*)(W1 + (size_t)(k + 1) * 128 + c0);
            float4 w2 = *(const float4*)(W1 + (size_t)(k + 2) * 128 + c0);
            float4 w3 = *(const float4*)(W1 + (size_t)(k + 3) * 128 + c0);
            #pragma unroll
            for (int rr = 0; rr < 2; ++rr) {
                float4 xv = *(const float4*)(&sX[tr * 2 + rr][k]);
                acc[rr][0] += xv.x * w0.x + xv.y * w1.x + xv.z * w2.x + xv.w * w3.x;
                acc[rr][1] += xv.x * w0.y + xv.y * w1.y + xv.z * w2.y + xv.w * w3.y;
                acc[rr][2] += xv.x * w0.z + xv.y * w1.z + xv.z * w2.z + xv.w * w3.z;
                acc[rr][3] += xv.x * w0.w + xv.y * w1.w + xv.z * w2.w + xv.w * w3.w;
            }
        }
        float4 bv = *(const float4*)(b1 + c0);
        #pragma unroll
        for (int rr = 0; rr < 2; ++rr) {
            float4 o;
            o.x = lrelu(acc[rr][0] + bv.x); o.y = lrelu(acc[rr][1] + bv.y);
            o.z = lrelu(acc[rr][2] + bv.z); o.w = lrelu(acc[rr][3] + bv.w);
            *(float4*)(&sH[tr * 2 + rr][c0]) = o;
        }
    }
    __syncthreads();

    // layer 2: (16x128)@(128x256); wave w -> cols [w*64, w*64+64)
    {
        const int tj = lane & 15, tr = lane >> 4;
        const int c0 = w * 64 + tj * 4;
        const float4 av4 = *(const float4*)(av + 64 + c0);
        float acc[4][4];
        #pragma unroll
        for (int a = 0; a < 4; ++a)
            #pragma unroll
            for (int b = 0; b < 4; ++b) acc[a][b] = 0.f;

        for (int k = 0; k < 128; k += 4) {
            float4 w0 = *(const float4*)(W2 + (size_t)(k + 0) * 256 + c0);
            float4 w1 = *(const float4*)(W2 + (size_t)(k + 1) * 256 + c0);
            float4 w2 = *(const float4*)(W2 + (size_t)(k + 2) * 256 + c0);
            float4 w3 = *(const float4*)(W2 + (size_t)(k + 3) * 256 + c0);
            #pragma unroll
            for (int rr = 0; rr < 4; ++rr) {
                float4 xv = *(const float4*)(&sH[tr * 4 + rr][k]);
                acc[rr][0] += xv.x * w0.x + xv.y * w1.x + xv.z * w2.x + xv.w * w3.x;
                acc[rr][1] += xv.x * w0.y + xv.y * w1.y + xv.z * w2.y + xv.w * w3.y;
                acc[rr][2] += xv.x * w0.z + xv.y * w1.z + xv.z * w2.z + xv.w * w3.z;
                acc[rr][3] += xv.x * w0.w + xv.y * w1.w + xv.z * w2.w + xv.w * w3.w;
            }
        }
        float4 bv = *(const float4*)(b2 + c0);
        #pragma unroll
        for (int rr = 0; rr < 4; ++rr) {
            const int gm = level * NM + row0 + tr * 4 + rr;
            bool po = (is_po[gm] == 1);
            float4 o;
            o.x = acc[rr][0] + bv.x; o.y = acc[rr][1] + bv.y;
            o.z = acc[rr][2] + bv.z; o.w = acc[rr][3] + bv.w;
            if (!po) {
                o.x = fmaxf(o.x, 0.f); o.y = fmaxf(o.y, 0.f);
                o.z = fmaxf(o.z, 0.f); o.w = fmaxf(o.w, 0.f);
            }
            *(ushort4*)(h_all + (size_t)gm * NH + c0) = f4_to_bf4(o);
            float gp = o.x * av4.x + o.y * av4.y + o.z * av4.z + o.w * av4.w;
            gp += __shfl_xor(gp, 1); gp += __shfl_xor(gp, 2);
            gp += __shfl_xor(gp, 4); gp += __shfl_xor(gp, 8);
            if (tj == 0) gpart[w][tr * 4 + rr] = gp;
        }
    }
    __syncthreads();
    if (tid < 16)
        g_all[level * NM + row0 + tid] =
            gpart[0][tid] + gpart[1][tid] + gpart[2][tid] + gpart[3][tid];
}

// ---------- Final readout: 256 thr / 8 rows / 1024 blocks; f32 LDS; unroll 4 ----------
__global__ __launch_bounds__(256) void final_kernel(
    const u16* __restrict__ h_gnn, const float* __restrict__ po_feat,
    const float* __restrict__ Wg1, const float* __restrict__ bg1,
    const float* __restrict__ Wg2, const float* __restrict__ bg2,
    const float* __restrict__ Wo1, const float* __restrict__ bo1,
    const float* __restrict__ Wo2, const float* __restrict__ bo2,
    float* __restrict__ out)
{
    const int tid = threadIdx.x;
    const int w = tid >> 6, lane = tid & 63;
    const int row0 = blockIdx.x * 8;
    __shared__ __align__(16) float sx[8][516];   // stride 516 (mod32=4)
    __shared__ __align__(16) float sg[8][132];
    __shared__ float part[4][8];

    // stage h (bf16 -> f32, one uint4 per thread)
    {
        int r = tid >> 5, c = tid & 31;
        uint4 hv = *(const uint4*)(h_gnn + (size_t)(row0 + r) * NH + c * 8);
        float2 p0 = bfp(hv.x), p1 = bfp(hv.y), p2 = bfp(hv.z), p3 = bfp(hv.w);
        float* dst = &sx[r][c * 8];
        dst[0] = p0.x; dst[1] = p0.y; dst[2] = p1.x; dst[3] = p1.y;
        dst[4] = p2.x; dst[5] = p2.y; dst[6] = p3.x; dst[7] = p3.y;
    }
    for (int x = tid; x < 8 * 128; x += 256) {
        int r = x >> 7, j = x & 127;
        sg[r][j] = lrelu(po_feat[row0 + r] * Wg1[j] + bg1[j]);
    }
    __syncthreads();

    // h_global = sg @ Wg2 + bg2 -> sx[:, 256:]; wave w -> cols [w*64, w*64+64); 4 grp x 2 rows
    {
        const int tj = lane & 15, tr = lane >> 4;
        const int c0 = w * 64 + tj * 4;
        float acc[2][4];
        #pragma unroll
        for (int a = 0; a < 2; ++a)
            #pragma unroll
            for (int b = 0; b < 4; ++b) acc[a][b] = 0.f;

        #pragma unroll 4
        for (int k = 0; k < 128; k += 4) {
            float4 w0 = *(const float4*)(Wg2 + (size_t)(k + 0) * 256 + c0);
            float4 w1 = *(const float4*)(Wg2 + (size_t)(k + 1) * 256 + c0);
            float4 w2 = *(const float4*)(Wg2 + (size_t)(k + 2) * 256 + c0);
            float4 w3 = *(const float4*)(Wg2 + (size_t)(k + 3) * 256 + c0);
            #pragma unroll
            for (int rr = 0; rr < 2; ++rr) {
                float4 xv = *(const float4*)(&sg[tr * 2 + rr][k]);
                acc[rr][0] += xv.x * w0.x + xv.y * w1.x + xv.z * w2.x + xv.w * w3.x;
                acc[rr][1] += xv.x * w0.y + xv.y * w1.y + xv.z * w2.y + xv.w * w3.y;
                acc[rr][2] += xv.x * w0.z + xv.y * w1.z + xv.z * w2.z + xv.w * w3.z;
                acc[rr][3] += xv.x * w0.w + xv.y * w1.w + xv.z * w2.w + xv.w * w3.w;
            }
        }
        float4 bv = *(const float4*)(bg2 + c0);
        #pragma unroll
        for (int rr = 0; rr < 2; ++rr) {
            float4 o;
            o.x = acc[rr][0] + bv.x; o.y = acc[rr][1] + bv.y;
            o.z = acc[rr][2] + bv.z; o.w = acc[rr][3] + bv.w;
            *(float4*)(&sx[tr * 2 + rr][256 + c0]) = o;
        }
    }
    __syncthreads();

    // o1 = lrelu(sx @ Wo1 + bo1), K=512; fused partial dot with Wo2
    {
        const int tj = lane & 15, tr = lane >> 4;
        const int c0 = w * 64 + tj * 4;
        float acc[2][4];
        #pragma unroll
        for (int a = 0; a < 2; ++a)
            #pragma unroll
            for (int b = 0; b < 4; ++b) acc[a][b] = 0.f;

        #pragma unroll 4
        for (int k = 0; k < 512; k += 4) {
            float4 w0 = *(const float4*)(Wo1 + (size_t)(k + 0) * 256 + c0);
            float4 w1 = *(const float4*)(Wo1 + (size_t)(k + 1) * 256 + c0);
            float4 w2 = *(const float4*)(Wo1 + (size_t)(k + 2) * 256 + c0);
            float4 w3 = *(const float4*)(Wo1 + (size_t)(k + 3) * 256 + c0);
            #pragma unroll
            for (int rr = 0; rr < 2; ++rr) {
                float4 xv = *(const float4*)(&sx[tr * 2 + rr][k]);
                acc[rr][0] += xv.x * w0.x + xv.y * w1.x + xv.z * w2.x + xv.w * w3.x;
                acc[rr][1] += xv.x * w0.y + xv.y * w1.y + xv.z * w2.y + xv.w * w3.y;
                acc[rr][2] += xv.x * w0.z + xv.y * w1.z + xv.z * w2.z + xv.w * w3.z;
                acc[rr][3] += xv.x * w0.w + xv.y * w1.w + xv.z * w2.w + xv.w * w3.w;
            }
        }
        float4 bv = *(const float4*)(bo1 + c0);
        float4 wv = *(const float4*)(Wo2 + c0);
        #pragma unroll
        for (int rr = 0; rr < 2; ++rr) {
            float pc = lrelu(acc[rr][0] + bv.x) * wv.x
                     + lrelu(acc[rr][1] + bv.y) * wv.y
                     + lrelu(acc[rr][2] + bv.z) * wv.z
                     + lrelu(acc[rr][3] + bv.w) * wv.w;
            pc += __shfl_xor(pc, 1); pc += __shfl_xor(pc, 2);
            pc += __shfl_xor(pc, 4); pc += __shfl_xor(pc, 8);
            if (tj == 0) part[w][tr * 2 + rr] = pc;
        }
    }
    __syncthreads();
    if (tid < 8)
        out[row0 + tid] = part[0][tid] + part[1][tid] + part[2][tid] + part[3][tid] + bo2[0];
}

extern "C" void kernel_launch(void* const* d_in, const int* in_sizes, int n_in,
                              void* d_out, int out_size, void* d_ws, size_t ws_size,
                              hipStream_t stream) {
    const float* W_pi1 = (const float*)d_in[0];
    const float* b_pi1 = (const float*)d_in[1];
    const float* W_pi2 = (const float*)d_in[2];
    const float* b_pi2 = (const float*)d_in[3];
    const float* W_p1  = (const float*)d_in[8];
    const float* b_p1  = (const float*)d_in[9];
    const float* W_p2  = (const float*)d_in[10];
    const float* W_n1  = (const float*)d_in[12];
    const float* b_n1  = (const float*)d_in[13];
    const float* W_n2  = (const float*)d_in[14];
    const float* b_n2  = (const float*)d_in[15];
    const float* W_g1  = (const float*)d_in[16];
    const float* b_g1  = (const float*)d_in[17];
    const float* W_g2  = (const float*)d_in[18];
    const float* b_g2  = (const float*)d_in[19];
    const float* W_o1  = (const float*)d_in[20];
    const float* b_o1  = (const float*)d_in[21];
    const float* W_o2  = (const float*)d_in[22];
    const float* b_o2  = (const float*)d_in[23];
    const float* av    = (const float*)d_in[24];
    const float* delay = (const float*)d_in[26];
    const float* bit_pos = (const float*)d_in[27];
    const float* po_feat = (const float*)d_in[28];
    const int*   is_po   = (const int*)d_in[29];
    const int*   nbr_idx = (const int*)d_in[30];

    u16*   h_all = (u16*)d_ws;                                // NN*NH bf16 (33.5 MB)
    float* g_all = (float*)(h_all + (size_t)NN * NH);         // NN floats
    u16*   neigh = (u16*)(g_all + NN);                        // NM*NH bf16 (4 MB)
    float* cst   = (float*)(neigh + (size_t)NM * NH);         // 64 floats
    float* out   = (float*)d_out;

    precomp_kernel<<<1, 32, 0, stream>>>(W_p2, av, cst);

    level0_kernel<<<NM / 32, 512, 0, stream>>>(delay, W_pi1, b_pi1, W_pi2, b_pi2,
                                               av, h_all, g_all);

    for (int level = 1; level < NL; ++level) {
        attn_kernel<<<NM / 4, 256, 0, stream>>>(h_all, g_all, bit_pos, nbr_idx,
                                                W_p1, b_p1, cst, neigh, level);
        mlp_n_kernel<<<NM / 16, 256, 0, stream>>>(neigh, W_n1, b_n1, W_n2, b_n2,
                                                  is_po, av, h_all, g_all, level);
    }

    final_kernel<<<NM / 8, 256, 0, stream>>>(h_all + (size_t)(NN - NM) * NH, po_feat,
                                             W_g1, b_g1, W_g2, b_g2,
                                             W_o1, b_o1, W_o2, b_o2, out);
}

// Round 15
// 346.155 us; speedup vs baseline: 3.8483x; 1.0927x over previous
//
#include <hip/hip_runtime.h>

#define NL 8
#define NM 8192
#define ND 16
#define NH 256
#define NF 64
#define NN (NL * NM)

typedef unsigned short u16;

__device__ __forceinline__ float lrelu(float x) { return fmaxf(x, 0.1f * x); }

__device__ __forceinline__ u16 f2bf(float x) {
    union { float f; unsigned int u; } v; v.f = x;
    unsigned int r = (v.u + 0x7FFFu + ((v.u >> 16) & 1u)) >> 16;
    return (u16)r;
}
__device__ __forceinline__ ushort4 f4_to_bf4(float4 o) {
    ushort4 r; r.x = f2bf(o.x); r.y = f2bf(o.y); r.z = f2bf(o.z); r.w = f2bf(o.w);
    return r;
}
__device__ __forceinline__ float2 bfp(unsigned int u) {
    union { unsigned int u; float f; } lo, hi;
    lo.u = u << 16; hi.u = u & 0xFFFF0000u;
    return make_float2(lo.f, hi.f);
}

// ---------- precompute attention constants: cst[32..63] = W_p2 @ av_p ----------
__global__ void precomp_kernel(const float* __restrict__ W_p2, const float* __restrict__ av,
                               float* __restrict__ cst)
{
    int j = threadIdx.x;   // 32 threads
    float w = 0.f;
    for (int k = 0; k < 32; ++k) w += W_p2[j * 32 + k] * av[32 + k];
    cst[32 + j] = w;
}

// ---------- Level 0: h = mlp_pi(delay) (bf16 store) + g epilogue ----------
__global__ __launch_bounds__(512) void level0_kernel(
    const float* __restrict__ delay,
    const float* __restrict__ W1, const float* __restrict__ b1,
    const float* __restrict__ W2, const float* __restrict__ b2,
    const float* __restrict__ av,
    u16* __restrict__ h_all, float* __restrict__ g_all)
{
    const int tid = threadIdx.x;
    const int row0 = blockIdx.x * 32;
    __shared__ __align__(16) float sH[32][132];

    for (int x = tid; x < 32 * 128; x += 512) {
        int r = x >> 7, j = x & 127;
        sH[r][j] = lrelu(delay[row0 + r] * W1[j] + b1[j]);
    }
    __syncthreads();

    const int tj = tid & 63, tr = tid >> 6;
    const float4 av4 = *(const float4*)(av + 64 + tj * 4);
    float acc[4][4];
    #pragma unroll
    for (int a = 0; a < 4; ++a)
        #pragma unroll
        for (int b = 0; b < 4; ++b) acc[a][b] = 0.f;

    for (int k = 0; k < 128; k += 4) {
        float4 w0 = *(const float4*)(W2 + (size_t)(k + 0) * 256 + tj * 4);
        float4 w1 = *(const float4*)(W2 + (size_t)(k + 1) * 256 + tj * 4);
        float4 w2 = *(const float4*)(W2 + (size_t)(k + 2) * 256 + tj * 4);
        float4 w3 = *(const float4*)(W2 + (size_t)(k + 3) * 256 + tj * 4);
        #pragma unroll
        for (int rr = 0; rr < 4; ++rr) {
            float4 xv = *(const float4*)(&sH[tr * 4 + rr][k]);
            acc[rr][0] += xv.x * w0.x + xv.y * w1.x + xv.z * w2.x + xv.w * w3.x;
            acc[rr][1] += xv.x * w0.y + xv.y * w1.y + xv.z * w2.y + xv.w * w3.y;
            acc[rr][2] += xv.x * w0.z + xv.y * w1.z + xv.z * w2.z + xv.w * w3.z;
            acc[rr][3] += xv.x * w0.w + xv.y * w1.w + xv.z * w2.w + xv.w * w3.w;
        }
    }
    float4 bv = *(const float4*)(b2 + tj * 4);
    #pragma unroll
    for (int rr = 0; rr < 4; ++rr) {
        const int row = row0 + tr * 4 + rr;
        float4 o;
        o.x = acc[rr][0] + bv.x; o.y = acc[rr][1] + bv.y;
        o.z = acc[rr][2] + bv.z; o.w = acc[rr][3] + bv.w;
        *(ushort4*)(h_all + (size_t)row * NH + tj * 4) = f4_to_bf4(o);
        float gp = o.x * av4.x + o.y * av4.y + o.z * av4.z + o.w * av4.w;
        #pragma unroll
        for (int off = 1; off < 64; off <<= 1) gp += __shfl_xor(gp, off);
        if (tj == 0) g_all[row] = gp;
    }
}

// ---------- Attention: 1 wave per m; g-gather alpha + single 16B-load streamed pass ----------
__global__ __launch_bounds__(256) void attn_kernel(
    const u16* __restrict__ h_all, const float* __restrict__ g_all,
    const float* __restrict__ bit_pos, const int* __restrict__ nbr_idx,
    const float* __restrict__ W_p1, const float* __restrict__ b_p1,
    const float* __restrict__ cst,
    u16* __restrict__ neigh, int level)
{
    const int w = threadIdx.x >> 6, lane = threadIdx.x & 63;
    const int m = blockIdx.x * 4 + w;
    const int d = lane & 15, jj = lane >> 4;
    const size_t ebase = ((size_t)(level - 1) * NM + m) * ND;

    const int   idx = nbr_idx[ebase + d];
    const float bp  = bit_pos[ebase + d];

    float ep = 0.f;
    #pragma unroll
    for (int t = 0; t < 8; ++t) {
        int j = jj * 8 + t;
        ep += cst[32 + j] * lrelu(bp * W_p1[j] + b_p1[j]);
    }
    ep += __shfl_xor(ep, 16);
    ep += __shfl_xor(ep, 32);

    float e = g_all[idx] + ep;
    float mx = e;
    #pragma unroll
    for (int off = 1; off < 16; off <<= 1) mx = fmaxf(mx, __shfl_xor(mx, off));
    float wexp = __expf(e - mx);
    float s = wexp;
    #pragma unroll
    for (int off = 1; off < 16; off <<= 1) s += __shfl_xor(s, off);
    const float alpha = wexp / s;

    const int rh = lane >> 5, cl = lane & 31;
    float4 a0 = make_float4(0.f, 0.f, 0.f, 0.f);
    float4 a1 = make_float4(0.f, 0.f, 0.f, 0.f);
    #pragma unroll
    for (int t = 0; t < 8; ++t) {
        const int d2 = t * 2 + rh;
        float a = __shfl(alpha, d2);
        int   r = __shfl(idx, d2);
        uint4 hv = *(const uint4*)(h_all + (size_t)r * NH + cl * 8);
        float2 p0 = bfp(hv.x), p1 = bfp(hv.y), p2 = bfp(hv.z), p3 = bfp(hv.w);
        a0.x += a * p0.x; a0.y += a * p0.y; a0.z += a * p1.x; a0.w += a * p1.y;
        a1.x += a * p2.x; a1.y += a * p2.y; a1.z += a * p3.x; a1.w += a * p3.y;
    }
    a0.x += __shfl_xor(a0.x, 32); a0.y += __shfl_xor(a0.y, 32);
    a0.z += __shfl_xor(a0.z, 32); a0.w += __shfl_xor(a0.w, 32);
    a1.x += __shfl_xor(a1.x, 32); a1.y += __shfl_xor(a1.y, 32);
    a1.z += __shfl_xor(a1.z, 32); a1.w += __shfl_xor(a1.w, 32);

    float4 outv = (rh == 0) ? a0 : a1;
    *(ushort4*)(neigh + (size_t)m * NH + cl * 8 + rh * 4) = f4_to_bf4(outv);
}

// ---------- Neighborhood MLP: 256 thr / 16 rows / 512 blocks; bf16 neigh, f32 LDS ----------
__global__ __launch_bounds__(256) void mlp_n_kernel(
    const u16* __restrict__ neigh,
    const float* __restrict__ W1, const float* __restrict__ b1,
    const float* __restrict__ W2, const float* __restrict__ b2,
    const int* __restrict__ is_po, const float* __restrict__ av,
    u16* __restrict__ h_all, float* __restrict__ g_all, int level)
{
    const int tid = threadIdx.x;
    const int w = tid >> 6, lane = tid & 63;
    const int row0 = blockIdx.x * 16;
    __shared__ __align__(16) float sX[16][NH + 4];   // stride 260 (mod32=4)
    __shared__ __align__(16) float sH[16][132];      // stride 132 (mod32=4)
    __shared__ float gpart[4][16];

    // stage: bf16 -> f32 once, outside the K-loops
    for (int x = tid; x < 16 * 32; x += 256) {
        int r = x >> 5, c = x & 31;
        uint4 nv = *(const uint4*)(neigh + (size_t)(row0 + r) * NH + c * 8);
        float2 p0 = bfp(nv.x), p1 = bfp(nv.y), p2 = bfp(nv.z), p3 = bfp(nv.w);
        float* dst = &sX[r][c * 8];
        dst[0] = p0.x; dst[1] = p0.y; dst[2] = p1.x; dst[3] = p1.y;
        dst[4] = p2.x; dst[5] = p2.y; dst[6] = p3.x; dst[7] = p3.y;
    }
    __syncthreads();

    // layer 1: (16x256)@(256x128); wave w -> cols [w*32, w*32+32)
    {
        const int tj = lane & 7, tr = lane >> 3;
        const int c0 = w * 32 + tj * 4;
        float acc[2][4];
        #pragma unroll
        for (int a = 0; a < 2; ++a)
            #pragma unroll
            for (int b = 0; b < 4; ++b) acc[a][b] = 0.f;

        for (int k = 0; k < NH; k += 4) {
            float4 w0 = *(const float4*)(W1 + (size_t)(k + 0) * 128 + c0);
            float4 w1 = *(const float4*)(W1 + (size_t)(k + 1) * 128 + c0);
            float4 w2 = *(const float4*)(W1 + (size_t)(k + 2) * 128 + c0);
            float4 w3 = *(const float4*)(W1 + (size_t)(k + 3) * 128 + c0);
            #pragma unroll
            for (int rr = 0; rr < 2; ++rr) {
                float4 xv = *(const float4*)(&sX[tr * 2 + rr][k]);
                acc[rr][0] += xv.x * w0.x + xv.y * w1.x + xv.z * w2.x + xv.w * w3.x;
                acc[rr][1] += xv.x * w0.y + xv.y * w1.y + xv.z * w2.y + xv.w * w3.y;
                acc[rr][2] += xv.x * w0.z + xv.y * w1.z + xv.z * w2.z + xv.w * w3.z;
                acc[rr][3] += xv.x * w0.w + xv.y * w1.w + xv.z * w2.w + xv.w * w3.w;
            }
        }
        float4 bv = *(const float4*)(b1 + c0);
        #pragma unroll
        for (int rr = 0; rr < 2; ++rr) {
            float4 o;
            o.x = lrelu(acc[rr][0] + bv.x); o.y = lrelu(acc[rr][1] + bv.y);
            o.z = lrelu(acc[rr][2] + bv.z); o.w = lrelu(acc[rr][3] + bv.w);
            *(float4*)(&sH[tr * 2 + rr][c0]) = o;
        }
    }
    __syncthreads();

    // layer 2: (16x128)@(128x256); wave w -> cols [w*64, w*64+64)
    {
        const int tj = lane & 15, tr = lane >> 4;
        const int c0 = w * 64 + tj * 4;
        const float4 av4 = *(const float4*)(av + 64 + c0);
        float acc[4][4];
        #pragma unroll
        for (int a = 0; a < 4; ++a)
            #pragma unroll
            for (int b = 0; b < 4; ++b) acc[a][b] = 0.f;

        for (int k = 0; k < 128; k += 4) {
            float4 w0 = *(const float4*)(W2 + (size_t)(k + 0) * 256 + c0);
            float4 w1 = *(const float4*)(W2 + (size_t)(k + 1) * 256 + c0);
            float4 w2 = *(const float4*)(W2 + (size_t)(k + 2) * 256 + c0);
            float4 w3 = *(const float4*)(W2 + (size_t)(k + 3) * 256 + c0);
            #pragma unroll
            for (int rr = 0; rr < 4; ++rr) {
                float4 xv = *(const float4*)(&sH[tr * 4 + rr][k]);
                acc[rr][0] += xv.x * w0.x + xv.y * w1.x + xv.z * w2.x + xv.w * w3.x;
                acc[rr][1] += xv.x * w0.y + xv.y * w1.y + xv.z * w2.y + xv.w * w3.y;
                acc[rr][2] += xv.x * w0.z + xv.y * w1.z + xv.z * w2.z + xv.w * w3.z;
                acc[rr][3] += xv.x * w0.w + xv.y * w1.w + xv.z * w2.w + xv.w * w3.w;
            }
        }
        float4 bv = *(const float4*)(b2 + c0);
        #pragma unroll
        for (int rr = 0; rr < 4; ++rr) {
            const int gm = level * NM + row0 + tr * 4 + rr;
            bool po = (is_po[gm] == 1);
            float4 o;
            o.x = acc[rr][0] + bv.x; o.y = acc[rr][1] + bv.y;
            o.z = acc[rr][2] + bv.z; o.w = acc[rr][3] + bv.w;
            if (!po) {
                o.x = fmaxf(o.x, 0.f); o.y = fmaxf(o.y, 0.f);
                o.z = fmaxf(o.z, 0.f); o.w = fmaxf(o.w, 0.f);
            }
            *(ushort4*)(h_all + (size_t)gm * NH + c0) = f4_to_bf4(o);
            float gp = o.x * av4.x + o.y * av4.y + o.z * av4.z + o.w * av4.w;
            gp += __shfl_xor(gp, 1); gp += __shfl_xor(gp, 2);
            gp += __shfl_xor(gp, 4); gp += __shfl_xor(gp, 8);
            if (tj == 0) gpart[w][tr * 4 + rr] = gp;
        }
    }
    __syncthreads();
    if (tid < 16)
        g_all[level * NM + row0 + tid] =
            gpart[0][tid] + gpart[1][tid] + gpart[2][tid] + gpart[3][tid];
}

// ---------- Final readout (r9-exact, proven 55 us): 256 thr / 16 rows / 512 blocks ----------
__global__ __launch_bounds__(256) void final_kernel(
    const u16* __restrict__ h_gnn, const float* __restrict__ po_feat,
    const float* __restrict__ Wg1, const float* __restrict__ bg1,
    const float* __restrict__ Wg2, const float* __restrict__ bg2,
    const float* __restrict__ Wo1, const float* __restrict__ bo1,
    const float* __restrict__ Wo2, const float* __restrict__ bo2,
    float* __restrict__ out)
{
    const int tid = threadIdx.x;
    const int w = tid >> 6, lane = tid & 63;
    const int row0 = blockIdx.x * 16;
    __shared__ __align__(16) float sx[16][516];   // stride 516 (mod32=4)
    __shared__ __align__(16) float sg[16][132];
    __shared__ float part[4][16];

    for (int x = tid; x < 16 * 32; x += 256) {
        int r = x >> 5, c = x & 31;
        uint4 hv = *(const uint4*)(h_gnn + (size_t)(row0 + r) * NH + c * 8);
        float2 p0 = bfp(hv.x), p1 = bfp(hv.y), p2 = bfp(hv.z), p3 = bfp(hv.w);
        float* dst = &sx[r][c * 8];
        dst[0] = p0.x; dst[1] = p0.y; dst[2] = p1.x; dst[3] = p1.y;
        dst[4] = p2.x; dst[5] = p2.y; dst[6] = p3.x; dst[7] = p3.y;
    }
    for (int x = tid; x < 16 * 128; x += 256) {
        int r = x >> 7, j = x & 127;
        sg[r][j] = lrelu(po_feat[row0 + r] * Wg1[j] + bg1[j]);
    }
    __syncthreads();

    // h_global = sg @ Wg2 + bg2 -> sx[:, 256:]; wave w -> cols [w*64, w*64+64)
    {
        const int tj = lane & 15, tr = lane >> 4;
        const int c0 = w * 64 + tj * 4;
        float acc[4][4];
        #pragma unroll
        for (int a = 0; a < 4; ++a)
            #pragma unroll
            for (int b = 0; b < 4; ++b) acc[a][b] = 0.f;

        for (int k = 0; k < 128; k += 4) {
            float4 w0 = *(const float4*)(Wg2 + (size_t)(k + 0) * 256 + c0);
            float4 w1 = *(const float4*)(Wg2 + (size_t)(k + 1) * 256 + c0);
            float4 w2 = *(const float4*)(Wg2 + (size_t)(k + 2) * 256 + c0);
            float4 w3 = *(const float4*)(Wg2 + (size_t)(k + 3) * 256 + c0);
            #pragma unroll
            for (int rr = 0; rr < 4; ++rr) {
                float4 xv = *(const float4*)(&sg[tr * 4 + rr][k]);
                acc[rr][0] += xv.x * w0.x + xv.y * w1.x + xv.z * w2.x + xv.w * w3.x;
                acc[rr][1] += xv.x * w0.y + xv.y * w1.y + xv.z * w2.y + xv.w * w3.y;
                acc[rr][2] += xv.x * w0.z + xv.y * w1.z + xv.z * w2.z + xv.w * w3.z;
                acc[rr][3] += xv.x * w0.w + xv.y * w1.w + xv.z * w2.w + xv.w * w3.w;
            }
        }
        float4 bv = *(const float4*)(bg2 + c0);
        #pragma unroll
        for (int rr = 0; rr < 4; ++rr) {
            float4 o;
            o.x = acc[rr][0] + bv.x; o.y = acc[rr][1] + bv.y;
            o.z = acc[rr][2] + bv.z; o.w = acc[rr][3] + bv.w;
            *(float4*)(&sx[tr * 4 + rr][256 + c0]) = o;
        }
    }
    __syncthreads();

    // o1 = lrelu(sx @ Wo1 + bo1), K=512, col-split; fused partial dot with Wo2
    {
        const int tj = lane & 15, tr = lane >> 4;
        const int c0 = w * 64 + tj * 4;
        float acc[4][4];
        #pragma unroll
        for (int a = 0; a < 4; ++a)
            #pragma unroll
            for (int b = 0; b < 4; ++b) acc[a][b] = 0.f;

        for (int k = 0; k < 512; k += 4) {
            float4 w0 = *(const float4*)(Wo1 + (size_t)(k + 0) * 256 + c0);
            float4 w1 = *(const float4*)(Wo1 + (size_t)(k + 1) * 256 + c0);
            float4 w2 = *(const float4*)(Wo1 + (size_t)(k + 2) * 256 + c0);
            float4 w3 = *(const float4*)(Wo1 + (size_t)(k + 3) * 256 + c0);
            #pragma unroll
            for (int rr = 0; rr < 4; ++rr) {
                float4 xv = *(const float4*)(&sx[tr * 4 + rr][k]);
                acc[rr][0] += xv.x * w0.x + xv.y * w1.x + xv.z * w2.x + xv.w * w3.x;
                acc[rr][1] += xv.x * w0.y + xv.y * w1.y + xv.z * w2.y + xv.w * w3.y;
                acc[rr][2] += xv.x * w0.z + xv.y * w1.z + xv.z * w2.z + xv.w * w3.z;
                acc[rr][3] += xv.x * w0.w + xv.y * w1.w + xv.z * w2.w + xv.w * w3.w;
            }
        }
        float4 bv = *(const float4*)(bo1 + c0);
        float4 wv = *(const float4*)(Wo2 + c0);
        #pragma unroll
        for (int rr = 0; rr < 4; ++rr) {
            float pc = lrelu(acc[rr][0] + bv.x) * wv.x
                     + lrelu(acc[rr][1] + bv.y) * wv.y
                     + lrelu(acc[rr][2] + bv.z) * wv.z
                     + lrelu(acc[rr][3] + bv.w) * wv.w;
            pc += __shfl_xor(pc, 1); pc += __shfl_xor(pc, 2);
            pc += __shfl_xor(pc, 4); pc += __shfl_xor(pc, 8);
            if (tj == 0) part[w][tr * 4 + rr] = pc;
        }
    }
    __syncthreads();
    if (tid < 16)
        out[row0 + tid] = part[0][tid] + part[1][tid] + part[2][tid] + part[3][tid] + bo2[0];
}

extern "C" void kernel_launch(void* const* d_in, const int* in_sizes, int n_in,
                              void* d_out, int out_size, void* d_ws, size_t ws_size,
                              hipStream_t stream) {
    const float* W_pi1 = (const float*)d_in[0];
    const float* b_pi1 = (const float*)d_in[1];
    const float* W_pi2 = (const float*)d_in[2];
    const float* b_pi2 = (const float*)d_in[3];
    const float* W_p1  = (const float*)d_in[8];
    const float* b_p1  = (const float*)d_in[9];
    const float* W_p2  = (const float*)d_in[10];
    const float* W_n1  = (const float*)d_in[12];
    const float* b_n1  = (const float*)d_in[13];
    const float* W_n2  = (const float*)d_in[14];
    const float* b_n2  = (const float*)d_in[15];
    const float* W_g1  = (const float*)d_in[16];
    const float* b_g1  = (const float*)d_in[17];
    const float* W_g2  = (const float*)d_in[18];
    const float* b_g2  = (const float*)d_in[19];
    const float* W_o1  = (const float*)d_in[20];
    const float* b_o1  = (const float*)d_in[21];
    const float* W_o2  = (const float*)d_in[22];
    const float* b_o2  = (const float*)d_in[23];
    const float* av    = (const float*)d_in[24];
    const float* delay = (const float*)d_in[26];
    const float* bit_pos = (const float*)d_in[27];
    const float* po_feat = (const float*)d_in[28];
    const int*   is_po   = (const int*)d_in[29];
    const int*   nbr_idx = (const int*)d_in[30];

    u16*   h_all = (u16*)d_ws;                                // NN*NH bf16 (33.5 MB)
    float* g_all = (float*)(h_all + (size_t)NN * NH);         // NN floats
    u16*   neigh = (u16*)(g_all + NN);                        // NM*NH bf16 (4 MB)
    float* cst   = (float*)(neigh + (size_t)NM * NH);         // 64 floats
    float* out   = (float*)d_out;

    precomp_kernel<<<1, 32, 0, stream>>>(W_p2, av, cst);

    level0_kernel<<<NM / 32, 512, 0, stream>>>(delay, W_pi1, b_pi1, W_pi2, b_pi2,
                                               av, h_all, g_all);

    for (int level = 1; level < NL; ++level) {
        attn_kernel<<<NM / 4, 256, 0, stream>>>(h_all, g_all, bit_pos, nbr_idx,
                                                W_p1, b_p1, cst, neigh, level);
        mlp_n_kernel<<<NM / 16, 256, 0, stream>>>(neigh, W_n1, b_n1, W_n2, b_n2,
                                                  is_po, av, h_all, g_all, level);
    }

    final_kernel<<<NM / 16, 256, 0, stream>>>(h_all + (size_t)(NN - NM) * NH, po_feat,
                                              W_g1, b_g1, W_g2, b_g2,
                                              W_o1, b_o1, W_o2, b_o2, out);
}

// Round 16
// 333.930 us; speedup vs baseline: 3.9892x; 1.0366x over previous
//
#include <hip/hip_runtime.h>

#define NL 8
#define NM 8192
#define ND 16
#define NH 256
#define NF 64
#define NN (NL * NM)

typedef unsigned short u16;
typedef __attribute__((ext_vector_type(8))) short bf16x8;
typedef __attribute__((ext_vector_type(4))) float f32x4;

__device__ __forceinline__ float lrelu(float x) { return fmaxf(x, 0.1f * x); }

__device__ __forceinline__ u16 f2bf(float x) {
    union { float f; unsigned int u; } v; v.f = x;
    unsigned int r = (v.u + 0x7FFFu + ((v.u >> 16) & 1u)) >> 16;
    return (u16)r;
}
__device__ __forceinline__ ushort4 f4_to_bf4(float4 o) {
    ushort4 r; r.x = f2bf(o.x); r.y = f2bf(o.y); r.z = f2bf(o.z); r.w = f2bf(o.w);
    return r;
}
__device__ __forceinline__ float2 bfp(unsigned int u) {
    union { unsigned int u; float f; } lo, hi;
    lo.u = u << 16; hi.u = u & 0xFFFF0000u;
    return make_float2(lo.f, hi.f);
}

// ---------- precompute attention constants: cst[32..63] = W_p2 @ av_p ----------
__global__ void precomp_kernel(const float* __restrict__ W_p2, const float* __restrict__ av,
                               float* __restrict__ cst)
{
    int j = threadIdx.x;   // 32 threads
    float w = 0.f;
    for (int k = 0; k < 32; ++k) w += W_p2[j * 32 + k] * av[32 + k];
    cst[32 + j] = w;
}

// ---------- prep: Wo1t (bf16, [256][512]) = transpose(Wo1 [512][256]) ----------
// grid 128 = 8 n-tiles x 16 k-tiles; 256 thr; LDS-tiled for coalescing both sides
__global__ __launch_bounds__(256) void prep_wo1t_kernel(
    const float* __restrict__ Wo1, u16* __restrict__ Wo1t)
{
    const int bn = blockIdx.x & 7, bk = blockIdx.x >> 3;
    const int n0 = bn * 32, k0 = bk * 32;
    const int tn = threadIdx.x & 31, tk4 = threadIdx.x >> 5;   // 8 k/n rows per pass
    __shared__ float t[32][33];
    #pragma unroll
    for (int i = 0; i < 4; ++i) {
        int k = tk4 + i * 8;
        t[k][tn] = Wo1[(size_t)(k0 + k) * 256 + n0 + tn];
    }
    __syncthreads();
    #pragma unroll
    for (int i = 0; i < 4; ++i) {
        int n = tk4 + i * 8;
        Wo1t[(size_t)(n0 + n) * 512 + k0 + tn] = f2bf(t[tn][n]);
    }
}

// ---------- Level 0: h = mlp_pi(delay) (bf16 store) + g epilogue ----------
__global__ __launch_bounds__(512) void level0_kernel(
    const float* __restrict__ delay,
    const float* __restrict__ W1, const float* __restrict__ b1,
    const float* __restrict__ W2, const float* __restrict__ b2,
    const float* __restrict__ av,
    u16* __restrict__ h_all, float* __restrict__ g_all)
{
    const int tid = threadIdx.x;
    const int row0 = blockIdx.x * 32;
    __shared__ __align__(16) float sH[32][132];

    for (int x = tid; x < 32 * 128; x += 512) {
        int r = x >> 7, j = x & 127;
        sH[r][j] = lrelu(delay[row0 + r] * W1[j] + b1[j]);
    }
    __syncthreads();

    const int tj = tid & 63, tr = tid >> 6;
    const float4 av4 = *(const float4*)(av + 64 + tj * 4);
    float acc[4][4];
    #pragma unroll
    for (int a = 0; a < 4; ++a)
        #pragma unroll
        for (int b = 0; b < 4; ++b) acc[a][b] = 0.f;

    for (int k = 0; k < 128; k += 4) {
        float4 w0 = *(const float4*)(W2 + (size_t)(k + 0) * 256 + tj * 4);
        float4 w1 = *(const float4*)(W2 + (size_t)(k + 1) * 256 + tj * 4);
        float4 w2 = *(const float4*)(W2 + (size_t)(k + 2) * 256 + tj * 4);
        float4 w3 = *(const float4*)(W2 + (size_t)(k + 3) * 256 + tj * 4);
        #pragma unroll
        for (int rr = 0; rr < 4; ++rr) {
            float4 xv = *(const float4*)(&sH[tr * 4 + rr][k]);
            acc[rr][0] += xv.x * w0.x + xv.y * w1.x + xv.z * w2.x + xv.w * w3.x;
            acc[rr][1] += xv.x * w0.y + xv.y * w1.y + xv.z * w2.y + xv.w * w3.y;
            acc[rr][2] += xv.x * w0.z + xv.y * w1.z + xv.z * w2.z + xv.w * w3.z;
            acc[rr][3] += xv.x * w0.w + xv.y * w1.w + xv.z * w2.w + xv.w * w3.w;
        }
    }
    float4 bv = *(const float4*)(b2 + tj * 4);
    #pragma unroll
    for (int rr = 0; rr < 4; ++rr) {
        const int row = row0 + tr * 4 + rr;
        float4 o;
        o.x = acc[rr][0] + bv.x; o.y = acc[rr][1] + bv.y;
        o.z = acc[rr][2] + bv.z; o.w = acc[rr][3] + bv.w;
        *(ushort4*)(h_all + (size_t)row * NH + tj * 4) = f4_to_bf4(o);
        float gp = o.x * av4.x + o.y * av4.y + o.z * av4.z + o.w * av4.w;
        #pragma unroll
        for (int off = 1; off < 64; off <<= 1) gp += __shfl_xor(gp, off);
        if (tj == 0) g_all[row] = gp;
    }
}

// ---------- Attention: 1 wave per m; g-gather alpha + single 16B-load streamed pass ----------
__global__ __launch_bounds__(256) void attn_kernel(
    const u16* __restrict__ h_all, const float* __restrict__ g_all,
    const float* __restrict__ bit_pos, const int* __restrict__ nbr_idx,
    const float* __restrict__ W_p1, const float* __restrict__ b_p1,
    const float* __restrict__ cst,
    u16* __restrict__ neigh, int level)
{
    const int w = threadIdx.x >> 6, lane = threadIdx.x & 63;
    const int m = blockIdx.x * 4 + w;
    const int d = lane & 15, jj = lane >> 4;
    const size_t ebase = ((size_t)(level - 1) * NM + m) * ND;

    const int   idx = nbr_idx[ebase + d];
    const float bp  = bit_pos[ebase + d];

    float ep = 0.f;
    #pragma unroll
    for (int t = 0; t < 8; ++t) {
        int j = jj * 8 + t;
        ep += cst[32 + j] * lrelu(bp * W_p1[j] + b_p1[j]);
    }
    ep += __shfl_xor(ep, 16);
    ep += __shfl_xor(ep, 32);

    float e = g_all[idx] + ep;
    float mx = e;
    #pragma unroll
    for (int off = 1; off < 16; off <<= 1) mx = fmaxf(mx, __shfl_xor(mx, off));
    float wexp = __expf(e - mx);
    float s = wexp;
    #pragma unroll
    for (int off = 1; off < 16; off <<= 1) s += __shfl_xor(s, off);
    const float alpha = wexp / s;

    const int rh = lane >> 5, cl = lane & 31;
    float4 a0 = make_float4(0.f, 0.f, 0.f, 0.f);
    float4 a1 = make_float4(0.f, 0.f, 0.f, 0.f);
    #pragma unroll
    for (int t = 0; t < 8; ++t) {
        const int d2 = t * 2 + rh;
        float a = __shfl(alpha, d2);
        int   r = __shfl(idx, d2);
        uint4 hv = *(const uint4*)(h_all + (size_t)r * NH + cl * 8);
        float2 p0 = bfp(hv.x), p1 = bfp(hv.y), p2 = bfp(hv.z), p3 = bfp(hv.w);
        a0.x += a * p0.x; a0.y += a * p0.y; a0.z += a * p1.x; a0.w += a * p1.y;
        a1.x += a * p2.x; a1.y += a * p2.y; a1.z += a * p3.x; a1.w += a * p3.y;
    }
    a0.x += __shfl_xor(a0.x, 32); a0.y += __shfl_xor(a0.y, 32);
    a0.z += __shfl_xor(a0.z, 32); a0.w += __shfl_xor(a0.w, 32);
    a1.x += __shfl_xor(a1.x, 32); a1.y += __shfl_xor(a1.y, 32);
    a1.z += __shfl_xor(a1.z, 32); a1.w += __shfl_xor(a1.w, 32);

    float4 outv = (rh == 0) ? a0 : a1;
    *(ushort4*)(neigh + (size_t)m * NH + cl * 8 + rh * 4) = f4_to_bf4(outv);
}

// ---------- Neighborhood MLP: 256 thr / 16 rows / 512 blocks; bf16 neigh, f32 LDS ----------
__global__ __launch_bounds__(256) void mlp_n_kernel(
    const u16* __restrict__ neigh,
    const float* __restrict__ W1, const float* __restrict__ b1,
    const float* __restrict__ W2, const float* __restrict__ b2,
    const int* __restrict__ is_po, const float* __restrict__ av,
    u16* __restrict__ h_all, float* __restrict__ g_all, int level)
{
    const int tid = threadIdx.x;
    const int w = tid >> 6, lane = tid & 63;
    const int row0 = blockIdx.x * 16;
    __shared__ __align__(16) float sX[16][NH + 4];   // stride 260 (mod32=4)
    __shared__ __align__(16) float sH[16][132];      // stride 132 (mod32=4)
    __shared__ float gpart[4][16];

    for (int x = tid; x < 16 * 32; x += 256) {
        int r = x >> 5, c = x & 31;
        uint4 nv = *(const uint4*)(neigh + (size_t)(row0 + r) * NH + c * 8);
        float2 p0 = bfp(nv.x), p1 = bfp(nv.y), p2 = bfp(nv.z), p3 = bfp(nv.w);
        float* dst = &sX[r][c * 8];
        dst[0] = p0.x; dst[1] = p0.y; dst[2] = p1.x; dst[3] = p1.y;
        dst[4] = p2.x; dst[5] = p2.y; dst[6] = p3.x; dst[7] = p3.y;
    }
    __syncthreads();

    // layer 1: (16x256)@(256x128); wave w -> cols [w*32, w*32+32)
    {
        const int tj = lane & 7, tr = lane >> 3;
        const int c0 = w * 32 + tj * 4;
        float acc[2][4];
        #pragma unroll
        for (int a = 0; a < 2; ++a)
            #pragma unroll
            for (int b = 0; b < 4; ++b) acc[a][b] = 0.f;

        for (int k = 0; k < NH; k += 4) {
            float4 w0 = *(const float4*)(W1 + (size_t)(k + 0) * 128 + c0);
            float4 w1 = *(const float4*)(W1 + (size_t)(k + 1) * 128 + c0);
            float4 w2 = *(const float4*)(W1 + (size_t)(k + 2) * 128 + c0);
            float4 w3 = *(const float4*)(W1 + (size_t)(k + 3) * 128 + c0);
            #pragma unroll
            for (int rr = 0; rr < 2; ++rr) {
                float4 xv = *(const float4*)(&sX[tr * 2 + rr][k]);
                acc[rr][0] += xv.x * w0.x + xv.y * w1.x + xv.z * w2.x + xv.w * w3.x;
                acc[rr][1] += xv.x * w0.y + xv.y * w1.y + xv.z * w2.y + xv.w * w3.y;
                acc[rr][2] += xv.x * w0.z + xv.y * w1.z + xv.z * w2.z + xv.w * w3.z;
                acc[rr][3] += xv.x * w0.w + xv.y * w1.w + xv.z * w2.w + xv.w * w3.w;
            }
        }
        float4 bv = *(const float4*)(b1 + c0);
        #pragma unroll
        for (int rr = 0; rr < 2; ++rr) {
            float4 o;
            o.x = lrelu(acc[rr][0] + bv.x); o.y = lrelu(acc[rr][1] + bv.y);
            o.z = lrelu(acc[rr][2] + bv.z); o.w = lrelu(acc[rr][3] + bv.w);
            *(float4*)(&sH[tr * 2 + rr][c0]) = o;
        }
    }
    __syncthreads();

    // layer 2: (16x128)@(128x256); wave w -> cols [w*64, w*64+64)
    {
        const int tj = lane & 15, tr = lane >> 4;
        const int c0 = w * 64 + tj * 4;
        const float4 av4 = *(const float4*)(av + 64 + c0);
        float acc[4][4];
        #pragma unroll
        for (int a = 0; a < 4; ++a)
            #pragma unroll
            for (int b = 0; b < 4; ++b) acc[a][b] = 0.f;

        for (int k = 0; k < 128; k += 4) {
            float4 w0 = *(const float4*)(W2 + (size_t)(k + 0) * 256 + c0);
            float4 w1 = *(const float4*)(W2 + (size_t)(k + 1) * 256 + c0);
            float4 w2 = *(const float4*)(W2 + (size_t)(k + 2) * 256 + c0);
            float4 w3 = *(const float4*)(W2 + (size_t)(k + 3) * 256 + c0);
            #pragma unroll
            for (int rr = 0; rr < 4; ++rr) {
                float4 xv = *(const float4*)(&sH[tr * 4 + rr][k]);
                acc[rr][0] += xv.x * w0.x + xv.y * w1.x + xv.z * w2.x + xv.w * w3.x;
                acc[rr][1] += xv.x * w0.y + xv.y * w1.y + xv.z * w2.y + xv.w * w3.y;
                acc[rr][2] += xv.x * w0.z + xv.y * w1.z + xv.z * w2.z + xv.w * w3.z;
                acc[rr][3] += xv.x * w0.w + xv.y * w1.w + xv.z * w2.w + xv.w * w3.w;
            }
        }
        float4 bv = *(const float4*)(b2 + c0);
        #pragma unroll
        for (int rr = 0; rr < 4; ++rr) {
            const int gm = level * NM + row0 + tr * 4 + rr;
            bool po = (is_po[gm] == 1);
            float4 o;
            o.x = acc[rr][0] + bv.x; o.y = acc[rr][1] + bv.y;
            o.z = acc[rr][2] + bv.z; o.w = acc[rr][3] + bv.w;
            if (!po) {
                o.x = fmaxf(o.x, 0.f); o.y = fmaxf(o.y, 0.f);
                o.z = fmaxf(o.z, 0.f); o.w = fmaxf(o.w, 0.f);
            }
            *(ushort4*)(h_all + (size_t)gm * NH + c0) = f4_to_bf4(o);
            float gp = o.x * av4.x + o.y * av4.y + o.z * av4.z + o.w * av4.w;
            gp += __shfl_xor(gp, 1); gp += __shfl_xor(gp, 2);
            gp += __shfl_xor(gp, 4); gp += __shfl_xor(gp, 8);
            if (tj == 0) gpart[w][tr * 4 + rr] = gp;
        }
    }
    __syncthreads();
    if (tid < 16)
        g_all[level * NM + row0 + tid] =
            gpart[0][tid] + gpart[1][tid] + gpart[2][tid] + gpart[3][tid];
}

// ---------- Final readout: stage + f32 Wg2 GEMM + MFMA o1 GEMM (bf16) ----------
__global__ __launch_bounds__(256) void final_kernel(
    const u16* __restrict__ h_gnn, const float* __restrict__ po_feat,
    const float* __restrict__ Wg1, const float* __restrict__ bg1,
    const float* __restrict__ Wg2, const float* __restrict__ bg2,
    const u16* __restrict__ Wo1t, const float* __restrict__ bo1,
    const float* __restrict__ Wo2, const float* __restrict__ bo2,
    float* __restrict__ out)
{
    const int tid = threadIdx.x;
    const int w = tid >> 6, lane = tid & 63;
    const int row0 = blockIdx.x * 16;
    __shared__ __align__(16) u16   sxb[16][520];   // bf16 activations, stride 1040B
    __shared__ __align__(16) float sg[16][132];
    __shared__ float part[4][16];

    // stage h quadrant: raw bf16 copy (no extra rounding)
    for (int x = tid; x < 16 * 32; x += 256) {
        int r = x >> 5, c = x & 31;
        *(uint4*)(&sxb[r][c * 8]) = *(const uint4*)(h_gnn + (size_t)(row0 + r) * NH + c * 8);
    }
    for (int x = tid; x < 16 * 128; x += 256) {
        int r = x >> 7, j = x & 127;
        sg[r][j] = lrelu(po_feat[row0 + r] * Wg1[j] + bg1[j]);
    }
    __syncthreads();

    // h_global = sg @ Wg2 + bg2 (f32) -> sxb[:, 256:] as bf16; wave w -> cols [w*64, w*64+64)
    {
        const int tj = lane & 15, tr = lane >> 4;
        const int c0 = w * 64 + tj * 4;
        float acc[4][4];
        #pragma unroll
        for (int a = 0; a < 4; ++a)
            #pragma unroll
            for (int b = 0; b < 4; ++b) acc[a][b] = 0.f;

        for (int k = 0; k < 128; k += 4) {
            float4 w0 = *(const float4*)(Wg2 + (size_t)(k + 0) * 256 + c0);
            float4 w1 = *(const float4*)(Wg2 + (size_t)(k + 1) * 256 + c0);
            float4 w2 = *(const float4*)(Wg2 + (size_t)(k + 2) * 256 + c0);
            float4 w3 = *(const float4*)(Wg2 + (size_t)(k + 3) * 256 + c0);
            #pragma unroll
            for (int rr = 0; rr < 4; ++rr) {
                float4 xv = *(const float4*)(&sg[tr * 4 + rr][k]);
                acc[rr][0] += xv.x * w0.x + xv.y * w1.x + xv.z * w2.x + xv.w * w3.x;
                acc[rr][1] += xv.x * w0.y + xv.y * w1.y + xv.z * w2.y + xv.w * w3.y;
                acc[rr][2] += xv.x * w0.z + xv.y * w1.z + xv.z * w2.z + xv.w * w3.z;
                acc[rr][3] += xv.x * w0.w + xv.y * w1.w + xv.z * w2.w + xv.w * w3.w;
            }
        }
        float4 bv = *(const float4*)(bg2 + c0);
        #pragma unroll
        for (int rr = 0; rr < 4; ++rr) {
            float4 o;
            o.x = acc[rr][0] + bv.x; o.y = acc[rr][1] + bv.y;
            o.z = acc[rr][2] + bv.z; o.w = acc[rr][3] + bv.w;
            *(ushort4*)(&sxb[tr * 4 + rr][256 + c0]) = f4_to_bf4(o);
        }
    }
    __syncthreads();

    // o1 = lrelu(sxb @ Wo1 + bo1) fused with out = o1 @ Wo2 + bo2  --- via MFMA
    // wave w owns cols [w*64, w*64+64) as 4 tiles of 16; M=16 rows; K=512 in 16 steps of 32.
    // A frag (16x32): lane: row = lane&15, k = (lane>>4)*8 + j  (contiguous bf16 in sxb)
    // B frag (32x16): lane: col = lane&15, k = (lane>>4)*8 + j  (contiguous in Wo1t[n][k])
    // C/D: col = lane&15, row = (lane>>4)*4 + reg   [m89/m91-verified]
    {
        const int krow = lane & 15;
        const int kgrp = lane >> 4;
        f32x4 acc0 = {0.f, 0.f, 0.f, 0.f};
        f32x4 acc1 = {0.f, 0.f, 0.f, 0.f};
        f32x4 acc2 = {0.f, 0.f, 0.f, 0.f};
        f32x4 acc3 = {0.f, 0.f, 0.f, 0.f};

        #pragma unroll 2
        for (int ks = 0; ks < 16; ++ks) {
            const int k0 = ks * 32;
            bf16x8 aF = *(const bf16x8*)(&sxb[krow][k0 + kgrp * 8]);
            const u16* bbase = Wo1t + (size_t)(w * 64 + krow) * 512 + k0 + kgrp * 8;
            bf16x8 b0 = *(const bf16x8*)(bbase);
            bf16x8 b1 = *(const bf16x8*)(bbase + 16 * 512);
            bf16x8 b2 = *(const bf16x8*)(bbase + 32 * 512);
            bf16x8 b3 = *(const bf16x8*)(bbase + 48 * 512);
            acc0 = __builtin_amdgcn_mfma_f32_16x16x32_bf16(aF, b0, acc0, 0, 0, 0);
            acc1 = __builtin_amdgcn_mfma_f32_16x16x32_bf16(aF, b1, acc1, 0, 0, 0);
            acc2 = __builtin_amdgcn_mfma_f32_16x16x32_bf16(aF, b2, acc2, 0, 0, 0);
            acc3 = __builtin_amdgcn_mfma_f32_16x16x32_bf16(aF, b3, acc3, 0, 0, 0);
        }

        // epilogue: p[reg] = sum over this lane's 4 cols of lrelu(o1+bo1)*Wo2
        float p0 = 0.f, p1 = 0.f, p2 = 0.f, p3 = 0.f;
        {
            int c = w * 64 + 0 * 16 + krow;  float b = bo1[c], v = Wo2[c];
            p0 += lrelu(acc0[0] + b) * v; p1 += lrelu(acc0[1] + b) * v;
            p2 += lrelu(acc0[2] + b) * v; p3 += lrelu(acc0[3] + b) * v;
        }
        {
            int c = w * 64 + 1 * 16 + krow;  float b = bo1[c], v = Wo2[c];
            p0 += lrelu(acc1[0] + b) * v; p1 += lrelu(acc1[1] + b) * v;
            p2 += lrelu(acc1[2] + b) * v; p3 += lrelu(acc1[3] + b) * v;
        }
        {
            int c = w * 64 + 2 * 16 + krow;  float b = bo1[c], v = Wo2[c];
            p0 += lrelu(acc2[0] + b) * v; p1 += lrelu(acc2[1] + b) * v;
            p2 += lrelu(acc2[2] + b) * v; p3 += lrelu(acc2[3] + b) * v;
        }
        {
            int c = w * 64 + 3 * 16 + krow;  float b = bo1[c], v = Wo2[c];
            p0 += lrelu(acc3[0] + b) * v; p1 += lrelu(acc3[1] + b) * v;
            p2 += lrelu(acc3[2] + b) * v; p3 += lrelu(acc3[3] + b) * v;
        }
        // reduce across the 16 col-lanes (xor<16 stays within the kgrp group)
        p0 += __shfl_xor(p0, 1); p0 += __shfl_xor(p0, 2); p0 += __shfl_xor(p0, 4); p0 += __shfl_xor(p0, 8);
        p1 += __shfl_xor(p1, 1); p1 += __shfl_xor(p1, 2); p1 += __shfl_xor(p1, 4); p1 += __shfl_xor(p1, 8);
        p2 += __shfl_xor(p2, 1); p2 += __shfl_xor(p2, 2); p2 += __shfl_xor(p2, 4); p2 += __shfl_xor(p2, 8);
        p3 += __shfl_xor(p3, 1); p3 += __shfl_xor(p3, 2); p3 += __shfl_xor(p3, 4); p3 += __shfl_xor(p3, 8);
        if (krow == 0) {
            part[w][kgrp * 4 + 0] = p0;
            part[w][kgrp * 4 + 1] = p1;
            part[w][kgrp * 4 + 2] = p2;
            part[w][kgrp * 4 + 3] = p3;
        }
    }
    __syncthreads();
    if (tid < 16)
        out[row0 + tid] = part[0][tid] + part[1][tid] + part[2][tid] + part[3][tid] + bo2[0];
}

extern "C" void kernel_launch(void* const* d_in, const int* in_sizes, int n_in,
                              void* d_out, int out_size, void* d_ws, size_t ws_size,
                              hipStream_t stream) {
    const float* W_pi1 = (const float*)d_in[0];
    const float* b_pi1 = (const float*)d_in[1];
    const float* W_pi2 = (const float*)d_in[2];
    const float* b_pi2 = (const float*)d_in[3];
    const float* W_p1  = (const float*)d_in[8];
    const float* b_p1  = (const float*)d_in[9];
    const float* W_p2  = (const float*)d_in[10];
    const float* W_n1  = (const float*)d_in[12];
    const float* b_n1  = (const float*)d_in[13];
    const float* W_n2  = (const float*)d_in[14];
    const float* b_n2  = (const float*)d_in[15];
    const float* W_g1  = (const float*)d_in[16];
    const float* b_g1  = (const float*)d_in[17];
    const float* W_g2  = (const float*)d_in[18];
    const float* b_g2  = (const float*)d_in[19];
    const float* W_o1  = (const float*)d_in[20];
    const float* b_o1  = (const float*)d_in[21];
    const float* W_o2  = (const float*)d_in[22];
    const float* b_o2  = (const float*)d_in[23];
    const float* av    = (const float*)d_in[24];
    const float* delay = (const float*)d_in[26];
    const float* bit_pos = (const float*)d_in[27];
    const float* po_feat = (const float*)d_in[28];
    const int*   is_po   = (const int*)d_in[29];
    const int*   nbr_idx = (const int*)d_in[30];

    u16*   h_all = (u16*)d_ws;                                // NN*NH bf16 (33.5 MB)
    float* g_all = (float*)(h_all + (size_t)NN * NH);         // NN floats
    u16*   neigh = (u16*)(g_all + NN);                        // NM*NH bf16 (4 MB)
    float* cst   = (float*)(neigh + (size_t)NM * NH);         // 64 floats
    u16*   Wo1t  = (u16*)(cst + 64);                          // 256*512 bf16 (0.26 MB)
    float* out   = (float*)d_out;

    precomp_kernel<<<1, 32, 0, stream>>>(W_p2, av, cst);
    prep_wo1t_kernel<<<128, 256, 0, stream>>>(W_o1, Wo1t);

    level0_kernel<<<NM / 32, 512, 0, stream>>>(delay, W_pi1, b_pi1, W_pi2, b_pi2,
                                               av, h_all, g_all);

    for (int level = 1; level < NL; ++level) {
        attn_kernel<<<NM / 4, 256, 0, stream>>>(h_all, g_all, bit_pos, nbr_idx,
                                                W_p1, b_p1, cst, neigh, level);
        mlp_n_kernel<<<NM / 16, 256, 0, stream>>>(neigh, W_n1, b_n1, W_n2, b_n2,
                                                  is_po, av, h_all, g_all, level);
    }

    final_kernel<<<NM / 16, 256, 0, stream>>>(h_all + (size_t)(NN - NM) * NH, po_feat,
                                              W_g1, b_g1, W_g2, b_g2,
                                              Wo1t, b_o1, W_o2, b_o2, out);
}

// Round 17
// 260.672 us; speedup vs baseline: 5.1103x; 1.2810x over previous
//
#include <hip/hip_runtime.h>

#define NL 8
#define NM 8192
#define ND 16
#define NH 256
#define NF 64
#define NN (NL * NM)

typedef unsigned short u16;
typedef __attribute__((ext_vector_type(8))) short bf16x8;
typedef __attribute__((ext_vector_type(4))) float f32x4;

__device__ __forceinline__ float lrelu(float x) { return fmaxf(x, 0.1f * x); }

__device__ __forceinline__ u16 f2bf(float x) {
    union { float f; unsigned int u; } v; v.f = x;
    unsigned int r = (v.u + 0x7FFFu + ((v.u >> 16) & 1u)) >> 16;
    return (u16)r;
}
__device__ __forceinline__ ushort4 f4_to_bf4(float4 o) {
    ushort4 r; r.x = f2bf(o.x); r.y = f2bf(o.y); r.z = f2bf(o.z); r.w = f2bf(o.w);
    return r;
}
__device__ __forceinline__ float2 bfp(unsigned int u) {
    union { unsigned int u; float f; } lo, hi;
    lo.u = u << 16; hi.u = u & 0xFFFF0000u;
    return make_float2(lo.f, hi.f);
}

// ---------- precompute attention constants: cst[32..63] = W_p2 @ av_p ----------
__global__ void precomp_kernel(const float* __restrict__ W_p2, const float* __restrict__ av,
                               float* __restrict__ cst)
{
    int j = threadIdx.x;   // 32 threads
    float w = 0.f;
    for (int k = 0; k < 32; ++k) w += W_p2[j * 32 + k] * av[32 + k];
    cst[32 + j] = w;
}

// ---------- generic: out[C][R] (bf16) = transpose(in [R][C] f32) ----------
// grid = (R/32)*(C/32) blocks, 256 thr; LDS-tiled, coalesced both sides
__global__ __launch_bounds__(256) void transpose_bf16_kernel(
    const float* __restrict__ in, u16* __restrict__ out, int R, int C)
{
    const int tiles_c = C >> 5;
    const int tr = blockIdx.x / tiles_c, tc = blockIdx.x % tiles_c;
    const int r0 = tr * 32, c0 = tc * 32;
    const int tx = threadIdx.x & 31, ty4 = threadIdx.x >> 5;
    __shared__ float t[32][33];
    #pragma unroll
    for (int i = 0; i < 4; ++i) {
        int r = ty4 + i * 8;
        t[r][tx] = in[(size_t)(r0 + r) * C + c0 + tx];
    }
    __syncthreads();
    #pragma unroll
    for (int i = 0; i < 4; ++i) {
        int c = ty4 + i * 8;
        out[(size_t)(c0 + c) * R + r0 + tx] = f2bf(t[tx][c]);
    }
}

// ---------- Level 0: h = mlp_pi(delay) (bf16 store) + g epilogue ----------
__global__ __launch_bounds__(512) void level0_kernel(
    const float* __restrict__ delay,
    const float* __restrict__ W1, const float* __restrict__ b1,
    const float* __restrict__ W2, const float* __restrict__ b2,
    const float* __restrict__ av,
    u16* __restrict__ h_all, float* __restrict__ g_all)
{
    const int tid = threadIdx.x;
    const int row0 = blockIdx.x * 32;
    __shared__ __align__(16) float sH[32][132];

    for (int x = tid; x < 32 * 128; x += 512) {
        int r = x >> 7, j = x & 127;
        sH[r][j] = lrelu(delay[row0 + r] * W1[j] + b1[j]);
    }
    __syncthreads();

    const int tj = tid & 63, tr = tid >> 6;
    const float4 av4 = *(const float4*)(av + 64 + tj * 4);
    float acc[4][4];
    #pragma unroll
    for (int a = 0; a < 4; ++a)
        #pragma unroll
        for (int b = 0; b < 4; ++b) acc[a][b] = 0.f;

    for (int k = 0; k < 128; k += 4) {
        float4 w0 = *(const float4*)(W2 + (size_t)(k + 0) * 256 + tj * 4);
        float4 w1 = *(const float4*)(W2 + (size_t)(k + 1) * 256 + tj * 4);
        float4 w2 = *(const float4*)(W2 + (size_t)(k + 2) * 256 + tj * 4);
        float4 w3 = *(const float4*)(W2 + (size_t)(k + 3) * 256 + tj * 4);
        #pragma unroll
        for (int rr = 0; rr < 4; ++rr) {
            float4 xv = *(const float4*)(&sH[tr * 4 + rr][k]);
            acc[rr][0] += xv.x * w0.x + xv.y * w1.x + xv.z * w2.x + xv.w * w3.x;
            acc[rr][1] += xv.x * w0.y + xv.y * w1.y + xv.z * w2.y + xv.w * w3.y;
            acc[rr][2] += xv.x * w0.z + xv.y * w1.z + xv.z * w2.z + xv.w * w3.z;
            acc[rr][3] += xv.x * w0.w + xv.y * w1.w + xv.z * w2.w + xv.w * w3.w;
        }
    }
    float4 bv = *(const float4*)(b2 + tj * 4);
    #pragma unroll
    for (int rr = 0; rr < 4; ++rr) {
        const int row = row0 + tr * 4 + rr;
        float4 o;
        o.x = acc[rr][0] + bv.x; o.y = acc[rr][1] + bv.y;
        o.z = acc[rr][2] + bv.z; o.w = acc[rr][3] + bv.w;
        *(ushort4*)(h_all + (size_t)row * NH + tj * 4) = f4_to_bf4(o);
        float gp = o.x * av4.x + o.y * av4.y + o.z * av4.z + o.w * av4.w;
        #pragma unroll
        for (int off = 1; off < 64; off <<= 1) gp += __shfl_xor(gp, off);
        if (tj == 0) g_all[row] = gp;
    }
}

// ---------- Attention: 1 wave per m; g-gather alpha + single 16B-load streamed pass ----------
__global__ __launch_bounds__(256) void attn_kernel(
    const u16* __restrict__ h_all, const float* __restrict__ g_all,
    const float* __restrict__ bit_pos, const int* __restrict__ nbr_idx,
    const float* __restrict__ W_p1, const float* __restrict__ b_p1,
    const float* __restrict__ cst,
    u16* __restrict__ neigh, int level)
{
    const int w = threadIdx.x >> 6, lane = threadIdx.x & 63;
    const int m = blockIdx.x * 4 + w;
    const int d = lane & 15, jj = lane >> 4;
    const size_t ebase = ((size_t)(level - 1) * NM + m) * ND;

    const int   idx = nbr_idx[ebase + d];
    const float bp  = bit_pos[ebase + d];

    float ep = 0.f;
    #pragma unroll
    for (int t = 0; t < 8; ++t) {
        int j = jj * 8 + t;
        ep += cst[32 + j] * lrelu(bp * W_p1[j] + b_p1[j]);
    }
    ep += __shfl_xor(ep, 16);
    ep += __shfl_xor(ep, 32);

    float e = g_all[idx] + ep;
    float mx = e;
    #pragma unroll
    for (int off = 1; off < 16; off <<= 1) mx = fmaxf(mx, __shfl_xor(mx, off));
    float wexp = __expf(e - mx);
    float s = wexp;
    #pragma unroll
    for (int off = 1; off < 16; off <<= 1) s += __shfl_xor(s, off);
    const float alpha = wexp / s;

    const int rh = lane >> 5, cl = lane & 31;
    float4 a0 = make_float4(0.f, 0.f, 0.f, 0.f);
    float4 a1 = make_float4(0.f, 0.f, 0.f, 0.f);
    #pragma unroll
    for (int t = 0; t < 8; ++t) {
        const int d2 = t * 2 + rh;
        float a = __shfl(alpha, d2);
        int   r = __shfl(idx, d2);
        uint4 hv = *(const uint4*)(h_all + (size_t)r * NH + cl * 8);
        float2 p0 = bfp(hv.x), p1 = bfp(hv.y), p2 = bfp(hv.z), p3 = bfp(hv.w);
        a0.x += a * p0.x; a0.y += a * p0.y; a0.z += a * p1.x; a0.w += a * p1.y;
        a1.x += a * p2.x; a1.y += a * p2.y; a1.z += a * p3.x; a1.w += a * p3.y;
    }
    a0.x += __shfl_xor(a0.x, 32); a0.y += __shfl_xor(a0.y, 32);
    a0.z += __shfl_xor(a0.z, 32); a0.w += __shfl_xor(a0.w, 32);
    a1.x += __shfl_xor(a1.x, 32); a1.y += __shfl_xor(a1.y, 32);
    a1.z += __shfl_xor(a1.z, 32); a1.w += __shfl_xor(a1.w, 32);

    float4 outv = (rh == 0) ? a0 : a1;
    *(ushort4*)(neigh + (size_t)m * NH + cl * 8 + rh * 4) = f4_to_bf4(outv);
}

// ---------- Neighborhood MLP: layer1 via MFMA (bf16 A=neigh, bf16 W1t), layer2 f32 ----------
__global__ __launch_bounds__(256) void mlp_n_kernel(
    const u16* __restrict__ neigh, const u16* __restrict__ W1t,
    const float* __restrict__ b1,
    const float* __restrict__ W2, const float* __restrict__ b2,
    const int* __restrict__ is_po, const float* __restrict__ av,
    u16* __restrict__ h_all, float* __restrict__ g_all, int level)
{
    const int tid = threadIdx.x;
    const int w = tid >> 6, lane = tid & 63;
    const int row0 = blockIdx.x * 16;
    __shared__ __align__(16) u16   sXb[16][NH + 8];   // bf16, stride 264 u16 (132 dw, mod32=4)
    __shared__ __align__(16) float sH[16][132];       // stride 132 (mod32=4)
    __shared__ float gpart[4][16];

    // stage: raw bf16 copy (neigh is already bf16)
    for (int x = tid; x < 16 * 32; x += 256) {
        int r = x >> 5, c = x & 31;
        *(uint4*)(&sXb[r][c * 8]) = *(const uint4*)(neigh + (size_t)(row0 + r) * NH + c * 8);
    }
    __syncthreads();

    // layer 1 via MFMA: (16x256)@(256x128); wave w -> cols [w*32, w*32+32) = 2 tiles
    // A frag: row = lane&15, k = (lane>>4)*8 + j (contiguous in sXb)
    // B frag: col = lane&15, k = (lane>>4)*8 + j (contiguous in W1t[col][k])
    // C/D:   col = lane&15, row = (lane>>4)*4 + reg
    {
        const int krow = lane & 15, kgrp = lane >> 4;
        f32x4 acc0 = {0.f, 0.f, 0.f, 0.f};
        f32x4 acc1 = {0.f, 0.f, 0.f, 0.f};
        #pragma unroll 2
        for (int ks = 0; ks < 8; ++ks) {
            const int k0 = ks * 32;
            bf16x8 aF = *(const bf16x8*)(&sXb[krow][k0 + kgrp * 8]);
            const u16* bbase = W1t + (size_t)(w * 32 + krow) * 256 + k0 + kgrp * 8;
            bf16x8 b0 = *(const bf16x8*)(bbase);
            bf16x8 b1v = *(const bf16x8*)(bbase + 16 * 256);
            acc0 = __builtin_amdgcn_mfma_f32_16x16x32_bf16(aF, b0, acc0, 0, 0, 0);
            acc1 = __builtin_amdgcn_mfma_f32_16x16x32_bf16(aF, b1v, acc1, 0, 0, 0);
        }
        {
            const int c = w * 32 + krow;
            const float b = b1[c];
            #pragma unroll
            for (int r = 0; r < 4; ++r) sH[kgrp * 4 + r][c] = lrelu(acc0[r] + b);
        }
        {
            const int c = w * 32 + 16 + krow;
            const float b = b1[c];
            #pragma unroll
            for (int r = 0; r < 4; ++r) sH[kgrp * 4 + r][c] = lrelu(acc1[r] + b);
        }
    }
    __syncthreads();

    // layer 2 (f32): (16x128)@(128x256); wave w -> cols [w*64, w*64+64)
    {
        const int tj = lane & 15, tr = lane >> 4;
        const int c0 = w * 64 + tj * 4;
        const float4 av4 = *(const float4*)(av + 64 + c0);
        float acc[4][4];
        #pragma unroll
        for (int a = 0; a < 4; ++a)
            #pragma unroll
            for (int b = 0; b < 4; ++b) acc[a][b] = 0.f;

        for (int k = 0; k < 128; k += 4) {
            float4 w0 = *(const float4*)(W2 + (size_t)(k + 0) * 256 + c0);
            float4 w1 = *(const float4*)(W2 + (size_t)(k + 1) * 256 + c0);
            float4 w2 = *(const float4*)(W2 + (size_t)(k + 2) * 256 + c0);
            float4 w3 = *(const float4*)(W2 + (size_t)(k + 3) * 256 + c0);
            #pragma unroll
            for (int rr = 0; rr < 4; ++rr) {
                float4 xv = *(const float4*)(&sH[tr * 4 + rr][k]);
                acc[rr][0] += xv.x * w0.x + xv.y * w1.x + xv.z * w2.x + xv.w * w3.x;
                acc[rr][1] += xv.x * w0.y + xv.y * w1.y + xv.z * w2.y + xv.w * w3.y;
                acc[rr][2] += xv.x * w0.z + xv.y * w1.z + xv.z * w2.z + xv.w * w3.z;
                acc[rr][3] += xv.x * w0.w + xv.y * w1.w + xv.z * w2.w + xv.w * w3.w;
            }
        }
        float4 bv = *(const float4*)(b2 + c0);
        #pragma unroll
        for (int rr = 0; rr < 4; ++rr) {
            const int gm = level * NM + row0 + tr * 4 + rr;
            bool po = (is_po[gm] == 1);
            float4 o;
            o.x = acc[rr][0] + bv.x; o.y = acc[rr][1] + bv.y;
            o.z = acc[rr][2] + bv.z; o.w = acc[rr][3] + bv.w;
            if (!po) {
                o.x = fmaxf(o.x, 0.f); o.y = fmaxf(o.y, 0.f);
                o.z = fmaxf(o.z, 0.f); o.w = fmaxf(o.w, 0.f);
            }
            *(ushort4*)(h_all + (size_t)gm * NH + c0) = f4_to_bf4(o);
            float gp = o.x * av4.x + o.y * av4.y + o.z * av4.z + o.w * av4.w;
            gp += __shfl_xor(gp, 1); gp += __shfl_xor(gp, 2);
            gp += __shfl_xor(gp, 4); gp += __shfl_xor(gp, 8);
            if (tj == 0) gpart[w][tr * 4 + rr] = gp;
        }
    }
    __syncthreads();
    if (tid < 16)
        g_all[level * NM + row0 + tid] =
            gpart[0][tid] + gpart[1][tid] + gpart[2][tid] + gpart[3][tid];
}

// ---------- Final readout: stage + f32 Wg2 GEMM + MFMA o1 GEMM (bf16) ----------
__global__ __launch_bounds__(256) void final_kernel(
    const u16* __restrict__ h_gnn, const float* __restrict__ po_feat,
    const float* __restrict__ Wg1, const float* __restrict__ bg1,
    const float* __restrict__ Wg2, const float* __restrict__ bg2,
    const u16* __restrict__ Wo1t, const float* __restrict__ bo1,
    const float* __restrict__ Wo2, const float* __restrict__ bo2,
    float* __restrict__ out)
{
    const int tid = threadIdx.x;
    const int w = tid >> 6, lane = tid & 63;
    const int row0 = blockIdx.x * 16;
    __shared__ __align__(16) u16   sxb[16][520];
    __shared__ __align__(16) float sg[16][132];
    __shared__ float part[4][16];

    for (int x = tid; x < 16 * 32; x += 256) {
        int r = x >> 5, c = x & 31;
        *(uint4*)(&sxb[r][c * 8]) = *(const uint4*)(h_gnn + (size_t)(row0 + r) * NH + c * 8);
    }
    for (int x = tid; x < 16 * 128; x += 256) {
        int r = x >> 7, j = x & 127;
        sg[r][j] = lrelu(po_feat[row0 + r] * Wg1[j] + bg1[j]);
    }
    __syncthreads();

    {
        const int tj = lane & 15, tr = lane >> 4;
        const int c0 = w * 64 + tj * 4;
        float acc[4][4];
        #pragma unroll
        for (int a = 0; a < 4; ++a)
            #pragma unroll
            for (int b = 0; b < 4; ++b) acc[a][b] = 0.f;

        for (int k = 0; k < 128; k += 4) {
            float4 w0 = *(const float4*)(Wg2 + (size_t)(k + 0) * 256 + c0);
            float4 w1 = *(const float4*)(Wg2 + (size_t)(k + 1) * 256 + c0);
            float4 w2 = *(const float4*)(Wg2 + (size_t)(k + 2) * 256 + c0);
            float4 w3 = *(const float4*)(Wg2 + (size_t)(k + 3) * 256 + c0);
            #pragma unroll
            for (int rr = 0; rr < 4; ++rr) {
                float4 xv = *(const float4*)(&sg[tr * 4 + rr][k]);
                acc[rr][0] += xv.x * w0.x + xv.y * w1.x + xv.z * w2.x + xv.w * w3.x;
                acc[rr][1] += xv.x * w0.y + xv.y * w1.y + xv.z * w2.y + xv.w * w3.y;
                acc[rr][2] += xv.x * w0.z + xv.y * w1.z + xv.z * w2.z + xv.w * w3.z;
                acc[rr][3] += xv.x * w0.w + xv.y * w1.w + xv.z * w2.w + xv.w * w3.w;
            }
        }
        float4 bv = *(const float4*)(bg2 + c0);
        #pragma unroll
        for (int rr = 0; rr < 4; ++rr) {
            float4 o;
            o.x = acc[rr][0] + bv.x; o.y = acc[rr][1] + bv.y;
            o.z = acc[rr][2] + bv.z; o.w = acc[rr][3] + bv.w;
            *(ushort4*)(&sxb[tr * 4 + rr][256 + c0]) = f4_to_bf4(o);
        }
    }
    __syncthreads();

    {
        const int krow = lane & 15;
        const int kgrp = lane >> 4;
        f32x4 acc0 = {0.f, 0.f, 0.f, 0.f};
        f32x4 acc1 = {0.f, 0.f, 0.f, 0.f};
        f32x4 acc2 = {0.f, 0.f, 0.f, 0.f};
        f32x4 acc3 = {0.f, 0.f, 0.f, 0.f};

        #pragma unroll 2
        for (int ks = 0; ks < 16; ++ks) {
            const int k0 = ks * 32;
            bf16x8 aF = *(const bf16x8*)(&sxb[krow][k0 + kgrp * 8]);
            const u16* bbase = Wo1t + (size_t)(w * 64 + krow) * 512 + k0 + kgrp * 8;
            bf16x8 b0 = *(const bf16x8*)(bbase);
            bf16x8 b1 = *(const bf16x8*)(bbase + 16 * 512);
            bf16x8 b2 = *(const bf16x8*)(bbase + 32 * 512);
            bf16x8 b3 = *(const bf16x8*)(bbase + 48 * 512);
            acc0 = __builtin_amdgcn_mfma_f32_16x16x32_bf16(aF, b0, acc0, 0, 0, 0);
            acc1 = __builtin_amdgcn_mfma_f32_16x16x32_bf16(aF, b1, acc1, 0, 0, 0);
            acc2 = __builtin_amdgcn_mfma_f32_16x16x32_bf16(aF, b2, acc2, 0, 0, 0);
            acc3 = __builtin_amdgcn_mfma_f32_16x16x32_bf16(aF, b3, acc3, 0, 0, 0);
        }

        float p0 = 0.f, p1 = 0.f, p2 = 0.f, p3 = 0.f;
        {
            int c = w * 64 + 0 * 16 + krow;  float b = bo1[c], v = Wo2[c];
            p0 += lrelu(acc0[0] + b) * v; p1 += lrelu(acc0[1] + b) * v;
            p2 += lrelu(acc0[2] + b) * v; p3 += lrelu(acc0[3] + b) * v;
        }
        {
            int c = w * 64 + 1 * 16 + krow;  float b = bo1[c], v = Wo2[c];
            p0 += lrelu(acc1[0] + b) * v; p1 += lrelu(acc1[1] + b) * v;
            p2 += lrelu(acc1[2] + b) * v; p3 += lrelu(acc1[3] + b) * v;
        }
        {
            int c = w * 64 + 2 * 16 + krow;  float b = bo1[c], v = Wo2[c];
            p0 += lrelu(acc2[0] + b) * v; p1 += lrelu(acc2[1] + b) * v;
            p2 += lrelu(acc2[2] + b) * v; p3 += lrelu(acc2[3] + b) * v;
        }
        {
            int c = w * 64 + 3 * 16 + krow;  float b = bo1[c], v = Wo2[c];
            p0 += lrelu(acc3[0] + b) * v; p1 += lrelu(acc3[1] + b) * v;
            p2 += lrelu(acc3[2] + b) * v; p3 += lrelu(acc3[3] + b) * v;
        }
        p0 += __shfl_xor(p0, 1); p0 += __shfl_xor(p0, 2); p0 += __shfl_xor(p0, 4); p0 += __shfl_xor(p0, 8);
        p1 += __shfl_xor(p1, 1); p1 += __shfl_xor(p1, 2); p1 += __shfl_xor(p1, 4); p1 += __shfl_xor(p1, 8);
        p2 += __shfl_xor(p2, 1); p2 += __shfl_xor(p2, 2); p2 += __shfl_xor(p2, 4); p2 += __shfl_xor(p2, 8);
        p3 += __shfl_xor(p3, 1); p3 += __shfl_xor(p3, 2); p3 += __shfl_xor(p3, 4); p3 += __shfl_xor(p3, 8);
        if (krow == 0) {
            part[w][kgrp * 4 + 0] = p0;
            part[w][kgrp * 4 + 1] = p1;
            part[w][kgrp * 4 + 2] = p2;
            part[w][kgrp * 4 + 3] = p3;
        }
    }
    __syncthreads();
    if (tid < 16)
        out[row0 + tid] = part[0][tid] + part[1][tid] + part[2][tid] + part[3][tid] + bo2[0];
}

extern "C" void kernel_launch(void* const* d_in, const int* in_sizes, int n_in,
                              void* d_out, int out_size, void* d_ws, size_t ws_size,
                              hipStream_t stream) {
    const float* W_pi1 = (const float*)d_in[0];
    const float* b_pi1 = (const float*)d_in[1];
    const float* W_pi2 = (const float*)d_in[2];
    const float* b_pi2 = (const float*)d_in[3];
    const float* W_p1  = (const float*)d_in[8];
    const float* b_p1  = (const float*)d_in[9];
    const float* W_p2  = (const float*)d_in[10];
    const float* W_n1  = (const float*)d_in[12];
    const float* b_n1  = (const float*)d_in[13];
    const float* W_n2  = (const float*)d_in[14];
    const float* b_n2  = (const float*)d_in[15];
    const float* W_g1  = (const float*)d_in[16];
    const float* b_g1  = (const float*)d_in[17];
    const float* W_g2  = (const float*)d_in[18];
    const float* b_g2  = (const float*)d_in[19];
    const float* W_o1  = (const float*)d_in[20];
    const float* b_o1  = (const float*)d_in[21];
    const float* W_o2  = (const float*)d_in[22];
    const float* b_o2  = (const float*)d_in[23];
    const float* av    = (const float*)d_in[24];
    const float* delay = (const float*)d_in[26];
    const float* bit_pos = (const float*)d_in[27];
    const float* po_feat = (const float*)d_in[28];
    const int*   is_po   = (const int*)d_in[29];
    const int*   nbr_idx = (const int*)d_in[30];

    u16*   h_all = (u16*)d_ws;                                // NN*NH bf16 (33.5 MB)
    float* g_all = (float*)(h_all + (size_t)NN * NH);         // NN floats
    u16*   neigh = (u16*)(g_all + NN);                        // NM*NH bf16 (4 MB)
    float* cst   = (float*)(neigh + (size_t)NM * NH);         // 64 floats
    u16*   Wo1t  = (u16*)(cst + 64);                          // 256*512 bf16
    u16*   W1t   = Wo1t + 256 * 512;                          // 128*256 bf16
    float* out   = (float*)d_out;

    precomp_kernel<<<1, 32, 0, stream>>>(W_p2, av, cst);
    transpose_bf16_kernel<<<128, 256, 0, stream>>>(W_o1, Wo1t, 512, 256);
    transpose_bf16_kernel<<<32, 256, 0, stream>>>(W_n1, W1t, 256, 128);

    level0_kernel<<<NM / 32, 512, 0, stream>>>(delay, W_pi1, b_pi1, W_pi2, b_pi2,
                                               av, h_all, g_all);

    for (int level = 1; level < NL; ++level) {
        attn_kernel<<<NM / 4, 256, 0, stream>>>(h_all, g_all, bit_pos, nbr_idx,
                                                W_p1, b_p1, cst, neigh, level);
        mlp_n_kernel<<<NM / 16, 256, 0, stream>>>(neigh, W1t, b_n1, W_n2, b_n2,
                                                  is_po, av, h_all, g_all, level);
    }

    final_kernel<<<NM / 16, 256, 0, stream>>>(h_all + (size_t)(NN - NM) * NH, po_feat,
                                              W_g1, b_g1, W_g2, b_g2,
                                              Wo1t, b_o1, W_o2, b_o2, out);
}

// Round 18
// 204.020 us; speedup vs baseline: 6.5294x; 1.2777x over previous
//
#include <hip/hip_runtime.h>

#define NL 8
#define NM 8192
#define ND 16
#define NH 256
#define NF 64
#define NN (NL * NM)

typedef unsigned short u16;
typedef __attribute__((ext_vector_type(8))) short bf16x8;
typedef __attribute__((ext_vector_type(4))) float f32x4;

__device__ __forceinline__ float lrelu(float x) { return fmaxf(x, 0.1f * x); }

__device__ __forceinline__ u16 f2bf(float x) {
    union { float f; unsigned int u; } v; v.f = x;
    unsigned int r = (v.u + 0x7FFFu + ((v.u >> 16) & 1u)) >> 16;
    return (u16)r;
}
__device__ __forceinline__ float bf2f(u16 u) {
    union { unsigned int u; float f; } v; v.u = ((unsigned int)u) << 16;
    return v.f;
}
__device__ __forceinline__ ushort4 f4_to_bf4(float4 o) {
    ushort4 r; r.x = f2bf(o.x); r.y = f2bf(o.y); r.z = f2bf(o.z); r.w = f2bf(o.w);
    return r;
}
__device__ __forceinline__ float2 bfp(unsigned int u) {
    union { unsigned int u; float f; } lo, hi;
    lo.u = u << 16; hi.u = u & 0xFFFF0000u;
    return make_float2(lo.f, hi.f);
}

// ---------- precompute attention constants: cst[32..63] = W_p2 @ av_p ----------
__global__ void precomp_kernel(const float* __restrict__ W_p2, const float* __restrict__ av,
                               float* __restrict__ cst)
{
    int j = threadIdx.x;   // 32 threads
    float w = 0.f;
    for (int k = 0; k < 32; ++k) w += W_p2[j * 32 + k] * av[32 + k];
    cst[32 + j] = w;
}

// ---------- generic: out[C][R] (bf16) = transpose(in [R][C] f32) ----------
__global__ __launch_bounds__(256) void transpose_bf16_kernel(
    const float* __restrict__ in, u16* __restrict__ out, int R, int C)
{
    const int tiles_c = C >> 5;
    const int tr = blockIdx.x / tiles_c, tc = blockIdx.x % tiles_c;
    const int r0 = tr * 32, c0 = tc * 32;
    const int tx = threadIdx.x & 31, ty4 = threadIdx.x >> 5;
    __shared__ float t[32][33];
    #pragma unroll
    for (int i = 0; i < 4; ++i) {
        int r = ty4 + i * 8;
        t[r][tx] = in[(size_t)(r0 + r) * C + c0 + tx];
    }
    __syncthreads();
    #pragma unroll
    for (int i = 0; i < 4; ++i) {
        int c = ty4 + i * 8;
        out[(size_t)(c0 + c) * R + r0 + tx] = f2bf(t[tx][c]);
    }
}

// ---------- Level 0: h = mlp_pi(delay) (bf16 store) + g epilogue ----------
__global__ __launch_bounds__(512) void level0_kernel(
    const float* __restrict__ delay,
    const float* __restrict__ W1, const float* __restrict__ b1,
    const float* __restrict__ W2, const float* __restrict__ b2,
    const float* __restrict__ av,
    u16* __restrict__ h_all, float* __restrict__ g_all)
{
    const int tid = threadIdx.x;
    const int row0 = blockIdx.x * 32;
    __shared__ __align__(16) float sH[32][132];

    for (int x = tid; x < 32 * 128; x += 512) {
        int r = x >> 7, j = x & 127;
        sH[r][j] = lrelu(delay[row0 + r] * W1[j] + b1[j]);
    }
    __syncthreads();

    const int tj = tid & 63, tr = tid >> 6;
    const float4 av4 = *(const float4*)(av + 64 + tj * 4);
    float acc[4][4];
    #pragma unroll
    for (int a = 0; a < 4; ++a)
        #pragma unroll
        for (int b = 0; b < 4; ++b) acc[a][b] = 0.f;

    for (int k = 0; k < 128; k += 4) {
        float4 w0 = *(const float4*)(W2 + (size_t)(k + 0) * 256 + tj * 4);
        float4 w1 = *(const float4*)(W2 + (size_t)(k + 1) * 256 + tj * 4);
        float4 w2 = *(const float4*)(W2 + (size_t)(k + 2) * 256 + tj * 4);
        float4 w3 = *(const float4*)(W2 + (size_t)(k + 3) * 256 + tj * 4);
        #pragma unroll
        for (int rr = 0; rr < 4; ++rr) {
            float4 xv = *(const float4*)(&sH[tr * 4 + rr][k]);
            acc[rr][0] += xv.x * w0.x + xv.y * w1.x + xv.z * w2.x + xv.w * w3.x;
            acc[rr][1] += xv.x * w0.y + xv.y * w1.y + xv.z * w2.y + xv.w * w3.y;
            acc[rr][2] += xv.x * w0.z + xv.y * w1.z + xv.z * w2.z + xv.w * w3.z;
            acc[rr][3] += xv.x * w0.w + xv.y * w1.w + xv.z * w2.w + xv.w * w3.w;
        }
    }
    float4 bv = *(const float4*)(b2 + tj * 4);
    #pragma unroll
    for (int rr = 0; rr < 4; ++rr) {
        const int row = row0 + tr * 4 + rr;
        float4 o;
        o.x = acc[rr][0] + bv.x; o.y = acc[rr][1] + bv.y;
        o.z = acc[rr][2] + bv.z; o.w = acc[rr][3] + bv.w;
        *(ushort4*)(h_all + (size_t)row * NH + tj * 4) = f4_to_bf4(o);
        float gp = o.x * av4.x + o.y * av4.y + o.z * av4.z + o.w * av4.w;
        #pragma unroll
        for (int off = 1; off < 64; off <<= 1) gp += __shfl_xor(gp, off);
        if (tj == 0) g_all[row] = gp;
    }
}

// ---------- Attention: 1 wave per m; g-gather alpha + single 16B-load streamed pass ----------
__global__ __launch_bounds__(256) void attn_kernel(
    const u16* __restrict__ h_all, const float* __restrict__ g_all,
    const float* __restrict__ bit_pos, const int* __restrict__ nbr_idx,
    const float* __restrict__ W_p1, const float* __restrict__ b_p1,
    const float* __restrict__ cst,
    u16* __restrict__ neigh, int level)
{
    const int w = threadIdx.x >> 6, lane = threadIdx.x & 63;
    const int m = blockIdx.x * 4 + w;
    const int d = lane & 15, jj = lane >> 4;
    const size_t ebase = ((size_t)(level - 1) * NM + m) * ND;

    const int   idx = nbr_idx[ebase + d];
    const float bp  = bit_pos[ebase + d];

    float ep = 0.f;
    #pragma unroll
    for (int t = 0; t < 8; ++t) {
        int j = jj * 8 + t;
        ep += cst[32 + j] * lrelu(bp * W_p1[j] + b_p1[j]);
    }
    ep += __shfl_xor(ep, 16);
    ep += __shfl_xor(ep, 32);

    float e = g_all[idx] + ep;
    float mx = e;
    #pragma unroll
    for (int off = 1; off < 16; off <<= 1) mx = fmaxf(mx, __shfl_xor(mx, off));
    float wexp = __expf(e - mx);
    float s = wexp;
    #pragma unroll
    for (int off = 1; off < 16; off <<= 1) s += __shfl_xor(s, off);
    const float alpha = wexp / s;

    const int rh = lane >> 5, cl = lane & 31;
    float4 a0 = make_float4(0.f, 0.f, 0.f, 0.f);
    float4 a1 = make_float4(0.f, 0.f, 0.f, 0.f);
    #pragma unroll
    for (int t = 0; t < 8; ++t) {
        const int d2 = t * 2 + rh;
        float a = __shfl(alpha, d2);
        int   r = __shfl(idx, d2);
        uint4 hv = *(const uint4*)(h_all + (size_t)r * NH + cl * 8);
        float2 p0 = bfp(hv.x), p1 = bfp(hv.y), p2 = bfp(hv.z), p3 = bfp(hv.w);
        a0.x += a * p0.x; a0.y += a * p0.y; a0.z += a * p1.x; a0.w += a * p1.y;
        a1.x += a * p2.x; a1.y += a * p2.y; a1.z += a * p3.x; a1.w += a * p3.y;
    }
    a0.x += __shfl_xor(a0.x, 32); a0.y += __shfl_xor(a0.y, 32);
    a0.z += __shfl_xor(a0.z, 32); a0.w += __shfl_xor(a0.w, 32);
    a1.x += __shfl_xor(a1.x, 32); a1.y += __shfl_xor(a1.y, 32);
    a1.z += __shfl_xor(a1.z, 32); a1.w += __shfl_xor(a1.w, 32);

    float4 outv = (rh == 0) ? a0 : a1;
    *(ushort4*)(neigh + (size_t)m * NH + cl * 8 + rh * 4) = f4_to_bf4(outv);
}

// ---------- Neighborhood MLP: both layers via MFMA; layer2 uses split-bf16 activations ----------
__global__ __launch_bounds__(256) void mlp_n_kernel(
    const u16* __restrict__ neigh, const u16* __restrict__ W1t,
    const float* __restrict__ b1,
    const u16* __restrict__ W2t, const float* __restrict__ b2,
    const int* __restrict__ is_po, const float* __restrict__ av,
    u16* __restrict__ h_all, float* __restrict__ g_all, int level)
{
    const int tid = threadIdx.x;
    const int w = tid >> 6, lane = tid & 63;
    const int row0 = blockIdx.x * 16;
    __shared__ __align__(16) u16 sXb[16][NH + 8];   // input (bf16), later output staging
    __shared__ __align__(16) u16 sHhi[16][136];     // hidden hi (bf16)
    __shared__ __align__(16) u16 sHlo[16][136];     // hidden lo (bf16 residual)
    __shared__ float gpart[4][16];

    // stage: raw bf16 copy
    for (int x = tid; x < 16 * 32; x += 256) {
        int r = x >> 5, c = x & 31;
        *(uint4*)(&sXb[r][c * 8]) = *(const uint4*)(neigh + (size_t)(row0 + r) * NH + c * 8);
    }
    __syncthreads();

    const int krow = lane & 15, kgrp = lane >> 4;

    // layer 1 via MFMA: (16x256)@(256x128); wave w -> cols [w*32, w*32+32)
    {
        f32x4 acc0 = {0.f, 0.f, 0.f, 0.f};
        f32x4 acc1 = {0.f, 0.f, 0.f, 0.f};
        #pragma unroll 2
        for (int ks = 0; ks < 8; ++ks) {
            const int k0 = ks * 32;
            bf16x8 aF = *(const bf16x8*)(&sXb[krow][k0 + kgrp * 8]);
            const u16* bbase = W1t + (size_t)(w * 32 + krow) * 256 + k0 + kgrp * 8;
            bf16x8 b0 = *(const bf16x8*)(bbase);
            bf16x8 b1v = *(const bf16x8*)(bbase + 16 * 256);
            acc0 = __builtin_amdgcn_mfma_f32_16x16x32_bf16(aF, b0, acc0, 0, 0, 0);
            acc1 = __builtin_amdgcn_mfma_f32_16x16x32_bf16(aF, b1v, acc1, 0, 0, 0);
        }
        {
            const int c = w * 32 + krow;
            const float b = b1[c];
            #pragma unroll
            for (int r = 0; r < 4; ++r) {
                float v = lrelu(acc0[r] + b);
                u16 hi = f2bf(v);
                sHhi[kgrp * 4 + r][c] = hi;
                sHlo[kgrp * 4 + r][c] = f2bf(v - bf2f(hi));
            }
        }
        {
            const int c = w * 32 + 16 + krow;
            const float b = b1[c];
            #pragma unroll
            for (int r = 0; r < 4; ++r) {
                float v = lrelu(acc1[r] + b);
                u16 hi = f2bf(v);
                sHhi[kgrp * 4 + r][c] = hi;
                sHlo[kgrp * 4 + r][c] = f2bf(v - bf2f(hi));
            }
        }
    }
    __syncthreads();

    // layer 2 via MFMA: (16x128)@(128x256); wave w -> cols [w*64, w*64+64) = 4 tiles
    // acc = A_hi @ W2t + A_lo @ W2t (split-precision activations)
    {
        f32x4 acc0 = {0.f, 0.f, 0.f, 0.f};
        f32x4 acc1 = {0.f, 0.f, 0.f, 0.f};
        f32x4 acc2 = {0.f, 0.f, 0.f, 0.f};
        f32x4 acc3 = {0.f, 0.f, 0.f, 0.f};
        #pragma unroll 2
        for (int ks = 0; ks < 4; ++ks) {
            const int k0 = ks * 32;
            bf16x8 ahi = *(const bf16x8*)(&sHhi[krow][k0 + kgrp * 8]);
            bf16x8 alo = *(const bf16x8*)(&sHlo[krow][k0 + kgrp * 8]);
            const u16* bb = W2t + (size_t)(w * 64 + krow) * 128 + k0 + kgrp * 8;
            bf16x8 b0 = *(const bf16x8*)(bb);
            bf16x8 b1v = *(const bf16x8*)(bb + 16 * 128);
            bf16x8 b2v = *(const bf16x8*)(bb + 32 * 128);
            bf16x8 b3v = *(const bf16x8*)(bb + 48 * 128);
            acc0 = __builtin_amdgcn_mfma_f32_16x16x32_bf16(ahi, b0, acc0, 0, 0, 0);
            acc0 = __builtin_amdgcn_mfma_f32_16x16x32_bf16(alo, b0, acc0, 0, 0, 0);
            acc1 = __builtin_amdgcn_mfma_f32_16x16x32_bf16(ahi, b1v, acc1, 0, 0, 0);
            acc1 = __builtin_amdgcn_mfma_f32_16x16x32_bf16(alo, b1v, acc1, 0, 0, 0);
            acc2 = __builtin_amdgcn_mfma_f32_16x16x32_bf16(ahi, b2v, acc2, 0, 0, 0);
            acc2 = __builtin_amdgcn_mfma_f32_16x16x32_bf16(alo, b2v, acc2, 0, 0, 0);
            acc3 = __builtin_amdgcn_mfma_f32_16x16x32_bf16(ahi, b3v, acc3, 0, 0, 0);
            acc3 = __builtin_amdgcn_mfma_f32_16x16x32_bf16(alo, b3v, acc3, 0, 0, 0);
        }

        // per-row is_po flags (rows kgrp*4 + r)
        int po0 = is_po[level * NM + row0 + kgrp * 4 + 0];
        int po1 = is_po[level * NM + row0 + kgrp * 4 + 1];
        int po2 = is_po[level * NM + row0 + kgrp * 4 + 2];
        int po3 = is_po[level * NM + row0 + kgrp * 4 + 3];

        float gsum0 = 0.f, gsum1 = 0.f, gsum2 = 0.f, gsum3 = 0.f;
        #pragma unroll
        for (int t = 0; t < 4; ++t) {
            f32x4 a = (t == 0) ? acc0 : (t == 1) ? acc1 : (t == 2) ? acc2 : acc3;
            const int c = w * 64 + t * 16 + krow;
            const float b = b2[c];
            const float avc = av[64 + c];
            float o0 = a[0] + b, o1 = a[1] + b, o2 = a[2] + b, o3 = a[3] + b;
            if (po0 != 1) o0 = fmaxf(o0, 0.f);
            if (po1 != 1) o1 = fmaxf(o1, 0.f);
            if (po2 != 1) o2 = fmaxf(o2, 0.f);
            if (po3 != 1) o3 = fmaxf(o3, 0.f);
            sXb[kgrp * 4 + 0][c] = f2bf(o0);
            sXb[kgrp * 4 + 1][c] = f2bf(o1);
            sXb[kgrp * 4 + 2][c] = f2bf(o2);
            sXb[kgrp * 4 + 3][c] = f2bf(o3);
            gsum0 += o0 * avc; gsum1 += o1 * avc;
            gsum2 += o2 * avc; gsum3 += o3 * avc;
        }
        gsum0 += __shfl_xor(gsum0, 1); gsum0 += __shfl_xor(gsum0, 2);
        gsum0 += __shfl_xor(gsum0, 4); gsum0 += __shfl_xor(gsum0, 8);
        gsum1 += __shfl_xor(gsum1, 1); gsum1 += __shfl_xor(gsum1, 2);
        gsum1 += __shfl_xor(gsum1, 4); gsum1 += __shfl_xor(gsum1, 8);
        gsum2 += __shfl_xor(gsum2, 1); gsum2 += __shfl_xor(gsum2, 2);
        gsum2 += __shfl_xor(gsum2, 4); gsum2 += __shfl_xor(gsum2, 8);
        gsum3 += __shfl_xor(gsum3, 1); gsum3 += __shfl_xor(gsum3, 2);
        gsum3 += __shfl_xor(gsum3, 4); gsum3 += __shfl_xor(gsum3, 8);
        if (krow == 0) {
            gpart[w][kgrp * 4 + 0] = gsum0;
            gpart[w][kgrp * 4 + 1] = gsum1;
            gpart[w][kgrp * 4 + 2] = gsum2;
            gpart[w][kgrp * 4 + 3] = gsum3;
        }
    }
    __syncthreads();

    // g write (sum over the 4 waves' col-slices)
    if (tid < 16)
        g_all[level * NM + row0 + tid] =
            gpart[0][tid] + gpart[1][tid] + gpart[2][tid] + gpart[3][tid];

    // coalesced h writeout from staging
    for (int x = tid; x < 16 * 32; x += 256) {
        int r = x >> 5, c = x & 31;
        const int gm = level * NM + row0 + r;
        *(uint4*)(h_all + (size_t)gm * NH + c * 8) = *(const uint4*)(&sXb[r][c * 8]);
    }
}

// ---------- Final readout: stage + f32 Wg2 GEMM + MFMA o1 GEMM (bf16) ----------
__global__ __launch_bounds__(256) void final_kernel(
    const u16* __restrict__ h_gnn, const float* __restrict__ po_feat,
    const float* __restrict__ Wg1, const float* __restrict__ bg1,
    const float* __restrict__ Wg2, const float* __restrict__ bg2,
    const u16* __restrict__ Wo1t, const float* __restrict__ bo1,
    const float* __restrict__ Wo2, const float* __restrict__ bo2,
    float* __restrict__ out)
{
    const int tid = threadIdx.x;
    const int w = tid >> 6, lane = tid & 63;
    const int row0 = blockIdx.x * 16;
    __shared__ __align__(16) u16   sxb[16][520];
    __shared__ __align__(16) float sg[16][132];
    __shared__ float part[4][16];

    for (int x = tid; x < 16 * 32; x += 256) {
        int r = x >> 5, c = x & 31;
        *(uint4*)(&sxb[r][c * 8]) = *(const uint4*)(h_gnn + (size_t)(row0 + r) * NH + c * 8);
    }
    for (int x = tid; x < 16 * 128; x += 256) {
        int r = x >> 7, j = x & 127;
        sg[r][j] = lrelu(po_feat[row0 + r] * Wg1[j] + bg1[j]);
    }
    __syncthreads();

    {
        const int tj = lane & 15, tr = lane >> 4;
        const int c0 = w * 64 + tj * 4;
        float acc[4][4];
        #pragma unroll
        for (int a = 0; a < 4; ++a)
            #pragma unroll
            for (int b = 0; b < 4; ++b) acc[a][b] = 0.f;

        for (int k = 0; k < 128; k += 4) {
            float4 w0 = *(const float4*)(Wg2 + (size_t)(k + 0) * 256 + c0);
            float4 w1 = *(const float4*)(Wg2 + (size_t)(k + 1) * 256 + c0);
            float4 w2 = *(const float4*)(Wg2 + (size_t)(k + 2) * 256 + c0);
            float4 w3 = *(const float4*)(Wg2 + (size_t)(k + 3) * 256 + c0);
            #pragma unroll
            for (int rr = 0; rr < 4; ++rr) {
                float4 xv = *(const float4*)(&sg[tr * 4 + rr][k]);
                acc[rr][0] += xv.x * w0.x + xv.y * w1.x + xv.z * w2.x + xv.w * w3.x;
                acc[rr][1] += xv.x * w0.y + xv.y * w1.y + xv.z * w2.y + xv.w * w3.y;
                acc[rr][2] += xv.x * w0.z + xv.y * w1.z + xv.z * w2.z + xv.w * w3.z;
                acc[rr][3] += xv.x * w0.w + xv.y * w1.w + xv.z * w2.w + xv.w * w3.w;
            }
        }
        float4 bv = *(const float4*)(bg2 + c0);
        #pragma unroll
        for (int rr = 0; rr < 4; ++rr) {
            float4 o;
            o.x = acc[rr][0] + bv.x; o.y = acc[rr][1] + bv.y;
            o.z = acc[rr][2] + bv.z; o.w = acc[rr][3] + bv.w;
            *(ushort4*)(&sxb[tr * 4 + rr][256 + c0]) = f4_to_bf4(o);
        }
    }
    __syncthreads();

    {
        const int krow = lane & 15;
        const int kgrp = lane >> 4;
        f32x4 acc0 = {0.f, 0.f, 0.f, 0.f};
        f32x4 acc1 = {0.f, 0.f, 0.f, 0.f};
        f32x4 acc2 = {0.f, 0.f, 0.f, 0.f};
        f32x4 acc3 = {0.f, 0.f, 0.f, 0.f};

        #pragma unroll 2
        for (int ks = 0; ks < 16; ++ks) {
            const int k0 = ks * 32;
            bf16x8 aF = *(const bf16x8*)(&sxb[krow][k0 + kgrp * 8]);
            const u16* bbase = Wo1t + (size_t)(w * 64 + krow) * 512 + k0 + kgrp * 8;
            bf16x8 b0 = *(const bf16x8*)(bbase);
            bf16x8 b1 = *(const bf16x8*)(bbase + 16 * 512);
            bf16x8 b2 = *(const bf16x8*)(bbase + 32 * 512);
            bf16x8 b3 = *(const bf16x8*)(bbase + 48 * 512);
            acc0 = __builtin_amdgcn_mfma_f32_16x16x32_bf16(aF, b0, acc0, 0, 0, 0);
            acc1 = __builtin_amdgcn_mfma_f32_16x16x32_bf16(aF, b1, acc1, 0, 0, 0);
            acc2 = __builtin_amdgcn_mfma_f32_16x16x32_bf16(aF, b2, acc2, 0, 0, 0);
            acc3 = __builtin_amdgcn_mfma_f32_16x16x32_bf16(aF, b3, acc3, 0, 0, 0);
        }

        float p0 = 0.f, p1 = 0.f, p2 = 0.f, p3 = 0.f;
        {
            int c = w * 64 + 0 * 16 + krow;  float b = bo1[c], v = Wo2[c];
            p0 += lrelu(acc0[0] + b) * v; p1 += lrelu(acc0[1] + b) * v;
            p2 += lrelu(acc0[2] + b) * v; p3 += lrelu(acc0[3] + b) * v;
        }
        {
            int c = w * 64 + 1 * 16 + krow;  float b = bo1[c], v = Wo2[c];
            p0 += lrelu(acc1[0] + b) * v; p1 += lrelu(acc1[1] + b) * v;
            p2 += lrelu(acc1[2] + b) * v; p3 += lrelu(acc1[3] + b) * v;
        }
        {
            int c = w * 64 + 2 * 16 + krow;  float b = bo1[c], v = Wo2[c];
            p0 += lrelu(acc2[0] + b) * v; p1 += lrelu(acc2[1] + b) * v;
            p2 += lrelu(acc2[2] + b) * v; p3 += lrelu(acc2[3] + b) * v;
        }
        {
            int c = w * 64 + 3 * 16 + krow;  float b = bo1[c], v = Wo2[c];
            p0 += lrelu(acc3[0] + b) * v; p1 += lrelu(acc3[1] + b) * v;
            p2 += lrelu(acc3[2] + b) * v; p3 += lrelu(acc3[3] + b) * v;
        }
        p0 += __shfl_xor(p0, 1); p0 += __shfl_xor(p0, 2); p0 += __shfl_xor(p0, 4); p0 += __shfl_xor(p0, 8);
        p1 += __shfl_xor(p1, 1); p1 += __shfl_xor(p1, 2); p1 += __shfl_xor(p1, 4); p1 += __shfl_xor(p1, 8);
        p2 += __shfl_xor(p2, 1); p2 += __shfl_xor(p2, 2); p2 += __shfl_xor(p2, 4); p2 += __shfl_xor(p2, 8);
        p3 += __shfl_xor(p3, 1); p3 += __shfl_xor(p3, 2); p3 += __shfl_xor(p3, 4); p3 += __shfl_xor(p3, 8);
        if (krow == 0) {
            part[w][kgrp * 4 + 0] = p0;
            part[w][kgrp * 4 + 1] = p1;
            part[w][kgrp * 4 + 2] = p2;
            part[w][kgrp * 4 + 3] = p3;
        }
    }
    __syncthreads();
    if (tid < 16)
        out[row0 + tid] = part[0][tid] + part[1][tid] + part[2][tid] + part[3][tid] + bo2[0];
}

extern "C" void kernel_launch(void* const* d_in, const int* in_sizes, int n_in,
                              void* d_out, int out_size, void* d_ws, size_t ws_size,
                              hipStream_t stream) {
    const float* W_pi1 = (const float*)d_in[0];
    const float* b_pi1 = (const float*)d_in[1];
    const float* W_pi2 = (const float*)d_in[2];
    const float* b_pi2 = (const float*)d_in[3];
    const float* W_p1  = (const float*)d_in[8];
    const float* b_p1  = (const float*)d_in[9];
    const float* W_p2  = (const float*)d_in[10];
    const float* W_n1  = (const float*)d_in[12];
    const float* b_n1  = (const float*)d_in[13];
    const float* W_n2  = (const float*)d_in[14];
    const float* b_n2  = (const float*)d_in[15];
    const float* W_g1  = (const float*)d_in[16];
    const float* b_g1  = (const float*)d_in[17];
    const float* W_g2  = (const float*)d_in[18];
    const float* b_g2  = (const float*)d_in[19];
    const float* W_o1  = (const float*)d_in[20];
    const float* b_o1  = (const float*)d_in[21];
    const float* W_o2  = (const float*)d_in[22];
    const float* b_o2  = (const float*)d_in[23];
    const float* av    = (const float*)d_in[24];
    const float* delay = (const float*)d_in[26];
    const float* bit_pos = (const float*)d_in[27];
    const float* po_feat = (const float*)d_in[28];
    const int*   is_po   = (const int*)d_in[29];
    const int*   nbr_idx = (const int*)d_in[30];

    u16*   h_all = (u16*)d_ws;                                // NN*NH bf16 (33.5 MB)
    float* g_all = (float*)(h_all + (size_t)NN * NH);         // NN floats
    u16*   neigh = (u16*)(g_all + NN);                        // NM*NH bf16 (4 MB)
    float* cst   = (float*)(neigh + (size_t)NM * NH);         // 64 floats
    u16*   Wo1t  = (u16*)(cst + 64);                          // 256*512 bf16
    u16*   W1t   = Wo1t + 256 * 512;                          // 128*256 bf16
    u16*   W2t   = W1t + 128 * 256;                           // 256*128 bf16
    float* out   = (float*)d_out;

    precomp_kernel<<<1, 32, 0, stream>>>(W_p2, av, cst);
    transpose_bf16_kernel<<<128, 256, 0, stream>>>(W_o1, Wo1t, 512, 256);
    transpose_bf16_kernel<<<32, 256, 0, stream>>>(W_n1, W1t, 256, 128);
    transpose_bf16_kernel<<<32, 256, 0, stream>>>(W_n2, W2t, 128, 256);

    level0_kernel<<<NM / 32, 512, 0, stream>>>(delay, W_pi1, b_pi1, W_pi2, b_pi2,
                                               av, h_all, g_all);

    for (int level = 1; level < NL; ++level) {
        attn_kernel<<<NM / 4, 256, 0, stream>>>(h_all, g_all, bit_pos, nbr_idx,
                                                W_p1, b_p1, cst, neigh, level);
        mlp_n_kernel<<<NM / 16, 256, 0, stream>>>(neigh, W1t, b_n1, W2t, b_n2,
                                                  is_po, av, h_all, g_all, level);
    }

    final_kernel<<<NM / 16, 256, 0, stream>>>(h_all + (size_t)(NN - NM) * NH, po_feat,
                                              W_g1, b_g1, W_g2, b_g2,
                                              Wo1t, b_o1, W_o2, b_o2, out);
}

// Round 19
// 201.119 us; speedup vs baseline: 6.6235x; 1.0144x over previous
//
#include <hip/hip_runtime.h>

#define NL 8
#define NM 8192
#define ND 16
#define NH 256
#define NF 64
#define NN (NL * NM)

typedef unsigned short u16;
typedef __attribute__((ext_vector_type(8))) short bf16x8;
typedef __attribute__((ext_vector_type(4))) float f32x4;

__device__ __forceinline__ float lrelu(float x) { return fmaxf(x, 0.1f * x); }

__device__ __forceinline__ u16 f2bf(float x) {
    union { float f; unsigned int u; } v; v.f = x;
    unsigned int r = (v.u + 0x7FFFu + ((v.u >> 16) & 1u)) >> 16;
    return (u16)r;
}
__device__ __forceinline__ float bf2f(u16 u) {
    union { unsigned int u; float f; } v; v.u = ((unsigned int)u) << 16;
    return v.f;
}
__device__ __forceinline__ ushort4 f4_to_bf4(float4 o) {
    ushort4 r; r.x = f2bf(o.x); r.y = f2bf(o.y); r.z = f2bf(o.z); r.w = f2bf(o.w);
    return r;
}
__device__ __forceinline__ float2 bfp(unsigned int u) {
    union { unsigned int u; float f; } lo, hi;
    lo.u = u << 16; hi.u = u & 0xFFFF0000u;
    return make_float2(lo.f, hi.f);
}

// ---------- precompute attention constants: cst[32..63] = W_p2 @ av_p ----------
__global__ void precomp_kernel(const float* __restrict__ W_p2, const float* __restrict__ av,
                               float* __restrict__ cst)
{
    int j = threadIdx.x;   // 32 threads
    float w = 0.f;
    for (int k = 0; k < 32; ++k) w += W_p2[j * 32 + k] * av[32 + k];
    cst[32 + j] = w;
}

// ---------- generic: out[C][R] (bf16) = transpose(in [R][C] f32) ----------
__global__ __launch_bounds__(256) void transpose_bf16_kernel(
    const float* __restrict__ in, u16* __restrict__ out, int R, int C)
{
    const int tiles_c = C >> 5;
    const int tr = blockIdx.x / tiles_c, tc = blockIdx.x % tiles_c;
    const int r0 = tr * 32, c0 = tc * 32;
    const int tx = threadIdx.x & 31, ty4 = threadIdx.x >> 5;
    __shared__ float t[32][33];
    #pragma unroll
    for (int i = 0; i < 4; ++i) {
        int r = ty4 + i * 8;
        t[r][tx] = in[(size_t)(r0 + r) * C + c0 + tx];
    }
    __syncthreads();
    #pragma unroll
    for (int i = 0; i < 4; ++i) {
        int c = ty4 + i * 8;
        out[(size_t)(c0 + c) * R + r0 + tx] = f2bf(t[tx][c]);
    }
}

// ---------- Level 0: h = mlp_pi(delay) (bf16 store) + g epilogue ----------
__global__ __launch_bounds__(512) void level0_kernel(
    const float* __restrict__ delay,
    const float* __restrict__ W1, const float* __restrict__ b1,
    const float* __restrict__ W2, const float* __restrict__ b2,
    const float* __restrict__ av,
    u16* __restrict__ h_all, float* __restrict__ g_all)
{
    const int tid = threadIdx.x;
    const int row0 = blockIdx.x * 32;
    __shared__ __align__(16) float sH[32][132];

    for (int x = tid; x < 32 * 128; x += 512) {
        int r = x >> 7, j = x & 127;
        sH[r][j] = lrelu(delay[row0 + r] * W1[j] + b1[j]);
    }
    __syncthreads();

    const int tj = tid & 63, tr = tid >> 6;
    const float4 av4 = *(const float4*)(av + 64 + tj * 4);
    float acc[4][4];
    #pragma unroll
    for (int a = 0; a < 4; ++a)
        #pragma unroll
        for (int b = 0; b < 4; ++b) acc[a][b] = 0.f;

    for (int k = 0; k < 128; k += 4) {
        float4 w0 = *(const float4*)(W2 + (size_t)(k + 0) * 256 + tj * 4);
        float4 w1 = *(const float4*)(W2 + (size_t)(k + 1) * 256 + tj * 4);
        float4 w2 = *(const float4*)(W2 + (size_t)(k + 2) * 256 + tj * 4);
        float4 w3 = *(const float4*)(W2 + (size_t)(k + 3) * 256 + tj * 4);
        #pragma unroll
        for (int rr = 0; rr < 4; ++rr) {
            float4 xv = *(const float4*)(&sH[tr * 4 + rr][k]);
            acc[rr][0] += xv.x * w0.x + xv.y * w1.x + xv.z * w2.x + xv.w * w3.x;
            acc[rr][1] += xv.x * w0.y + xv.y * w1.y + xv.z * w2.y + xv.w * w3.y;
            acc[rr][2] += xv.x * w0.z + xv.y * w1.z + xv.z * w2.z + xv.w * w3.z;
            acc[rr][3] += xv.x * w0.w + xv.y * w1.w + xv.z * w2.w + xv.w * w3.w;
        }
    }
    float4 bv = *(const float4*)(b2 + tj * 4);
    #pragma unroll
    for (int rr = 0; rr < 4; ++rr) {
        const int row = row0 + tr * 4 + rr;
        float4 o;
        o.x = acc[rr][0] + bv.x; o.y = acc[rr][1] + bv.y;
        o.z = acc[rr][2] + bv.z; o.w = acc[rr][3] + bv.w;
        *(ushort4*)(h_all + (size_t)row * NH + tj * 4) = f4_to_bf4(o);
        float gp = o.x * av4.x + o.y * av4.y + o.z * av4.z + o.w * av4.w;
        #pragma unroll
        for (int off = 1; off < 64; off <<= 1) gp += __shfl_xor(gp, off);
        if (tj == 0) g_all[row] = gp;
    }
}

// ---------- Attention: 1 wave per m; g-gather alpha + single 16B-load streamed pass ----------
__global__ __launch_bounds__(256) void attn_kernel(
    const u16* __restrict__ h_all, const float* __restrict__ g_all,
    const float* __restrict__ bit_pos, const int* __restrict__ nbr_idx,
    const float* __restrict__ W_p1, const float* __restrict__ b_p1,
    const float* __restrict__ cst,
    u16* __restrict__ neigh, int level)
{
    const int w = threadIdx.x >> 6, lane = threadIdx.x & 63;
    const int m = blockIdx.x * 4 + w;
    const int d = lane & 15, jj = lane >> 4;
    const size_t ebase = ((size_t)(level - 1) * NM + m) * ND;

    const int   idx = nbr_idx[ebase + d];
    const float bp  = bit_pos[ebase + d];

    float ep = 0.f;
    #pragma unroll
    for (int t = 0; t < 8; ++t) {
        int j = jj * 8 + t;
        ep += cst[32 + j] * lrelu(bp * W_p1[j] + b_p1[j]);
    }
    ep += __shfl_xor(ep, 16);
    ep += __shfl_xor(ep, 32);

    float e = g_all[idx] + ep;
    float mx = e;
    #pragma unroll
    for (int off = 1; off < 16; off <<= 1) mx = fmaxf(mx, __shfl_xor(mx, off));
    float wexp = __expf(e - mx);
    float s = wexp;
    #pragma unroll
    for (int off = 1; off < 16; off <<= 1) s += __shfl_xor(s, off);
    const float alpha = wexp / s;

    const int rh = lane >> 5, cl = lane & 31;
    float4 a0 = make_float4(0.f, 0.f, 0.f, 0.f);
    float4 a1 = make_float4(0.f, 0.f, 0.f, 0.f);
    #pragma unroll
    for (int t = 0; t < 8; ++t) {
        const int d2 = t * 2 + rh;
        float a = __shfl(alpha, d2);
        int   r = __shfl(idx, d2);
        uint4 hv = *(const uint4*)(h_all + (size_t)r * NH + cl * 8);
        float2 p0 = bfp(hv.x), p1 = bfp(hv.y), p2 = bfp(hv.z), p3 = bfp(hv.w);
        a0.x += a * p0.x; a0.y += a * p0.y; a0.z += a * p1.x; a0.w += a * p1.y;
        a1.x += a * p2.x; a1.y += a * p2.y; a1.z += a * p3.x; a1.w += a * p3.y;
    }
    a0.x += __shfl_xor(a0.x, 32); a0.y += __shfl_xor(a0.y, 32);
    a0.z += __shfl_xor(a0.z, 32); a0.w += __shfl_xor(a0.w, 32);
    a1.x += __shfl_xor(a1.x, 32); a1.y += __shfl_xor(a1.y, 32);
    a1.z += __shfl_xor(a1.z, 32); a1.w += __shfl_xor(a1.w, 32);

    float4 outv = (rh == 0) ? a0 : a1;
    *(ushort4*)(neigh + (size_t)m * NH + cl * 8 + rh * 4) = f4_to_bf4(outv);
}

// ---------- Neighborhood MLP: both layers via MFMA; layer2 uses split-bf16 activations ----------
__global__ __launch_bounds__(256) void mlp_n_kernel(
    const u16* __restrict__ neigh, const u16* __restrict__ W1t,
    const float* __restrict__ b1,
    const u16* __restrict__ W2t, const float* __restrict__ b2,
    const int* __restrict__ is_po, const float* __restrict__ av,
    u16* __restrict__ h_all, float* __restrict__ g_all, int level)
{
    const int tid = threadIdx.x;
    const int w = tid >> 6, lane = tid & 63;
    const int row0 = blockIdx.x * 16;
    __shared__ __align__(16) u16 sXb[16][NH + 8];
    __shared__ __align__(16) u16 sHhi[16][136];
    __shared__ __align__(16) u16 sHlo[16][136];
    __shared__ float gpart[4][16];

    for (int x = tid; x < 16 * 32; x += 256) {
        int r = x >> 5, c = x & 31;
        *(uint4*)(&sXb[r][c * 8]) = *(const uint4*)(neigh + (size_t)(row0 + r) * NH + c * 8);
    }
    __syncthreads();

    const int krow = lane & 15, kgrp = lane >> 4;

    // layer 1 via MFMA
    {
        f32x4 acc0 = {0.f, 0.f, 0.f, 0.f};
        f32x4 acc1 = {0.f, 0.f, 0.f, 0.f};
        #pragma unroll 2
        for (int ks = 0; ks < 8; ++ks) {
            const int k0 = ks * 32;
            bf16x8 aF = *(const bf16x8*)(&sXb[krow][k0 + kgrp * 8]);
            const u16* bbase = W1t + (size_t)(w * 32 + krow) * 256 + k0 + kgrp * 8;
            bf16x8 b0 = *(const bf16x8*)(bbase);
            bf16x8 b1v = *(const bf16x8*)(bbase + 16 * 256);
            acc0 = __builtin_amdgcn_mfma_f32_16x16x32_bf16(aF, b0, acc0, 0, 0, 0);
            acc1 = __builtin_amdgcn_mfma_f32_16x16x32_bf16(aF, b1v, acc1, 0, 0, 0);
        }
        {
            const int c = w * 32 + krow;
            const float b = b1[c];
            #pragma unroll
            for (int r = 0; r < 4; ++r) {
                float v = lrelu(acc0[r] + b);
                u16 hi = f2bf(v);
                sHhi[kgrp * 4 + r][c] = hi;
                sHlo[kgrp * 4 + r][c] = f2bf(v - bf2f(hi));
            }
        }
        {
            const int c = w * 32 + 16 + krow;
            const float b = b1[c];
            #pragma unroll
            for (int r = 0; r < 4; ++r) {
                float v = lrelu(acc1[r] + b);
                u16 hi = f2bf(v);
                sHhi[kgrp * 4 + r][c] = hi;
                sHlo[kgrp * 4 + r][c] = f2bf(v - bf2f(hi));
            }
        }
    }
    __syncthreads();

    // layer 2 via MFMA: split-precision activations
    {
        f32x4 acc0 = {0.f, 0.f, 0.f, 0.f};
        f32x4 acc1 = {0.f, 0.f, 0.f, 0.f};
        f32x4 acc2 = {0.f, 0.f, 0.f, 0.f};
        f32x4 acc3 = {0.f, 0.f, 0.f, 0.f};
        #pragma unroll 2
        for (int ks = 0; ks < 4; ++ks) {
            const int k0 = ks * 32;
            bf16x8 ahi = *(const bf16x8*)(&sHhi[krow][k0 + kgrp * 8]);
            bf16x8 alo = *(const bf16x8*)(&sHlo[krow][k0 + kgrp * 8]);
            const u16* bb = W2t + (size_t)(w * 64 + krow) * 128 + k0 + kgrp * 8;
            bf16x8 b0 = *(const bf16x8*)(bb);
            bf16x8 b1v = *(const bf16x8*)(bb + 16 * 128);
            bf16x8 b2v = *(const bf16x8*)(bb + 32 * 128);
            bf16x8 b3v = *(const bf16x8*)(bb + 48 * 128);
            acc0 = __builtin_amdgcn_mfma_f32_16x16x32_bf16(ahi, b0, acc0, 0, 0, 0);
            acc0 = __builtin_amdgcn_mfma_f32_16x16x32_bf16(alo, b0, acc0, 0, 0, 0);
            acc1 = __builtin_amdgcn_mfma_f32_16x16x32_bf16(ahi, b1v, acc1, 0, 0, 0);
            acc1 = __builtin_amdgcn_mfma_f32_16x16x32_bf16(alo, b1v, acc1, 0, 0, 0);
            acc2 = __builtin_amdgcn_mfma_f32_16x16x32_bf16(ahi, b2v, acc2, 0, 0, 0);
            acc2 = __builtin_amdgcn_mfma_f32_16x16x32_bf16(alo, b2v, acc2, 0, 0, 0);
            acc3 = __builtin_amdgcn_mfma_f32_16x16x32_bf16(ahi, b3v, acc3, 0, 0, 0);
            acc3 = __builtin_amdgcn_mfma_f32_16x16x32_bf16(alo, b3v, acc3, 0, 0, 0);
        }

        int po0 = is_po[level * NM + row0 + kgrp * 4 + 0];
        int po1 = is_po[level * NM + row0 + kgrp * 4 + 1];
        int po2 = is_po[level * NM + row0 + kgrp * 4 + 2];
        int po3 = is_po[level * NM + row0 + kgrp * 4 + 3];

        float gsum0 = 0.f, gsum1 = 0.f, gsum2 = 0.f, gsum3 = 0.f;
        #pragma unroll
        for (int t = 0; t < 4; ++t) {
            f32x4 a = (t == 0) ? acc0 : (t == 1) ? acc1 : (t == 2) ? acc2 : acc3;
            const int c = w * 64 + t * 16 + krow;
            const float b = b2[c];
            const float avc = av[64 + c];
            float o0 = a[0] + b, o1 = a[1] + b, o2 = a[2] + b, o3 = a[3] + b;
            if (po0 != 1) o0 = fmaxf(o0, 0.f);
            if (po1 != 1) o1 = fmaxf(o1, 0.f);
            if (po2 != 1) o2 = fmaxf(o2, 0.f);
            if (po3 != 1) o3 = fmaxf(o3, 0.f);
            sXb[kgrp * 4 + 0][c] = f2bf(o0);
            sXb[kgrp * 4 + 1][c] = f2bf(o1);
            sXb[kgrp * 4 + 2][c] = f2bf(o2);
            sXb[kgrp * 4 + 3][c] = f2bf(o3);
            gsum0 += o0 * avc; gsum1 += o1 * avc;
            gsum2 += o2 * avc; gsum3 += o3 * avc;
        }
        gsum0 += __shfl_xor(gsum0, 1); gsum0 += __shfl_xor(gsum0, 2);
        gsum0 += __shfl_xor(gsum0, 4); gsum0 += __shfl_xor(gsum0, 8);
        gsum1 += __shfl_xor(gsum1, 1); gsum1 += __shfl_xor(gsum1, 2);
        gsum1 += __shfl_xor(gsum1, 4); gsum1 += __shfl_xor(gsum1, 8);
        gsum2 += __shfl_xor(gsum2, 1); gsum2 += __shfl_xor(gsum2, 2);
        gsum2 += __shfl_xor(gsum2, 4); gsum2 += __shfl_xor(gsum2, 8);
        gsum3 += __shfl_xor(gsum3, 1); gsum3 += __shfl_xor(gsum3, 2);
        gsum3 += __shfl_xor(gsum3, 4); gsum3 += __shfl_xor(gsum3, 8);
        if (krow == 0) {
            gpart[w][kgrp * 4 + 0] = gsum0;
            gpart[w][kgrp * 4 + 1] = gsum1;
            gpart[w][kgrp * 4 + 2] = gsum2;
            gpart[w][kgrp * 4 + 3] = gsum3;
        }
    }
    __syncthreads();

    if (tid < 16)
        g_all[level * NM + row0 + tid] =
            gpart[0][tid] + gpart[1][tid] + gpart[2][tid] + gpart[3][tid];

    for (int x = tid; x < 16 * 32; x += 256) {
        int r = x >> 5, c = x & 31;
        const int gm = level * NM + row0 + r;
        *(uint4*)(h_all + (size_t)gm * NH + c * 8) = *(const uint4*)(&sXb[r][c * 8]);
    }
}

// ---------- Final readout: all-MFMA (Wg2 + o1), bf16 staging ----------
__global__ __launch_bounds__(256) void final_kernel(
    const u16* __restrict__ h_gnn, const float* __restrict__ po_feat,
    const float* __restrict__ Wg1, const float* __restrict__ bg1,
    const u16* __restrict__ Wg2t, const float* __restrict__ bg2,
    const u16* __restrict__ Wo1t, const float* __restrict__ bo1,
    const float* __restrict__ Wo2, const float* __restrict__ bo2,
    float* __restrict__ out)
{
    const int tid = threadIdx.x;
    const int w = tid >> 6, lane = tid & 63;
    const int row0 = blockIdx.x * 16;
    __shared__ __align__(16) u16 sxb[16][520];
    __shared__ __align__(16) u16 sgb[16][136];
    __shared__ float part[4][16];

    for (int x = tid; x < 16 * 32; x += 256) {
        int r = x >> 5, c = x & 31;
        *(uint4*)(&sxb[r][c * 8]) = *(const uint4*)(h_gnn + (size_t)(row0 + r) * NH + c * 8);
    }
    for (int x = tid; x < 16 * 128; x += 256) {
        int r = x >> 7, j = x & 127;
        sgb[r][j] = f2bf(lrelu(po_feat[row0 + r] * Wg1[j] + bg1[j]));
    }
    __syncthreads();

    const int krow = lane & 15;
    const int kgrp = lane >> 4;

    // h_global = sgb @ Wg2t + bg2 via MFMA -> sxb[:, 256:] (bf16)
    // wave w -> cols [w*64, w*64+64) = 4 tiles; K=128 in 4 steps of 32
    {
        f32x4 acc0 = {0.f, 0.f, 0.f, 0.f};
        f32x4 acc1 = {0.f, 0.f, 0.f, 0.f};
        f32x4 acc2 = {0.f, 0.f, 0.f, 0.f};
        f32x4 acc3 = {0.f, 0.f, 0.f, 0.f};
        #pragma unroll 2
        for (int ks = 0; ks < 4; ++ks) {
            const int k0 = ks * 32;
            bf16x8 aF = *(const bf16x8*)(&sgb[krow][k0 + kgrp * 8]);
            const u16* bb = Wg2t + (size_t)(w * 64 + krow) * 128 + k0 + kgrp * 8;
            bf16x8 b0 = *(const bf16x8*)(bb);
            bf16x8 b1v = *(const bf16x8*)(bb + 16 * 128);
            bf16x8 b2v = *(const bf16x8*)(bb + 32 * 128);
            bf16x8 b3v = *(const bf16x8*)(bb + 48 * 128);
            acc0 = __builtin_amdgcn_mfma_f32_16x16x32_bf16(aF, b0, acc0, 0, 0, 0);
            acc1 = __builtin_amdgcn_mfma_f32_16x16x32_bf16(aF, b1v, acc1, 0, 0, 0);
            acc2 = __builtin_amdgcn_mfma_f32_16x16x32_bf16(aF, b2v, acc2, 0, 0, 0);
            acc3 = __builtin_amdgcn_mfma_f32_16x16x32_bf16(aF, b3v, acc3, 0, 0, 0);
        }
        #pragma unroll
        for (int t = 0; t < 4; ++t) {
            f32x4 a = (t == 0) ? acc0 : (t == 1) ? acc1 : (t == 2) ? acc2 : acc3;
            const int c = w * 64 + t * 16 + krow;
            const float b = bg2[c];
            #pragma unroll
            for (int r = 0; r < 4; ++r)
                sxb[kgrp * 4 + r][256 + c] = f2bf(a[r] + b);
        }
    }
    __syncthreads();

    // o1 = lrelu(sxb @ Wo1 + bo1) fused with out = o1 @ Wo2 + bo2 via MFMA
    {
        f32x4 acc0 = {0.f, 0.f, 0.f, 0.f};
        f32x4 acc1 = {0.f, 0.f, 0.f, 0.f};
        f32x4 acc2 = {0.f, 0.f, 0.f, 0.f};
        f32x4 acc3 = {0.f, 0.f, 0.f, 0.f};

        #pragma unroll 2
        for (int ks = 0; ks < 16; ++ks) {
            const int k0 = ks * 32;
            bf16x8 aF = *(const bf16x8*)(&sxb[krow][k0 + kgrp * 8]);
            const u16* bbase = Wo1t + (size_t)(w * 64 + krow) * 512 + k0 + kgrp * 8;
            bf16x8 b0 = *(const bf16x8*)(bbase);
            bf16x8 b1 = *(const bf16x8*)(bbase + 16 * 512);
            bf16x8 b2 = *(const bf16x8*)(bbase + 32 * 512);
            bf16x8 b3 = *(const bf16x8*)(bbase + 48 * 512);
            acc0 = __builtin_amdgcn_mfma_f32_16x16x32_bf16(aF, b0, acc0, 0, 0, 0);
            acc1 = __builtin_amdgcn_mfma_f32_16x16x32_bf16(aF, b1, acc1, 0, 0, 0);
            acc2 = __builtin_amdgcn_mfma_f32_16x16x32_bf16(aF, b2, acc2, 0, 0, 0);
            acc3 = __builtin_amdgcn_mfma_f32_16x16x32_bf16(aF, b3, acc3, 0, 0, 0);
        }

        float p0 = 0.f, p1 = 0.f, p2 = 0.f, p3 = 0.f;
        {
            int c = w * 64 + 0 * 16 + krow;  float b = bo1[c], v = Wo2[c];
            p0 += lrelu(acc0[0] + b) * v; p1 += lrelu(acc0[1] + b) * v;
            p2 += lrelu(acc0[2] + b) * v; p3 += lrelu(acc0[3] + b) * v;
        }
        {
            int c = w * 64 + 1 * 16 + krow;  float b = bo1[c], v = Wo2[c];
            p0 += lrelu(acc1[0] + b) * v; p1 += lrelu(acc1[1] + b) * v;
            p2 += lrelu(acc1[2] + b) * v; p3 += lrelu(acc1[3] + b) * v;
        }
        {
            int c = w * 64 + 2 * 16 + krow;  float b = bo1[c], v = Wo2[c];
            p0 += lrelu(acc2[0] + b) * v; p1 += lrelu(acc2[1] + b) * v;
            p2 += lrelu(acc2[2] + b) * v; p3 += lrelu(acc2[3] + b) * v;
        }
        {
            int c = w * 64 + 3 * 16 + krow;  float b = bo1[c], v = Wo2[c];
            p0 += lrelu(acc3[0] + b) * v; p1 += lrelu(acc3[1] + b) * v;
            p2 += lrelu(acc3[2] + b) * v; p3 += lrelu(acc3[3] + b) * v;
        }
        p0 += __shfl_xor(p0, 1); p0 += __shfl_xor(p0, 2); p0 += __shfl_xor(p0, 4); p0 += __shfl_xor(p0, 8);
        p1 += __shfl_xor(p1, 1); p1 += __shfl_xor(p1, 2); p1 += __shfl_xor(p1, 4); p1 += __shfl_xor(p1, 8);
        p2 += __shfl_xor(p2, 1); p2 += __shfl_xor(p2, 2); p2 += __shfl_xor(p2, 4); p2 += __shfl_xor(p2, 8);
        p3 += __shfl_xor(p3, 1); p3 += __shfl_xor(p3, 2); p3 += __shfl_xor(p3, 4); p3 += __shfl_xor(p3, 8);
        if (krow == 0) {
            part[w][kgrp * 4 + 0] = p0;
            part[w][kgrp * 4 + 1] = p1;
            part[w][kgrp * 4 + 2] = p2;
            part[w][kgrp * 4 + 3] = p3;
        }
    }
    __syncthreads();
    if (tid < 16)
        out[row0 + tid] = part[0][tid] + part[1][tid] + part[2][tid] + part[3][tid] + bo2[0];
}

extern "C" void kernel_launch(void* const* d_in, const int* in_sizes, int n_in,
                              void* d_out, int out_size, void* d_ws, size_t ws_size,
                              hipStream_t stream) {
    const float* W_pi1 = (const float*)d_in[0];
    const float* b_pi1 = (const float*)d_in[1];
    const float* W_pi2 = (const float*)d_in[2];
    const float* b_pi2 = (const float*)d_in[3];
    const float* W_p1  = (const float*)d_in[8];
    const float* b_p1  = (const float*)d_in[9];
    const float* W_p2  = (const float*)d_in[10];
    const float* W_n1  = (const float*)d_in[12];
    const float* b_n1  = (const float*)d_in[13];
    const float* W_n2  = (const float*)d_in[14];
    const float* b_n2  = (const float*)d_in[15];
    const float* W_g1  = (const float*)d_in[16];
    const float* b_g1  = (const float*)d_in[17];
    const float* W_g2  = (const float*)d_in[18];
    const float* b_g2  = (const float*)d_in[19];
    const float* W_o1  = (const float*)d_in[20];
    const float* b_o1  = (const float*)d_in[21];
    const float* W_o2  = (const float*)d_in[22];
    const float* b_o2  = (const float*)d_in[23];
    const float* av    = (const float*)d_in[24];
    const float* delay = (const float*)d_in[26];
    const float* bit_pos = (const float*)d_in[27];
    const float* po_feat = (const float*)d_in[28];
    const int*   is_po   = (const int*)d_in[29];
    const int*   nbr_idx = (const int*)d_in[30];

    u16*   h_all = (u16*)d_ws;                                // NN*NH bf16 (33.5 MB)
    float* g_all = (float*)(h_all + (size_t)NN * NH);         // NN floats
    u16*   neigh = (u16*)(g_all + NN);                        // NM*NH bf16 (4 MB)
    float* cst   = (float*)(neigh + (size_t)NM * NH);         // 64 floats
    u16*   Wo1t  = (u16*)(cst + 64);                          // 256*512 bf16
    u16*   W1t   = Wo1t + 256 * 512;                          // 128*256 bf16
    u16*   W2t   = W1t + 128 * 256;                           // 256*128 bf16
    u16*   Wg2t  = W2t + 256 * 128;                           // 256*128 bf16
    float* out   = (float*)d_out;

    precomp_kernel<<<1, 32, 0, stream>>>(W_p2, av, cst);
    transpose_bf16_kernel<<<128, 256, 0, stream>>>(W_o1, Wo1t, 512, 256);
    transpose_bf16_kernel<<<32, 256, 0, stream>>>(W_n1, W1t, 256, 128);
    transpose_bf16_kernel<<<32, 256, 0, stream>>>(W_n2, W2t, 128, 256);
    transpose_bf16_kernel<<<32, 256, 0, stream>>>(W_g2, Wg2t, 128, 256);

    level0_kernel<<<NM / 32, 512, 0, stream>>>(delay, W_pi1, b_pi1, W_pi2, b_pi2,
                                               av, h_all, g_all);

    for (int level = 1; level < NL; ++level) {
        attn_kernel<<<NM / 4, 256, 0, stream>>>(h_all, g_all, bit_pos, nbr_idx,
                                                W_p1, b_p1, cst, neigh, level);
        mlp_n_kernel<<<NM / 16, 256, 0, stream>>>(neigh, W1t, b_n1, W2t, b_n2,
                                                  is_po, av, h_all, g_all, level);
    }

    final_kernel<<<NM / 16, 256, 0, stream>>>(h_all + (size_t)(NN - NM) * NH, po_feat,
                                              W_g1, b_g1, Wg2t, b_g2,
                                              Wo1t, b_o1, W_o2, b_o2, out);
}